// Round 5
// baseline (14813.579 us; speedup 1.0000x reference)
//
#include <hip/hip_runtime.h>
#include <hip/hip_bf16.h>
#include <math.h>

#define TCc 200
#define TDc 50
#define BATCH 256
#define Ec 300
#define Hc 512
#define VOC 10000
#define EPAD 320
#define KC_E 10
#define KC_H 16

typedef unsigned short u16;
typedef unsigned int u32;
typedef __bf16 bf16x8 __attribute__((ext_vector_type(8)));
typedef float f32x4 __attribute__((ext_vector_type(4)));

__device__ __forceinline__ float sigf(float x) { return 1.f / (1.f + expf(-x)); }

__device__ __forceinline__ u16 f2bf(float f) {
  unsigned u = __float_as_uint(f);
  unsigned r = (u + 0x7FFFu + ((u >> 16) & 1u)) >> 16;  // RNE
  return (u16)r;
}
__device__ __forceinline__ float bf2f(u16 v) { return __uint_as_float(((unsigned)v) << 16); }

__global__ __launch_bounds__(256) void zero_kernel(float* p, int n) {
  int i = blockIdx.x * 256 + threadIdx.x;
  if (i < n) p[i] = 0.f;
}

// emb (VOC, Ec) fp32 -> (VOC, EPAD) bf16, zero-padded
__global__ __launch_bounds__(256) void conv_emb_kernel(
    const float* __restrict__ emb, u32* __restrict__ out)
{
  int e = blockIdx.x * 256 + threadIdx.x;          // u32 index, VOC*EPAD/2 total
  if (e >= VOC * (EPAD / 2)) return;
  int v = e / (EPAD / 2);
  int k = (e - v * (EPAD / 2)) * 2;
  float a = (k < Ec) ? emb[(size_t)v * Ec + k] : 0.f;
  float b = (k + 1 < Ec) ? emb[(size_t)v * Ec + k + 1] : 0.f;
  out[e] = (u32)f2bf(a) | ((u32)f2bf(b) << 16);
}

// Weight (rows x K) fp32 -> MFMA B-fragment order bf16.
// Frag layout: [nc][kc][si][lane 64][8 bf16]; col-in-group c32 = si*16 + (lane&15);
// k = kc*32 + (lane>>4)*8 + jj. GATES: col c' = 4*ul+g -> source row g*512 + nc*8 + ul.
// else source row = nc*32 + c32.
template<int GATES>
__global__ __launch_bounds__(256) void conv_wfrag_kernel(
    const float* __restrict__ W, u32* __restrict__ out, int KC, int KREAL, int total)
{
  int e = blockIdx.x * 256 + threadIdx.x;          // u32 index
  if (e >= total) return;
  int jp = e & 3;
  int l = (e >> 2) & 63;
  int si = (e >> 8) & 1;
  int t2 = e >> 9;
  int kc = t2 % KC;
  int nc = t2 / KC;
  int c32 = (si << 4) + (l & 15);
  int srow = GATES ? (((c32 & 3) << 9) + nc * 8 + (c32 >> 2)) : (nc * 32 + c32);
  int k = (kc << 5) + ((l >> 4) << 3) + (jp << 1);
  float a = (k < KREAL) ? W[(size_t)srow * KREAL + k] : 0.f;
  float b = (k + 1 < KREAL) ? W[(size_t)srow * KREAL + k + 1] : 0.f;
  out[e] = (u32)f2bf(a) | ((u32)f2bf(b) << 16);
}

// ---------------- persistent MFMA LSTM, software rowgroup barrier ----------------
__device__ __forceinline__ void group_barrier(unsigned* cnt, unsigned target) {
  __threadfence();
  __syncthreads();
  if (threadIdx.x == 0) {
    __hip_atomic_fetch_add(cnt, 1u, __ATOMIC_ACQ_REL, __HIP_MEMORY_SCOPE_AGENT);
    while (__hip_atomic_load(cnt, __ATOMIC_ACQUIRE, __HIP_MEMORY_SCOPE_AGENT) < target)
      __builtin_amdgcn_s_sleep(1);
  }
  __syncthreads();
  __threadfence();
}

struct PArgs {
  const u32* WhhT; const u32* WihT; const u16* embT;
  const u32* WhhD; const u32* WihD; const u16* embD;
  const int* tokens; const int* desc_anchor; const int* desc_neg;
  const int* desc_anchor_len; const int* desc_neg_len;
  const float* tok_bih; const float* tok_bhh;
  const float* desc_bih; const float* desc_bhh;
  u16* hA; u16* hB; u16* hC; u16* hD;
  u16* featB; float* finals;
  unsigned* cnt;
};

// 256 blocks = 4 rowgroups x 64 colgroups (8 units = 32 gate-cols each).
// ROWS=64 (tok) / 128 (desc). RPW = ROWS/64 row-halves per wave.
template<int ROWS, bool IS_TOK>
__device__ void lstm_phase(
    u16* WhF, u16* WiF, float* gsum, int* idsL,
    const u32* __restrict__ WhhF, const u32* __restrict__ WihF, const u16* __restrict__ embB,
    const int* __restrict__ idsA, const int* __restrict__ idsB,
    const int* __restrict__ lenA, const int* __restrict__ lenB,
    const float* __restrict__ bih, const float* __restrict__ bhh,
    u16* __restrict__ h0, u16* __restrict__ h1,
    u16* __restrict__ featB, float* __restrict__ finals,
    unsigned* cntrg, int& gen, int T)
{
  constexpr int RPW = ROWS / 64;
  const int tid = threadIdx.x;
  const int cg = blockIdx.x & 63;
  const int row0 = (blockIdx.x >> 6) * ROWS;
  const int w = tid >> 6, l = tid & 63;
  const int rl = tid >> 2, u = tid & 3;

  // stage weight fragments into LDS
  {
    const uint4* s = (const uint4*)(WhhF + ((size_t)cg << 13));   // cg*8192 u32
    uint4* d = (uint4*)WhF;
    #pragma unroll
    for (int i = 0; i < 8; ++i) d[(i << 8) + tid] = s[(i << 8) + tid];
    const uint4* s2 = (const uint4*)(WihF + (size_t)cg * 5120);
    uint4* d2 = (uint4*)WiF;
    #pragma unroll
    for (int i = 0; i < 5; ++i) d2[(i << 8) + tid] = s2[(i << 8) + tid];
  }

  float bsv[2][4];
  #pragma unroll
  for (int uu = 0; uu < 2; ++uu)
    #pragma unroll
    for (int g = 0; g < 4; ++g) {
      int ug = (cg << 3) + u + (uu << 2);
      bsv[uu][g] = bih[(g << 9) + ug] + bhh[(g << 9) + ug];
    }

  float cc[RPW][2];
  int lens[RPW];
  #pragma unroll
  for (int p = 0; p < RPW; ++p) {
    cc[p][0] = 0.f; cc[p][1] = 0.f;
    int row = row0 + (p << 6) + rl;
    lens[p] = IS_TOK ? 0 : ((row < BATCH) ? lenA[row] : lenB[row - BATCH]);
    *(u32*)(h0 + ((size_t)row << 9) + (cg << 3) + (u << 1)) = 0;
  }
  ++gen; group_barrier(cntrg, (unsigned)gen * 64u);

  for (int t = 0; t < T; ++t) {
    const u16* hin = (t & 1) ? h1 : h0;
    u16* hout = (t & 1) ? h0 : h1;

    if (tid < ROWS) {
      int row = row0 + tid;
      idsL[tid] = IS_TOK ? idsA[row * T + t]
                         : ((row < BATCH) ? idsA[row * T + t] : idsB[(row - BATCH) * T + t]);
    }
    __syncthreads();

    f32x4 acc[RPW][2];
    #pragma unroll
    for (int p = 0; p < RPW; ++p) {
      acc[p][0] = (f32x4){0.f, 0.f, 0.f, 0.f};
      acc[p][1] = (f32x4){0.f, 0.f, 0.f, 0.f};
    }
    const u16* eb[RPW];
    const u16* hb[RPW];
    #pragma unroll
    for (int p = 0; p < RPW; ++p) {
      int rhp = w + (p << 2);
      int ida = idsL[(rhp << 4) + (l & 15)];
      eb[p] = embB + (size_t)ida * EPAD + ((l >> 4) << 3);
      hb[p] = hin + (((size_t)(row0 + (rhp << 4) + (l & 15))) << 9) + ((l >> 4) << 3);
    }
    #pragma unroll 2
    for (int kc = 0; kc < KC_E; ++kc) {
      bf16x8 b0 = *(const bf16x8*)(WiF + ((((kc << 1) | 0) << 6 | l) << 3));
      bf16x8 b1 = *(const bf16x8*)(WiF + ((((kc << 1) | 1) << 6 | l) << 3));
      #pragma unroll
      for (int p = 0; p < RPW; ++p) {
        bf16x8 a = *(const bf16x8*)(eb[p] + (kc << 5));
        acc[p][0] = __builtin_amdgcn_mfma_f32_16x16x32_bf16(a, b0, acc[p][0], 0, 0, 0);
        acc[p][1] = __builtin_amdgcn_mfma_f32_16x16x32_bf16(a, b1, acc[p][1], 0, 0, 0);
      }
    }
    #pragma unroll 4
    for (int kc = 0; kc < KC_H; ++kc) {
      bf16x8 b0 = *(const bf16x8*)(WhF + ((((kc << 1) | 0) << 6 | l) << 3));
      bf16x8 b1 = *(const bf16x8*)(WhF + ((((kc << 1) | 1) << 6 | l) << 3));
      #pragma unroll
      for (int p = 0; p < RPW; ++p) {
        bf16x8 a = *(const bf16x8*)(hb[p] + (kc << 5));
        acc[p][0] = __builtin_amdgcn_mfma_f32_16x16x32_bf16(a, b0, acc[p][0], 0, 0, 0);
        acc[p][1] = __builtin_amdgcn_mfma_f32_16x16x32_bf16(a, b1, acc[p][1], 0, 0, 0);
      }
    }

    #pragma unroll
    for (int p = 0; p < RPW; ++p) {
      int lr0 = (w << 4) + ((l >> 4) << 2);
      #pragma unroll
      for (int si = 0; si < 2; ++si)
        #pragma unroll
        for (int j = 0; j < 4; ++j)
          gsum[(lr0 + j) * 36 + (si << 4) + (l & 15)] = acc[p][si][j];
      __syncthreads();
      {
        float4 g0 = *(const float4*)&gsum[rl * 36 + (u << 2)];
        float4 g1 = *(const float4*)&gsum[rl * 36 + ((u + 4) << 2)];
        int row = row0 + (p << 6) + rl;
        float gi0 = sigf(g0.x + bsv[0][0]);
        float gf0 = sigf(g0.y + bsv[0][1]);
        float gg0 = tanhf(g0.z + bsv[0][2]);
        float go0 = sigf(g0.w + bsv[0][3]);
        float cn0 = gf0 * cc[p][0] + gi0 * gg0;
        cc[p][0] = cn0;
        float hn0 = go0 * tanhf(cn0);
        float gi1 = sigf(g1.x + bsv[1][0]);
        float gf1 = sigf(g1.y + bsv[1][1]);
        float gg1 = tanhf(g1.z + bsv[1][2]);
        float go1 = sigf(g1.w + bsv[1][3]);
        float cn1 = gf1 * cc[p][1] + gi1 * gg1;
        cc[p][1] = cn1;
        float hn1 = go1 * tanhf(cn1);
        int ug0 = (cg << 3) + u, ug1 = ug0 + 4;
        hout[((size_t)row << 9) + ug0] = f2bf(hn0);
        hout[((size_t)row << 9) + ug1] = f2bf(hn1);
        if (IS_TOK) {
          size_t fo = ((size_t)row * TCc + t) << 9;
          featB[fo + ug0] = f2bf(tanhf(hn0));
          featB[fo + ug1] = f2bf(tanhf(hn1));
        } else if (t == lens[p] - 1) {
          finals[((size_t)row << 9) + ug0] = tanhf(hn0);
          finals[((size_t)row << 9) + ug1] = tanhf(hn1);
        }
      }
      __syncthreads();
    }
    ++gen; group_barrier(cntrg, (unsigned)gen * 64u);
  }
}

__global__ void __launch_bounds__(256, 1) lstm_persist_kernel(PArgs A) {
  __shared__ __align__(16) u16 WhF[KC_H * 2 * 64 * 8];   // 32768 B
  __shared__ __align__(16) u16 WiF[KC_E * 2 * 64 * 8];   // 20480 B
  __shared__ __align__(16) float gsum[64 * 36];          // 9216 B
  __shared__ int idsL[128];                              // 512 B
  unsigned* cntrg = A.cnt + ((blockIdx.x >> 6) << 4);
  int gen = 0;
  lstm_phase<64, true>(WhF, WiF, gsum, idsL, A.WhhT, A.WihT, A.embT,
                       A.tokens, nullptr, nullptr, nullptr,
                       A.tok_bih, A.tok_bhh, A.hA, A.hB, A.featB, nullptr,
                       cntrg, gen, TCc);
  lstm_phase<128, false>(WhF, WiF, gsum, idsL, A.WhhD, A.WihD, A.embD,
                         A.desc_anchor, A.desc_neg, A.desc_anchor_len, A.desc_neg_len,
                         A.desc_bih, A.desc_bhh, A.hC, A.hD, nullptr, A.finals,
                         cntrg, gen, TDc);
}

// ---------------- attention scores via MFMA ----------------
// scores[m] = tanh(feat[m,:] @ attn_W^T + attn_b) . attnS_W + attnS_b
// Block: 64 rows; A-frags staged in 64KB LDS; wave w owns n-chunks w*4..w*4+3 (32 cols each).
__global__ __launch_bounds__(256) void attn_scores_mfma(
    const u16* __restrict__ featB, const u32* __restrict__ WF,
    const float* __restrict__ attn_b, const float* __restrict__ attnS_W,
    const float* __restrict__ attnS_b, float* __restrict__ scores)
{
  __shared__ __align__(16) u16 Af[4 * 16 * 64 * 8];   // 65536 B (reused as red after)
  const int tid = threadIdx.x;
  const int m0 = blockIdx.x * 64;

  #pragma unroll
  for (int i = 0; i < 16; ++i) {
    int c = (i << 8) + tid;
    int r = c >> 6, kb = c & 63;
    uint4 v = *(const uint4*)(featB + (((size_t)(m0 + r)) << 9) + (kb << 3));
    int kc = kb >> 2, lf = (r & 15) + ((kb & 3) << 4);
    *(uint4*)(Af + ((((r >> 4) * 16 + kc) << 6 | lf) << 3)) = v;
  }
  __syncthreads();

  const int w = tid >> 6, l = tid & 63;
  const u16* WF16 = (const u16*)WF;
  float p[4][4] = {};
  for (int nc = w * 4; nc < w * 4 + 4; ++nc) {
    f32x4 acc[4][2];
    #pragma unroll
    for (int rh = 0; rh < 4; ++rh) {
      acc[rh][0] = (f32x4){0.f, 0.f, 0.f, 0.f};
      acc[rh][1] = (f32x4){0.f, 0.f, 0.f, 0.f};
    }
    #pragma unroll 4
    for (int kc = 0; kc < 16; ++kc) {
      bf16x8 b0 = *(const bf16x8*)(WF16 + ((size_t)((((nc << 4) + kc) << 1 | 0) << 6 | l) << 3));
      bf16x8 b1 = *(const bf16x8*)(WF16 + ((size_t)((((nc << 4) + kc) << 1 | 1) << 6 | l) << 3));
      #pragma unroll
      for (int rh = 0; rh < 4; ++rh) {
        bf16x8 a = *(const bf16x8*)(Af + (((rh * 16 + kc) << 6 | l) << 3));
        acc[rh][0] = __builtin_amdgcn_mfma_f32_16x16x32_bf16(a, b0, acc[rh][0], 0, 0, 0);
        acc[rh][1] = __builtin_amdgcn_mfma_f32_16x16x32_bf16(a, b1, acc[rh][1], 0, 0, 0);
      }
    }
    int c0 = (nc << 5) + (l & 15), c1 = c0 + 16;
    float bb0 = attn_b[c0], sw0 = attnS_W[c0];
    float bb1 = attn_b[c1], sw1 = attnS_W[c1];
    #pragma unroll
    for (int rh = 0; rh < 4; ++rh)
      #pragma unroll
      for (int j = 0; j < 4; ++j)
        p[rh][j] += tanhf(acc[rh][0][j] + bb0) * sw0 + tanhf(acc[rh][1][j] + bb1) * sw1;
  }
  __syncthreads();
  float* red = (float*)Af;   // 64 x 68
  #pragma unroll
  for (int rh = 0; rh < 4; ++rh)
    #pragma unroll
    for (int j = 0; j < 4; ++j)
      red[(rh * 16 + ((l >> 4) << 2) + j) * 68 + (w << 4) + (l & 15)] = p[rh][j];
  __syncthreads();
  if (tid < 64) {
    float s = attnS_b[0];
    #pragma unroll 8
    for (int q = 0; q < 64; ++q) s += red[tid * 68 + q];
    scores[m0 + tid] = s;
  }
}

// masked softmax over T=200 + weighted pooling of bf16 feat -> pooled (B,H) fp32
__global__ __launch_bounds__(256) void softmax_pool_kernel(
    const float* __restrict__ scores, const int* __restrict__ tok_len,
    const u16* __restrict__ featB, float* __restrict__ pooled)
{
  const int b = blockIdx.x;
  const int tid = threadIdx.x;
  __shared__ float wgt[TCc];
  __shared__ float red[256];
  const int len = tok_len[b];

  float myv = -1e30f;
  if (tid < TCc) {
    float s = scores[b * TCc + tid];
    myv = (tid < len) ? s : -1e9f;
    wgt[tid] = myv;
  }
  red[tid] = myv;
  __syncthreads();
  for (int s = 128; s > 0; s >>= 1) {
    if (tid < s) red[tid] = fmaxf(red[tid], red[tid + s]);
    __syncthreads();
  }
  const float mx = red[0];
  __syncthreads();
  float e = 0.f;
  if (tid < TCc) e = expf(wgt[tid] - mx);
  red[tid] = e;
  __syncthreads();
  for (int s = 128; s > 0; s >>= 1) {
    if (tid < s) red[tid] += red[tid + s];
    __syncthreads();
  }
  const float sum = red[0];
  __syncthreads();
  if (tid < TCc) wgt[tid] = e / sum;
  __syncthreads();

  const u32* featU = (const u32*)featB;
  float a0 = 0.f, a1 = 0.f;
  for (int t = 0; t < TCc; ++t) {
    u32 v = featU[((size_t)b * TCc + t) * 256 + tid];
    float wv = wgt[t];
    a0 = fmaf(wv, bf2f((u16)(v & 0xFFFF)), a0);
    a1 = fmaf(wv, bf2f((u16)(v >> 16)), a1);
  }
  pooled[((size_t)b << 9) + tid * 2] = a0;
  pooled[((size_t)b << 9) + tid * 2 + 1] = a1;
}

// C[m,n] = tanh(A[m,:] . W[n,:] + bias[n]); fp32, grid (M/64, N/64)
__global__ __launch_bounds__(256) void gemm_bias_tanh_kernel(
    const float* __restrict__ A, const float* __restrict__ Bw,
    const float* __restrict__ bias, float* __restrict__ C, int M, int N, int K)
{
  const int r0 = blockIdx.x * 64;
  const int n0 = blockIdx.y * 64;
  const int tid = threadIdx.x;
  const int tu = tid & 15;
  const int tm = tid >> 4;
  __shared__ float As[32][68];
  __shared__ float Bs[32][68];

  float acc[4][4] = {};
  for (int k0 = 0; k0 < K; k0 += 32) {
    #pragma unroll
    for (int i = 0; i < 2; ++i) {
      int lin = tid + (i << 8);
      int kq = lin & 7, m = lin >> 3;
      int k = k0 + (kq << 2);
      int r = r0 + m; if (r >= M) r = M - 1;
      float4 va = *(const float4*)&A[(size_t)r * K + k];
      float4 vb = *(const float4*)&Bw[(size_t)(n0 + m) * K + k];
      As[(kq << 2) + 0][m] = va.x; As[(kq << 2) + 1][m] = va.y;
      As[(kq << 2) + 2][m] = va.z; As[(kq << 2) + 3][m] = va.w;
      Bs[(kq << 2) + 0][m] = vb.x; Bs[(kq << 2) + 1][m] = vb.y;
      Bs[(kq << 2) + 2][m] = vb.z; Bs[(kq << 2) + 3][m] = vb.w;
    }
    __syncthreads();
    #pragma unroll
    for (int kk = 0; kk < 32; ++kk) {
      float4 a = *(const float4*)&As[kk][tm << 2];
      float4 b = *(const float4*)&Bs[kk][tu << 2];
      acc[0][0] = fmaf(a.x, b.x, acc[0][0]); acc[0][1] = fmaf(a.x, b.y, acc[0][1]);
      acc[0][2] = fmaf(a.x, b.z, acc[0][2]); acc[0][3] = fmaf(a.x, b.w, acc[0][3]);
      acc[1][0] = fmaf(a.y, b.x, acc[1][0]); acc[1][1] = fmaf(a.y, b.y, acc[1][1]);
      acc[1][2] = fmaf(a.y, b.z, acc[1][2]); acc[1][3] = fmaf(a.y, b.w, acc[1][3]);
      acc[2][0] = fmaf(a.z, b.x, acc[2][0]); acc[2][1] = fmaf(a.z, b.y, acc[2][1]);
      acc[2][2] = fmaf(a.z, b.z, acc[2][2]); acc[2][3] = fmaf(a.z, b.w, acc[2][3]);
      acc[3][0] = fmaf(a.w, b.x, acc[3][0]); acc[3][1] = fmaf(a.w, b.y, acc[3][1]);
      acc[3][2] = fmaf(a.w, b.z, acc[3][2]); acc[3][3] = fmaf(a.w, b.w, acc[3][3]);
    }
    __syncthreads();
  }
  float bj[4];
  #pragma unroll
  for (int j = 0; j < 4; ++j) bj[j] = bias[n0 + (tu << 2) + j];
  #pragma unroll
  for (int i = 0; i < 4; ++i) {
    int r = r0 + (tm << 2) + i;
    if (r < M) {
      float4 v;
      v.x = tanhf(acc[i][0] + bj[0]); v.y = tanhf(acc[i][1] + bj[1]);
      v.z = tanhf(acc[i][2] + bj[2]); v.w = tanhf(acc[i][3] + bj[3]);
      *(float4*)&C[(size_t)r * N + n0 + (tu << 2)] = v;
    }
  }
}

__global__ __launch_bounds__(256) void loss_kernel(
    const float* __restrict__ code, const float* __restrict__ finals, float* __restrict__ out)
{
  const int b = threadIdx.x;
  const float* cv = code + (size_t)b * Hc;
  const float* av = finals + (size_t)b * Hc;
  const float* nv = finals + (size_t)(BATCH + b) * Hc;
  float dca = 0, dcn = 0, ncc = 0, naa = 0, nnn = 0;
  for (int k = 0; k < Hc; ++k) {
    float c = cv[k], a = av[k], n = nv[k];
    dca = fmaf(c, a, dca);
    dcn = fmaf(c, n, dcn);
    ncc = fmaf(c, c, ncc);
    naa = fmaf(a, a, naa);
    nnn = fmaf(n, n, nnn);
  }
  float cos_a = dca / fmaxf(sqrtf(ncc) * sqrtf(naa), 1e-8f);
  float cos_n = dcn / fmaxf(sqrtf(ncc) * sqrtf(nnn), 1e-8f);
  float hinge = fmaxf(0.6f - cos_a + cos_n, 1e-6f);
  __shared__ float red[256];
  red[b] = hinge;
  __syncthreads();
  for (int s = 128; s > 0; s >>= 1) {
    if (b < s) red[b] += red[b + s];
    __syncthreads();
  }
  if (b == 0) out[0] = red[0] / 256.0f;
}

extern "C" void kernel_launch(void* const* d_in, const int* in_sizes, int n_in,
                              void* d_out, int out_size, void* d_ws, size_t ws_size,
                              hipStream_t stream) {
  const int* tokens          = (const int*)d_in[0];
  const int* tok_len         = (const int*)d_in[1];
  const int* desc_anchor     = (const int*)d_in[2];
  const int* desc_anchor_len = (const int*)d_in[3];
  const int* desc_neg        = (const int*)d_in[4];
  const int* desc_neg_len    = (const int*)d_in[5];
  const float* tok_emb  = (const float*)d_in[6];
  const float* tok_Wih  = (const float*)d_in[7];
  const float* tok_Whh  = (const float*)d_in[8];
  const float* tok_bih  = (const float*)d_in[9];
  const float* tok_bhh  = (const float*)d_in[10];
  const float* desc_emb = (const float*)d_in[11];
  const float* desc_Wih = (const float*)d_in[12];
  const float* desc_Whh = (const float*)d_in[13];
  const float* desc_bih = (const float*)d_in[14];
  const float* desc_bhh = (const float*)d_in[15];
  const float* attn_W   = (const float*)d_in[16];
  const float* attn_b   = (const float*)d_in[17];
  const float* attnS_W  = (const float*)d_in[18];
  const float* attnS_b  = (const float*)d_in[19];
  const float* out_W1   = (const float*)d_in[20];
  const float* out_b1   = (const float*)d_in[21];
  const float* out_W2   = (const float*)d_in[22];
  const float* out_b2   = (const float*)d_in[23];

  float* p = (float*)d_ws;
  size_t off = 0;
  auto alloc = [&](size_t n) { float* q = p + off; off += n; return q; };

  u16*  featB  = (u16*)alloc(13107200);     // 256*200*512 bf16
  u16*  embT   = (u16*)alloc(1600000);      // VOC*320 bf16
  u16*  embD   = (u16*)alloc(1600000);
  u32*  WihT   = (u32*)alloc(327680);       // 64nc * 10kc * 2si * 64 * 4
  u32*  WihD   = (u32*)alloc(327680);
  u32*  WhhT   = (u32*)alloc(524288);       // 64nc * 16kc * 2si * 64 * 4
  u32*  WhhD   = (u32*)alloc(524288);
  u32*  attnWF = (u32*)alloc(131072);       // 16nc * 16kc * 2si * 64 * 4
  u16*  hA     = (u16*)alloc(65536);        // 256*512 bf16
  u16*  hB     = (u16*)alloc(65536);
  u16*  hC     = (u16*)alloc(131072);       // 512*512 bf16
  u16*  hD     = (u16*)alloc(131072);
  float* finals = alloc(262144);            // 512*512 fp32
  float* scores = alloc(51200);
  float* pooled = alloc(131072);
  float* a2     = alloc(131072);
  float* code   = alloc(131072);
  unsigned* cnt = (unsigned*)alloc(256);    // 4 rg x 16-u32 spaced counters

  // weight / embedding conversions (independent, parallel-ish)
  conv_emb_kernel<<<(VOC * (EPAD / 2) + 255) / 256, 256, 0, stream>>>(tok_emb, (u32*)embT);
  conv_emb_kernel<<<(VOC * (EPAD / 2) + 255) / 256, 256, 0, stream>>>(desc_emb, (u32*)embD);
  conv_wfrag_kernel<1><<<2048, 256, 0, stream>>>(tok_Whh, WhhT, KC_H, Hc, 524288);
  conv_wfrag_kernel<1><<<2048, 256, 0, stream>>>(desc_Whh, WhhD, KC_H, Hc, 524288);
  conv_wfrag_kernel<1><<<1280, 256, 0, stream>>>(tok_Wih, WihT, KC_E, Ec, 327680);
  conv_wfrag_kernel<1><<<1280, 256, 0, stream>>>(desc_Wih, WihD, KC_E, Ec, 327680);
  conv_wfrag_kernel<0><<<512, 256, 0, stream>>>(attn_W, attnWF, KC_H, Hc, 131072);
  zero_kernel<<<1, 256, 0, stream>>>((float*)cnt, 64);

  PArgs A;
  A.WhhT = WhhT; A.WihT = WihT; A.embT = embT;
  A.WhhD = WhhD; A.WihD = WihD; A.embD = embD;
  A.tokens = tokens; A.desc_anchor = desc_anchor; A.desc_neg = desc_neg;
  A.desc_anchor_len = desc_anchor_len; A.desc_neg_len = desc_neg_len;
  A.tok_bih = tok_bih; A.tok_bhh = tok_bhh;
  A.desc_bih = desc_bih; A.desc_bhh = desc_bhh;
  A.hA = hA; A.hB = hB; A.hC = hC; A.hD = hD;
  A.featB = featB; A.finals = finals; A.cnt = cnt;
  lstm_persist_kernel<<<256, 256, 0, stream>>>(A);

  attn_scores_mfma<<<(BATCH * TCc) / 64, 256, 0, stream>>>(
      featB, attnWF, attn_b, attnS_W, attnS_b, scores);
  softmax_pool_kernel<<<BATCH, 256, 0, stream>>>(scores, tok_len, featB, pooled);
  gemm_bias_tanh_kernel<<<dim3(BATCH / 64, Hc / 64), 256, 0, stream>>>(
      pooled, out_W1, out_b1, a2, BATCH, Hc, Hc);
  gemm_bias_tanh_kernel<<<dim3(BATCH / 64, Hc / 64), 256, 0, stream>>>(
      a2, out_W2, out_b2, code, BATCH, Hc, Hc);
  loss_kernel<<<1, 256, 0, stream>>>(code, finals, (float*)d_out);
}

// Round 6
// 9039.938 us; speedup vs baseline: 1.6387x; 1.6387x over previous
//
#include <hip/hip_runtime.h>
#include <hip/hip_bf16.h>
#include <math.h>

#define TCc 200
#define TDc 50
#define BATCH 256
#define Ec 300
#define Hc 512
#define VOC 10000
#define EPAD 320
#define KC_E 10
#define KC_H 16

typedef unsigned short u16;
typedef unsigned int u32;
typedef __bf16 bf16x8 __attribute__((ext_vector_type(8)));
typedef float f32x4 __attribute__((ext_vector_type(4)));

__device__ __forceinline__ float sigf(float x) { return 1.f / (1.f + expf(-x)); }

__device__ __forceinline__ u16 f2bf(float f) {
  unsigned u = __float_as_uint(f);
  unsigned r = (u + 0x7FFFu + ((u >> 16) & 1u)) >> 16;  // RNE
  return (u16)r;
}
__device__ __forceinline__ float bf2f(u16 v) { return __uint_as_float(((unsigned)v) << 16); }

__global__ __launch_bounds__(256) void zero_kernel(float* p, int n) {
  int i = blockIdx.x * 256 + threadIdx.x;
  if (i < n) p[i] = 0.f;
}

// emb (VOC, Ec) fp32 -> (VOC, EPAD) bf16, zero-padded
__global__ __launch_bounds__(256) void conv_emb_kernel(
    const float* __restrict__ emb, u32* __restrict__ out)
{
  int e = blockIdx.x * 256 + threadIdx.x;          // u32 index, VOC*EPAD/2 total
  if (e >= VOC * (EPAD / 2)) return;
  int v = e / (EPAD / 2);
  int k = (e - v * (EPAD / 2)) * 2;
  float a = (k < Ec) ? emb[(size_t)v * Ec + k] : 0.f;
  float b = (k + 1 < Ec) ? emb[(size_t)v * Ec + k + 1] : 0.f;
  out[e] = (u32)f2bf(a) | ((u32)f2bf(b) << 16);
}

// Weight (rows x K) fp32 -> MFMA B-fragment order bf16.
// Frag layout: [nc][kc][si][lane 64][8 bf16]; col-in-group c32 = si*16 + (lane&15);
// k = kc*32 + (lane>>4)*8 + jj.
// GATES: position ul'=c32>>2, g=c32&3; actual unit = ((ul'&3)<<1)|(ul'>>2)  (so the
// epilogue thread that reads positions u and u+4 gets ADJACENT units 2u, 2u+1);
// source row = g*512 + nc*8 + unit. Else: source row = nc*32 + c32.
template<int GATES>
__global__ __launch_bounds__(256) void conv_wfrag_kernel(
    const float* __restrict__ W, u32* __restrict__ out, int KC, int KREAL, int total)
{
  int e = blockIdx.x * 256 + threadIdx.x;          // u32 index
  if (e >= total) return;
  int jp = e & 3;
  int l = (e >> 2) & 63;
  int si = (e >> 8) & 1;
  int t2 = e >> 9;
  int kc = t2 % KC;
  int nc = t2 / KC;
  int c32 = (si << 4) + (l & 15);
  int srow;
  if (GATES) {
    int ulp = c32 >> 2, g = c32 & 3;
    int unit = ((ulp & 3) << 1) | (ulp >> 2);
    srow = (g << 9) + nc * 8 + unit;
  } else {
    srow = nc * 32 + c32;
  }
  int k = (kc << 5) + ((l >> 4) << 3) + (jp << 1);
  float a = (k < KREAL) ? W[(size_t)srow * KREAL + k] : 0.f;
  float b = (k + 1 < KREAL) ? W[(size_t)srow * KREAL + k + 1] : 0.f;
  out[e] = (u32)f2bf(a) | ((u32)f2bf(b) << 16);
}

// ---------------- persistent MFMA LSTM, flag-array rowgroup barrier ----------------
// flags: per rowgroup, 64 slots spaced 16 u32 (64 B) apart. Each block release-stores
// its own slot = gen, then lane l of wave 0 polls slot l. No RMW contention.
__device__ __forceinline__ void group_barrier(unsigned* flags, int cg, unsigned gen) {
  __threadfence();
  __syncthreads();
  if (threadIdx.x < 64) {
    if (threadIdx.x == 0)
      __hip_atomic_store(flags + (cg << 4), gen, __ATOMIC_RELEASE, __HIP_MEMORY_SCOPE_AGENT);
    unsigned v;
    do {
      v = __hip_atomic_load(flags + (threadIdx.x << 4), __ATOMIC_ACQUIRE,
                            __HIP_MEMORY_SCOPE_AGENT);
      if (v >= gen) break;
      __builtin_amdgcn_s_sleep(2);
    } while (true);
  }
  __syncthreads();
}

struct PArgs {
  const u32* WhhT; const u32* WihT; const u16* embT;
  const u32* WhhD; const u32* WihD; const u16* embD;
  const int* tokens; const int* desc_anchor; const int* desc_neg;
  const int* desc_anchor_len; const int* desc_neg_len;
  const float* tok_bih; const float* tok_bhh;
  const float* desc_bih; const float* desc_bhh;
  u16* hA; u16* hB; u16* hC; u16* hD;
  u16* featB; float* finals;
  unsigned* flags;
};

// 256 blocks = 4 rowgroups x 64 colgroups (8 units = 32 gate-cols each).
// ROWS=64 (tok) / 128 (desc). RPW = ROWS/64 row-halves per wave.
template<int ROWS, bool IS_TOK>
__device__ void lstm_phase(
    u16* WhF, u16* WiF, float* gsum, int* idsL,
    const u32* __restrict__ WhhF, const u32* __restrict__ WihF, const u16* __restrict__ embB,
    const int* __restrict__ idsA, const int* __restrict__ idsB,
    const int* __restrict__ lenA, const int* __restrict__ lenB,
    const float* __restrict__ bih, const float* __restrict__ bhh,
    u16* __restrict__ h0, u16* __restrict__ h1,
    u16* __restrict__ featB, float* __restrict__ finals,
    unsigned* flrg, int& gen, int T)
{
  constexpr int RPW = ROWS / 64;
  const int tid = threadIdx.x;
  const int cg = blockIdx.x & 63;
  const int row0 = (blockIdx.x >> 6) * ROWS;
  const int w = tid >> 6, l = tid & 63;
  const int rl = tid >> 2, u = tid & 3;

  // stage weight fragments into LDS
  {
    const uint4* s = (const uint4*)(WhhF + ((size_t)cg << 13));   // cg*8192 u32
    uint4* d = (uint4*)WhF;
    #pragma unroll
    for (int i = 0; i < 8; ++i) d[(i << 8) + tid] = s[(i << 8) + tid];
    const uint4* s2 = (const uint4*)(WihF + (size_t)cg * 5120);
    uint4* d2 = (uint4*)WiF;
    #pragma unroll
    for (int i = 0; i < 5; ++i) d2[(i << 8) + tid] = s2[(i << 8) + tid];
  }

  // units owned by this epilogue thread: ug0 = cg*8 + 2u, ug1 = ug0+1 (adjacent)
  float bsv[2][4];
  #pragma unroll
  for (int uu = 0; uu < 2; ++uu)
    #pragma unroll
    for (int g = 0; g < 4; ++g) {
      int ug = (cg << 3) + (u << 1) + uu;
      bsv[uu][g] = bih[(g << 9) + ug] + bhh[(g << 9) + ug];
    }

  float cc[RPW][2];
  int lens[RPW];
  #pragma unroll
  for (int p = 0; p < RPW; ++p) {
    cc[p][0] = 0.f; cc[p][1] = 0.f;
    int row = row0 + (p << 6) + rl;
    lens[p] = IS_TOK ? 0 : ((row < BATCH) ? lenA[row] : lenB[row - BATCH]);
    *(u32*)(h0 + ((size_t)row << 9) + (cg << 3) + (u << 1)) = 0;
  }
  ++gen; group_barrier(flrg, cg, (unsigned)gen);

  for (int t = 0; t < T; ++t) {
    const u16* hin = (t & 1) ? h1 : h0;
    u16* hout = (t & 1) ? h0 : h1;

    if (tid < ROWS) {
      int row = row0 + tid;
      idsL[tid] = IS_TOK ? idsA[row * T + t]
                         : ((row < BATCH) ? idsA[row * T + t] : idsB[(row - BATCH) * T + t]);
    }
    __syncthreads();

    f32x4 acc[RPW][2];
    #pragma unroll
    for (int p = 0; p < RPW; ++p) {
      acc[p][0] = (f32x4){0.f, 0.f, 0.f, 0.f};
      acc[p][1] = (f32x4){0.f, 0.f, 0.f, 0.f};
    }
    const u16* eb[RPW];
    const u16* hb[RPW];
    #pragma unroll
    for (int p = 0; p < RPW; ++p) {
      int rhp = w + (p << 2);
      int ida = idsL[(rhp << 4) + (l & 15)];
      eb[p] = embB + (size_t)ida * EPAD + ((l >> 4) << 3);
      hb[p] = hin + (((size_t)(row0 + (rhp << 4) + (l & 15))) << 9) + ((l >> 4) << 3);
    }
    #pragma unroll 2
    for (int kc = 0; kc < KC_E; ++kc) {
      bf16x8 b0 = *(const bf16x8*)(WiF + ((((kc << 1) | 0) << 6 | l) << 3));
      bf16x8 b1 = *(const bf16x8*)(WiF + ((((kc << 1) | 1) << 6 | l) << 3));
      #pragma unroll
      for (int p = 0; p < RPW; ++p) {
        bf16x8 a = *(const bf16x8*)(eb[p] + (kc << 5));
        acc[p][0] = __builtin_amdgcn_mfma_f32_16x16x32_bf16(a, b0, acc[p][0], 0, 0, 0);
        acc[p][1] = __builtin_amdgcn_mfma_f32_16x16x32_bf16(a, b1, acc[p][1], 0, 0, 0);
      }
    }
    #pragma unroll 4
    for (int kc = 0; kc < KC_H; ++kc) {
      bf16x8 b0 = *(const bf16x8*)(WhF + ((((kc << 1) | 0) << 6 | l) << 3));
      bf16x8 b1 = *(const bf16x8*)(WhF + ((((kc << 1) | 1) << 6 | l) << 3));
      #pragma unroll
      for (int p = 0; p < RPW; ++p) {
        bf16x8 a = *(const bf16x8*)(hb[p] + (kc << 5));
        acc[p][0] = __builtin_amdgcn_mfma_f32_16x16x32_bf16(a, b0, acc[p][0], 0, 0, 0);
        acc[p][1] = __builtin_amdgcn_mfma_f32_16x16x32_bf16(a, b1, acc[p][1], 0, 0, 0);
      }
    }

    #pragma unroll
    for (int p = 0; p < RPW; ++p) {
      int lr0 = (w << 4) + ((l >> 4) << 2);
      #pragma unroll
      for (int si = 0; si < 2; ++si)
        #pragma unroll
        for (int j = 0; j < 4; ++j)
          gsum[(lr0 + j) * 36 + (si << 4) + (l & 15)] = acc[p][si][j];
      __syncthreads();
      {
        float4 g0 = *(const float4*)&gsum[rl * 36 + (u << 2)];          // unit 2u
        float4 g1 = *(const float4*)&gsum[rl * 36 + ((u + 4) << 2)];    // unit 2u+1
        int row = row0 + (p << 6) + rl;
        float gi0 = sigf(g0.x + bsv[0][0]);
        float gf0 = sigf(g0.y + bsv[0][1]);
        float gg0 = tanhf(g0.z + bsv[0][2]);
        float go0 = sigf(g0.w + bsv[0][3]);
        float cn0 = gf0 * cc[p][0] + gi0 * gg0;
        cc[p][0] = cn0;
        float hn0 = go0 * tanhf(cn0);
        float gi1 = sigf(g1.x + bsv[1][0]);
        float gf1 = sigf(g1.y + bsv[1][1]);
        float gg1 = tanhf(g1.z + bsv[1][2]);
        float go1 = sigf(g1.w + bsv[1][3]);
        float cn1 = gf1 * cc[p][1] + gi1 * gg1;
        cc[p][1] = cn1;
        float hn1 = go1 * tanhf(cn1);
        int ug0 = (cg << 3) + (u << 1);
        *(u32*)(hout + ((size_t)row << 9) + ug0) =
            (u32)f2bf(hn0) | ((u32)f2bf(hn1) << 16);
        if (IS_TOK) {
          size_t fo = ((size_t)row * TCc + t) << 9;
          *(u32*)(featB + fo + ug0) =
              (u32)f2bf(tanhf(hn0)) | ((u32)f2bf(tanhf(hn1)) << 16);
        } else if (t == lens[p] - 1) {
          finals[((size_t)row << 9) + ug0]     = tanhf(hn0);
          finals[((size_t)row << 9) + ug0 + 1] = tanhf(hn1);
        }
      }
      __syncthreads();
    }
    ++gen; group_barrier(flrg, cg, (unsigned)gen);
  }
}

__global__ void __launch_bounds__(256, 1) lstm_persist_kernel(PArgs A) {
  __shared__ __align__(16) u16 WhF[KC_H * 2 * 64 * 8];   // 32768 B
  __shared__ __align__(16) u16 WiF[KC_E * 2 * 64 * 8];   // 20480 B
  __shared__ __align__(16) float gsum[64 * 36];          // 9216 B
  __shared__ int idsL[128];                              // 512 B
  unsigned* flrg = A.flags + ((blockIdx.x >> 6) << 10);  // rowgroup flag region
  int gen = 0;
  lstm_phase<64, true>(WhF, WiF, gsum, idsL, A.WhhT, A.WihT, A.embT,
                       A.tokens, nullptr, nullptr, nullptr,
                       A.tok_bih, A.tok_bhh, A.hA, A.hB, A.featB, nullptr,
                       flrg, gen, TCc);
  lstm_phase<128, false>(WhF, WiF, gsum, idsL, A.WhhD, A.WihD, A.embD,
                         A.desc_anchor, A.desc_neg, A.desc_anchor_len, A.desc_neg_len,
                         A.desc_bih, A.desc_bhh, A.hC, A.hD, nullptr, A.finals,
                         flrg, gen, TDc);
}

// ---------------- attention scores via MFMA ----------------
__global__ __launch_bounds__(256) void attn_scores_mfma(
    const u16* __restrict__ featB, const u32* __restrict__ WF,
    const float* __restrict__ attn_b, const float* __restrict__ attnS_W,
    const float* __restrict__ attnS_b, float* __restrict__ scores)
{
  __shared__ __align__(16) u16 Af[4 * 16 * 64 * 8];   // 65536 B (reused as red after)
  const int tid = threadIdx.x;
  const int m0 = blockIdx.x * 64;

  #pragma unroll
  for (int i = 0; i < 16; ++i) {
    int c = (i << 8) + tid;
    int r = c >> 6, kb = c & 63;
    uint4 v = *(const uint4*)(featB + (((size_t)(m0 + r)) << 9) + (kb << 3));
    int kc = kb >> 2, lf = (r & 15) + ((kb & 3) << 4);
    *(uint4*)(Af + ((((r >> 4) * 16 + kc) << 6 | lf) << 3)) = v;
  }
  __syncthreads();

  const int w = tid >> 6, l = tid & 63;
  const u16* WF16 = (const u16*)WF;
  float p[4][4] = {};
  for (int nc = w * 4; nc < w * 4 + 4; ++nc) {
    f32x4 acc[4][2];
    #pragma unroll
    for (int rh = 0; rh < 4; ++rh) {
      acc[rh][0] = (f32x4){0.f, 0.f, 0.f, 0.f};
      acc[rh][1] = (f32x4){0.f, 0.f, 0.f, 0.f};
    }
    #pragma unroll 4
    for (int kc = 0; kc < 16; ++kc) {
      bf16x8 b0 = *(const bf16x8*)(WF16 + ((size_t)((((nc << 4) + kc) << 1 | 0) << 6 | l) << 3));
      bf16x8 b1 = *(const bf16x8*)(WF16 + ((size_t)((((nc << 4) + kc) << 1 | 1) << 6 | l) << 3));
      #pragma unroll
      for (int rh = 0; rh < 4; ++rh) {
        bf16x8 a = *(const bf16x8*)(Af + (((rh * 16 + kc) << 6 | l) << 3));
        acc[rh][0] = __builtin_amdgcn_mfma_f32_16x16x32_bf16(a, b0, acc[rh][0], 0, 0, 0);
        acc[rh][1] = __builtin_amdgcn_mfma_f32_16x16x32_bf16(a, b1, acc[rh][1], 0, 0, 0);
      }
    }
    int c0 = (nc << 5) + (l & 15), c1 = c0 + 16;
    float bb0 = attn_b[c0], sw0 = attnS_W[c0];
    float bb1 = attn_b[c1], sw1 = attnS_W[c1];
    #pragma unroll
    for (int rh = 0; rh < 4; ++rh)
      #pragma unroll
      for (int j = 0; j < 4; ++j)
        p[rh][j] += tanhf(acc[rh][0][j] + bb0) * sw0 + tanhf(acc[rh][1][j] + bb1) * sw1;
  }
  __syncthreads();
  float* red = (float*)Af;   // 64 x 68
  #pragma unroll
  for (int rh = 0; rh < 4; ++rh)
    #pragma unroll
    for (int j = 0; j < 4; ++j)
      red[(rh * 16 + ((l >> 4) << 2) + j) * 68 + (w << 4) + (l & 15)] = p[rh][j];
  __syncthreads();
  if (tid < 64) {
    float s = attnS_b[0];
    #pragma unroll 8
    for (int q = 0; q < 64; ++q) s += red[tid * 68 + q];
    scores[m0 + tid] = s;
  }
}

// masked softmax over T=200 + weighted pooling of bf16 feat -> pooled (B,H) fp32
__global__ __launch_bounds__(256) void softmax_pool_kernel(
    const float* __restrict__ scores, const int* __restrict__ tok_len,
    const u16* __restrict__ featB, float* __restrict__ pooled)
{
  const int b = blockIdx.x;
  const int tid = threadIdx.x;
  __shared__ float wgt[TCc];
  __shared__ float red[256];
  const int len = tok_len[b];

  float myv = -1e30f;
  if (tid < TCc) {
    float s = scores[b * TCc + tid];
    myv = (tid < len) ? s : -1e9f;
    wgt[tid] = myv;
  }
  red[tid] = myv;
  __syncthreads();
  for (int s = 128; s > 0; s >>= 1) {
    if (tid < s) red[tid] = fmaxf(red[tid], red[tid + s]);
    __syncthreads();
  }
  const float mx = red[0];
  __syncthreads();
  float e = 0.f;
  if (tid < TCc) e = expf(wgt[tid] - mx);
  red[tid] = e;
  __syncthreads();
  for (int s = 128; s > 0; s >>= 1) {
    if (tid < s) red[tid] += red[tid + s];
    __syncthreads();
  }
  const float sum = red[0];
  __syncthreads();
  if (tid < TCc) wgt[tid] = e / sum;
  __syncthreads();

  const u32* featU = (const u32*)featB;
  float a0 = 0.f, a1 = 0.f;
  for (int t = 0; t < TCc; ++t) {
    u32 v = featU[((size_t)b * TCc + t) * 256 + tid];
    float wv = wgt[t];
    a0 = fmaf(wv, bf2f((u16)(v & 0xFFFF)), a0);
    a1 = fmaf(wv, bf2f((u16)(v >> 16)), a1);
  }
  pooled[((size_t)b << 9) + tid * 2] = a0;
  pooled[((size_t)b << 9) + tid * 2 + 1] = a1;
}

// C[m,n] = tanh(A[m,:] . W[n,:] + bias[n]); fp32, grid (M/64, N/64)
__global__ __launch_bounds__(256) void gemm_bias_tanh_kernel(
    const float* __restrict__ A, const float* __restrict__ Bw,
    const float* __restrict__ bias, float* __restrict__ C, int M, int N, int K)
{
  const int r0 = blockIdx.x * 64;
  const int n0 = blockIdx.y * 64;
  const int tid = threadIdx.x;
  const int tu = tid & 15;
  const int tm = tid >> 4;
  __shared__ float As[32][68];
  __shared__ float Bs[32][68];

  float acc[4][4] = {};
  for (int k0 = 0; k0 < K; k0 += 32) {
    #pragma unroll
    for (int i = 0; i < 2; ++i) {
      int lin = tid + (i << 8);
      int kq = lin & 7, m = lin >> 3;
      int k = k0 + (kq << 2);
      int r = r0 + m; if (r >= M) r = M - 1;
      float4 va = *(const float4*)&A[(size_t)r * K + k];
      float4 vb = *(const float4*)&Bw[(size_t)(n0 + m) * K + k];
      As[(kq << 2) + 0][m] = va.x; As[(kq << 2) + 1][m] = va.y;
      As[(kq << 2) + 2][m] = va.z; As[(kq << 2) + 3][m] = va.w;
      Bs[(kq << 2) + 0][m] = vb.x; Bs[(kq << 2) + 1][m] = vb.y;
      Bs[(kq << 2) + 2][m] = vb.z; Bs[(kq << 2) + 3][m] = vb.w;
    }
    __syncthreads();
    #pragma unroll
    for (int kk = 0; kk < 32; ++kk) {
      float4 a = *(const float4*)&As[kk][tm << 2];
      float4 b = *(const float4*)&Bs[kk][tu << 2];
      acc[0][0] = fmaf(a.x, b.x, acc[0][0]); acc[0][1] = fmaf(a.x, b.y, acc[0][1]);
      acc[0][2] = fmaf(a.x, b.z, acc[0][2]); acc[0][3] = fmaf(a.x, b.w, acc[0][3]);
      acc[1][0] = fmaf(a.y, b.x, acc[1][0]); acc[1][1] = fmaf(a.y, b.y, acc[1][1]);
      acc[1][2] = fmaf(a.y, b.z, acc[1][2]); acc[1][3] = fmaf(a.y, b.w, acc[1][3]);
      acc[2][0] = fmaf(a.z, b.x, acc[2][0]); acc[2][1] = fmaf(a.z, b.y, acc[2][1]);
      acc[2][2] = fmaf(a.z, b.z, acc[2][2]); acc[2][3] = fmaf(a.z, b.w, acc[2][3]);
      acc[3][0] = fmaf(a.w, b.x, acc[3][0]); acc[3][1] = fmaf(a.w, b.y, acc[3][1]);
      acc[3][2] = fmaf(a.w, b.z, acc[3][2]); acc[3][3] = fmaf(a.w, b.w, acc[3][3]);
    }
    __syncthreads();
  }
  float bj[4];
  #pragma unroll
  for (int j = 0; j < 4; ++j) bj[j] = bias[n0 + (tu << 2) + j];
  #pragma unroll
  for (int i = 0; i < 4; ++i) {
    int r = r0 + (tm << 2) + i;
    if (r < M) {
      float4 v;
      v.x = tanhf(acc[i][0] + bj[0]); v.y = tanhf(acc[i][1] + bj[1]);
      v.z = tanhf(acc[i][2] + bj[2]); v.w = tanhf(acc[i][3] + bj[3]);
      *(float4*)&C[(size_t)r * N + n0 + (tu << 2)] = v;
    }
  }
}

__global__ __launch_bounds__(256) void loss_kernel(
    const float* __restrict__ code, const float* __restrict__ finals, float* __restrict__ out)
{
  const int b = threadIdx.x;
  const float* cv = code + (size_t)b * Hc;
  const float* av = finals + (size_t)b * Hc;
  const float* nv = finals + (size_t)(BATCH + b) * Hc;
  float dca = 0, dcn = 0, ncc = 0, naa = 0, nnn = 0;
  for (int k = 0; k < Hc; ++k) {
    float c = cv[k], a = av[k], n = nv[k];
    dca = fmaf(c, a, dca);
    dcn = fmaf(c, n, dcn);
    ncc = fmaf(c, c, ncc);
    naa = fmaf(a, a, naa);
    nnn = fmaf(n, n, nnn);
  }
  float cos_a = dca / fmaxf(sqrtf(ncc) * sqrtf(naa), 1e-8f);
  float cos_n = dcn / fmaxf(sqrtf(ncc) * sqrtf(nnn), 1e-8f);
  float hinge = fmaxf(0.6f - cos_a + cos_n, 1e-6f);
  __shared__ float red[256];
  red[b] = hinge;
  __syncthreads();
  for (int s = 128; s > 0; s >>= 1) {
    if (b < s) red[b] += red[b + s];
    __syncthreads();
  }
  if (b == 0) out[0] = red[0] / 256.0f;
}

extern "C" void kernel_launch(void* const* d_in, const int* in_sizes, int n_in,
                              void* d_out, int out_size, void* d_ws, size_t ws_size,
                              hipStream_t stream) {
  const int* tokens          = (const int*)d_in[0];
  const int* tok_len         = (const int*)d_in[1];
  const int* desc_anchor     = (const int*)d_in[2];
  const int* desc_anchor_len = (const int*)d_in[3];
  const int* desc_neg        = (const int*)d_in[4];
  const int* desc_neg_len    = (const int*)d_in[5];
  const float* tok_emb  = (const float*)d_in[6];
  const float* tok_Wih  = (const float*)d_in[7];
  const float* tok_Whh  = (const float*)d_in[8];
  const float* tok_bih  = (const float*)d_in[9];
  const float* tok_bhh  = (const float*)d_in[10];
  const float* desc_emb = (const float*)d_in[11];
  const float* desc_Wih = (const float*)d_in[12];
  const float* desc_Whh = (const float*)d_in[13];
  const float* desc_bih = (const float*)d_in[14];
  const float* desc_bhh = (const float*)d_in[15];
  const float* attn_W   = (const float*)d_in[16];
  const float* attn_b   = (const float*)d_in[17];
  const float* attnS_W  = (const float*)d_in[18];
  const float* attnS_b  = (const float*)d_in[19];
  const float* out_W1   = (const float*)d_in[20];
  const float* out_b1   = (const float*)d_in[21];
  const float* out_W2   = (const float*)d_in[22];
  const float* out_b2   = (const float*)d_in[23];

  float* p = (float*)d_ws;
  size_t off = 0;
  auto alloc = [&](size_t n) { float* q = p + off; off += n; return q; };

  u16*  featB  = (u16*)alloc(13107200);     // 256*200*512 bf16
  u16*  embT   = (u16*)alloc(1600000);      // VOC*320 bf16
  u16*  embD   = (u16*)alloc(1600000);
  u32*  WihT   = (u32*)alloc(327680);       // 64nc * 10kc * 2si * 64 * 4
  u32*  WihD   = (u32*)alloc(327680);
  u32*  WhhT   = (u32*)alloc(524288);       // 64nc * 16kc * 2si * 64 * 4
  u32*  WhhD   = (u32*)alloc(524288);
  u32*  attnWF = (u32*)alloc(131072);       // 16nc * 16kc * 2si * 64 * 4
  u16*  hA     = (u16*)alloc(65536);        // 256*512 bf16
  u16*  hB     = (u16*)alloc(65536);
  u16*  hC     = (u16*)alloc(131072);       // 512*512 bf16
  u16*  hD     = (u16*)alloc(131072);
  float* finals = alloc(262144);            // 512*512 fp32
  float* scores = alloc(51200);
  float* pooled = alloc(131072);
  float* a2     = alloc(131072);
  float* code   = alloc(131072);
  unsigned* flags = (unsigned*)alloc(4096); // 4 rg x 64 blocks x 16-u32 spacing

  // weight / embedding conversions
  conv_emb_kernel<<<(VOC * (EPAD / 2) + 255) / 256, 256, 0, stream>>>(tok_emb, (u32*)embT);
  conv_emb_kernel<<<(VOC * (EPAD / 2) + 255) / 256, 256, 0, stream>>>(desc_emb, (u32*)embD);
  conv_wfrag_kernel<1><<<2048, 256, 0, stream>>>(tok_Whh, WhhT, KC_H, Hc, 524288);
  conv_wfrag_kernel<1><<<2048, 256, 0, stream>>>(desc_Whh, WhhD, KC_H, Hc, 524288);
  conv_wfrag_kernel<1><<<1280, 256, 0, stream>>>(tok_Wih, WihT, KC_E, Ec, 327680);
  conv_wfrag_kernel<1><<<1280, 256, 0, stream>>>(desc_Wih, WihD, KC_E, Ec, 327680);
  conv_wfrag_kernel<0><<<512, 256, 0, stream>>>(attn_W, attnWF, KC_H, Hc, 131072);
  zero_kernel<<<16, 256, 0, stream>>>((float*)flags, 4096);

  PArgs A;
  A.WhhT = WhhT; A.WihT = WihT; A.embT = embT;
  A.WhhD = WhhD; A.WihD = WihD; A.embD = embD;
  A.tokens = tokens; A.desc_anchor = desc_anchor; A.desc_neg = desc_neg;
  A.desc_anchor_len = desc_anchor_len; A.desc_neg_len = desc_neg_len;
  A.tok_bih = tok_bih; A.tok_bhh = tok_bhh;
  A.desc_bih = desc_bih; A.desc_bhh = desc_bhh;
  A.hA = hA; A.hB = hB; A.hC = hC; A.hD = hD;
  A.featB = featB; A.finals = finals; A.flags = flags;
  lstm_persist_kernel<<<256, 256, 0, stream>>>(A);

  attn_scores_mfma<<<(BATCH * TCc) / 64, 256, 0, stream>>>(
      featB, attnWF, attn_b, attnS_W, attnS_b, scores);
  softmax_pool_kernel<<<BATCH, 256, 0, stream>>>(scores, tok_len, featB, pooled);
  gemm_bias_tanh_kernel<<<dim3(BATCH / 64, Hc / 64), 256, 0, stream>>>(
      pooled, out_W1, out_b1, a2, BATCH, Hc, Hc);
  gemm_bias_tanh_kernel<<<dim3(BATCH / 64, Hc / 64), 256, 0, stream>>>(
      a2, out_W2, out_b2, code, BATCH, Hc, Hc);
  loss_kernel<<<1, 256, 0, stream>>>(code, finals, (float*)d_out);
}

// Round 7
// 3514.672 us; speedup vs baseline: 4.2148x; 2.5721x over previous
//
#include <hip/hip_runtime.h>
#include <hip/hip_bf16.h>
#include <math.h>

#define TCc 200
#define TDc 50
#define BATCH 256
#define Ec 300
#define Hc 512
#define VOC 10000
#define EPAD 320
#define KC_E 10
#define KC_H 16

typedef unsigned short u16;
typedef unsigned int u32;
typedef __bf16 bf16x8 __attribute__((ext_vector_type(8)));
typedef float f32x4 __attribute__((ext_vector_type(4)));

__device__ __forceinline__ float sigf(float x) { return 1.f / (1.f + expf(-x)); }

__device__ __forceinline__ u16 f2bf(float f) {
  unsigned u = __float_as_uint(f);
  unsigned r = (u + 0x7FFFu + ((u >> 16) & 1u)) >> 16;  // RNE
  return (u16)r;
}
__device__ __forceinline__ float bf2f(u16 v) { return __uint_as_float(((unsigned)v) << 16); }

// LLC-coherent (sc1) access: relaxed agent-scope atomics — no cache maintenance ops.
__device__ __forceinline__ void st_llc(u32* p, u32 v) {
  __hip_atomic_store(p, v, __ATOMIC_RELAXED, __HIP_MEMORY_SCOPE_AGENT);
}
__device__ __forceinline__ u32 ld_llc(const u32* p) {
  return __hip_atomic_load(p, __ATOMIC_RELAXED, __HIP_MEMORY_SCOPE_AGENT);
}
__device__ __forceinline__ bf16x8 ld_h8(const u32* p) {
  union { u32 w[4]; bf16x8 v; } t;
  t.w[0] = ld_llc(p + 0);
  t.w[1] = ld_llc(p + 1);
  t.w[2] = ld_llc(p + 2);
  t.w[3] = ld_llc(p + 3);
  return t.v;
}

__global__ __launch_bounds__(256) void zero_kernel(float* p, int n) {
  int i = blockIdx.x * 256 + threadIdx.x;
  if (i < n) p[i] = 0.f;
}

// emb (VOC, Ec) fp32 -> (VOC, EPAD) bf16, zero-padded
__global__ __launch_bounds__(256) void conv_emb_kernel(
    const float* __restrict__ emb, u32* __restrict__ out)
{
  int e = blockIdx.x * 256 + threadIdx.x;          // u32 index, VOC*EPAD/2 total
  if (e >= VOC * (EPAD / 2)) return;
  int v = e / (EPAD / 2);
  int k = (e - v * (EPAD / 2)) * 2;
  float a = (k < Ec) ? emb[(size_t)v * Ec + k] : 0.f;
  float b = (k + 1 < Ec) ? emb[(size_t)v * Ec + k + 1] : 0.f;
  out[e] = (u32)f2bf(a) | ((u32)f2bf(b) << 16);
}

// Weight (rows x K) fp32 -> MFMA B-fragment order bf16.
// Frag layout: [nc][kc][si][lane 64][8 bf16]; col-in-group c32 = si*16 + (lane&15);
// k = kc*32 + (lane>>4)*8 + jj.
// GATES: position ul'=c32>>2, g=c32&3; actual unit = ((ul'&3)<<1)|(ul'>>2); source row
// = g*512 + nc*8 + unit. Else: source row = nc*32 + c32.
template<int GATES>
__global__ __launch_bounds__(256) void conv_wfrag_kernel(
    const float* __restrict__ W, u32* __restrict__ out, int KC, int KREAL, int total)
{
  int e = blockIdx.x * 256 + threadIdx.x;          // u32 index
  if (e >= total) return;
  int jp = e & 3;
  int l = (e >> 2) & 63;
  int si = (e >> 8) & 1;
  int t2 = e >> 9;
  int kc = t2 % KC;
  int nc = t2 / KC;
  int c32 = (si << 4) + (l & 15);
  int srow;
  if (GATES) {
    int ulp = c32 >> 2, g = c32 & 3;
    int unit = ((ulp & 3) << 1) | (ulp >> 2);
    srow = (g << 9) + nc * 8 + unit;
  } else {
    srow = nc * 32 + c32;
  }
  int k = (kc << 5) + ((l >> 4) << 3) + (jp << 1);
  float a = (k < KREAL) ? W[(size_t)srow * KREAL + k] : 0.f;
  float b = (k + 1 < KREAL) ? W[(size_t)srow * KREAL + k + 1] : 0.f;
  out[e] = (u32)f2bf(a) | ((u32)f2bf(b) << 16);
}

// ---------------- persistent MFMA LSTM, LLC flag barrier (no fences) ----------------
// Each block: s_waitcnt vmcnt(0) (own h stores at LLC), syncthreads, release own flag
// slot (relaxed sc1), lane l<64 polls flag slot l (relaxed sc1), syncthreads.
__device__ __forceinline__ void group_barrier(u32* flags, int cg, u32 gen) {
  asm volatile("s_waitcnt vmcnt(0)" ::: "memory");
  __syncthreads();
  if (threadIdx.x == 0) st_llc(flags + (cg << 4), gen);
  if (threadIdx.x < 64) {
    while (ld_llc(flags + ((int)threadIdx.x << 4)) < gen)
      __builtin_amdgcn_s_sleep(1);
  }
  __syncthreads();
}

struct PArgs {
  const u32* WhhT; const u32* WihT; const u16* embT;
  const u32* WhhD; const u32* WihD; const u16* embD;
  const int* tokens; const int* desc_anchor; const int* desc_neg;
  const int* desc_anchor_len; const int* desc_neg_len;
  const float* tok_bih; const float* tok_bhh;
  const float* desc_bih; const float* desc_bhh;
  u16* hA; u16* hB; u16* hC; u16* hD;
  u16* featB; float* finals;
  u32* flags;
};

// 256 blocks = 4 rowgroups x 64 colgroups (8 units = 32 gate-cols each).
// ROWS=64 (tok) / 128 (desc). RPW = ROWS/64 row-halves per wave.
template<int ROWS, bool IS_TOK>
__device__ void lstm_phase(
    u16* WhF, u16* WiF, float* gsum, int* idsL,
    const u32* __restrict__ WhhF, const u32* __restrict__ WihF, const u16* __restrict__ embB,
    const int* __restrict__ idsA, const int* __restrict__ idsB,
    const int* __restrict__ lenA, const int* __restrict__ lenB,
    const float* __restrict__ bih, const float* __restrict__ bhh,
    u16* __restrict__ h0, u16* __restrict__ h1,
    u16* __restrict__ featB, float* __restrict__ finals,
    u32* flrg, int& gen, int T)
{
  constexpr int RPW = ROWS / 64;
  const int tid = threadIdx.x;
  const int cg = blockIdx.x & 63;
  const int row0 = (blockIdx.x >> 6) * ROWS;
  const int w = tid >> 6, l = tid & 63;
  const int rl = tid >> 2, u = tid & 3;

  // stage weight fragments into LDS
  {
    const uint4* s = (const uint4*)(WhhF + ((size_t)cg << 13));   // cg*8192 u32
    uint4* d = (uint4*)WhF;
    #pragma unroll
    for (int i = 0; i < 8; ++i) d[(i << 8) + tid] = s[(i << 8) + tid];
    const uint4* s2 = (const uint4*)(WihF + (size_t)cg * 5120);
    uint4* d2 = (uint4*)WiF;
    #pragma unroll
    for (int i = 0; i < 5; ++i) d2[(i << 8) + tid] = s2[(i << 8) + tid];
  }

  // units owned by this epilogue thread: ug0 = cg*8 + 2u, ug1 = ug0+1 (adjacent)
  float bsv[2][4];
  #pragma unroll
  for (int uu = 0; uu < 2; ++uu)
    #pragma unroll
    for (int g = 0; g < 4; ++g) {
      int ug = (cg << 3) + (u << 1) + uu;
      bsv[uu][g] = bih[(g << 9) + ug] + bhh[(g << 9) + ug];
    }

  float cc[RPW][2];
  int lens[RPW];
  #pragma unroll
  for (int p = 0; p < RPW; ++p) {
    cc[p][0] = 0.f; cc[p][1] = 0.f;
    int row = row0 + (p << 6) + rl;
    lens[p] = IS_TOK ? 0 : ((row < BATCH) ? lenA[row] : lenB[row - BATCH]);
    st_llc((u32*)(h0 + ((size_t)row << 9) + (cg << 3) + (u << 1)), 0u);
  }
  ++gen; group_barrier(flrg, cg, (u32)gen);

  for (int t = 0; t < T; ++t) {
    const u16* hin = (t & 1) ? h1 : h0;
    u16* hout = (t & 1) ? h0 : h1;

    if (tid < ROWS) {
      int row = row0 + tid;
      idsL[tid] = IS_TOK ? idsA[row * T + t]
                         : ((row < BATCH) ? idsA[row * T + t] : idsB[(row - BATCH) * T + t]);
    }
    __syncthreads();

    f32x4 acc[RPW][2];
    #pragma unroll
    for (int p = 0; p < RPW; ++p) {
      acc[p][0] = (f32x4){0.f, 0.f, 0.f, 0.f};
      acc[p][1] = (f32x4){0.f, 0.f, 0.f, 0.f};
    }
    const u16* eb[RPW];
    const u32* hb[RPW];
    #pragma unroll
    for (int p = 0; p < RPW; ++p) {
      int rhp = w + (p << 2);
      int ida = idsL[(rhp << 4) + (l & 15)];
      eb[p] = embB + (size_t)ida * EPAD + ((l >> 4) << 3);
      hb[p] = (const u32*)(hin + (((size_t)(row0 + (rhp << 4) + (l & 15))) << 9)
                               + ((l >> 4) << 3));
    }
    #pragma unroll 2
    for (int kc = 0; kc < KC_E; ++kc) {
      bf16x8 b0 = *(const bf16x8*)(WiF + ((((kc << 1) | 0) << 6 | l) << 3));
      bf16x8 b1 = *(const bf16x8*)(WiF + ((((kc << 1) | 1) << 6 | l) << 3));
      #pragma unroll
      for (int p = 0; p < RPW; ++p) {
        bf16x8 a = *(const bf16x8*)(eb[p] + (kc << 5));
        acc[p][0] = __builtin_amdgcn_mfma_f32_16x16x32_bf16(a, b0, acc[p][0], 0, 0, 0);
        acc[p][1] = __builtin_amdgcn_mfma_f32_16x16x32_bf16(a, b1, acc[p][1], 0, 0, 0);
      }
    }
    #pragma unroll 4
    for (int kc = 0; kc < KC_H; ++kc) {
      bf16x8 b0 = *(const bf16x8*)(WhF + ((((kc << 1) | 0) << 6 | l) << 3));
      bf16x8 b1 = *(const bf16x8*)(WhF + ((((kc << 1) | 1) << 6 | l) << 3));
      #pragma unroll
      for (int p = 0; p < RPW; ++p) {
        bf16x8 a = ld_h8(hb[p] + (kc << 4));   // 4x relaxed sc1 dword loads
        acc[p][0] = __builtin_amdgcn_mfma_f32_16x16x32_bf16(a, b0, acc[p][0], 0, 0, 0);
        acc[p][1] = __builtin_amdgcn_mfma_f32_16x16x32_bf16(a, b1, acc[p][1], 0, 0, 0);
      }
    }

    #pragma unroll
    for (int p = 0; p < RPW; ++p) {
      int lr0 = (w << 4) + ((l >> 4) << 2);
      #pragma unroll
      for (int si = 0; si < 2; ++si)
        #pragma unroll
        for (int j = 0; j < 4; ++j)
          gsum[(lr0 + j) * 36 + (si << 4) + (l & 15)] = acc[p][si][j];
      __syncthreads();
      {
        float4 g0 = *(const float4*)&gsum[rl * 36 + (u << 2)];          // unit 2u
        float4 g1 = *(const float4*)&gsum[rl * 36 + ((u + 4) << 2)];    // unit 2u+1
        int row = row0 + (p << 6) + rl;
        float gi0 = sigf(g0.x + bsv[0][0]);
        float gf0 = sigf(g0.y + bsv[0][1]);
        float gg0 = tanhf(g0.z + bsv[0][2]);
        float go0 = sigf(g0.w + bsv[0][3]);
        float cn0 = gf0 * cc[p][0] + gi0 * gg0;
        cc[p][0] = cn0;
        float hn0 = go0 * tanhf(cn0);
        float gi1 = sigf(g1.x + bsv[1][0]);
        float gf1 = sigf(g1.y + bsv[1][1]);
        float gg1 = tanhf(g1.z + bsv[1][2]);
        float go1 = sigf(g1.w + bsv[1][3]);
        float cn1 = gf1 * cc[p][1] + gi1 * gg1;
        cc[p][1] = cn1;
        float hn1 = go1 * tanhf(cn1);
        int ug0 = (cg << 3) + (u << 1);
        st_llc((u32*)(hout + ((size_t)row << 9) + ug0),
               (u32)f2bf(hn0) | ((u32)f2bf(hn1) << 16));
        if (IS_TOK) {
          size_t fo = ((size_t)row * TCc + t) << 9;
          *(u32*)(featB + fo + ug0) =
              (u32)f2bf(tanhf(hn0)) | ((u32)f2bf(tanhf(hn1)) << 16);
        } else if (t == lens[p] - 1) {
          finals[((size_t)row << 9) + ug0]     = tanhf(hn0);
          finals[((size_t)row << 9) + ug0 + 1] = tanhf(hn1);
        }
      }
      __syncthreads();
    }
    ++gen; group_barrier(flrg, cg, (u32)gen);
  }
}

__global__ void __launch_bounds__(256, 1) lstm_persist_kernel(PArgs A) {
  __shared__ __align__(16) u16 WhF[KC_H * 2 * 64 * 8];   // 32768 B
  __shared__ __align__(16) u16 WiF[KC_E * 2 * 64 * 8];   // 20480 B
  __shared__ __align__(16) float gsum[64 * 36];          // 9216 B
  __shared__ int idsL[128];                              // 512 B
  u32* flrg = A.flags + ((blockIdx.x >> 6) << 10);       // rowgroup flag region
  int gen = 0;
  lstm_phase<64, true>(WhF, WiF, gsum, idsL, A.WhhT, A.WihT, A.embT,
                       A.tokens, nullptr, nullptr, nullptr,
                       A.tok_bih, A.tok_bhh, A.hA, A.hB, A.featB, nullptr,
                       flrg, gen, TCc);
  lstm_phase<128, false>(WhF, WiF, gsum, idsL, A.WhhD, A.WihD, A.embD,
                         A.desc_anchor, A.desc_neg, A.desc_anchor_len, A.desc_neg_len,
                         A.desc_bih, A.desc_bhh, A.hC, A.hD, nullptr, A.finals,
                         flrg, gen, TDc);
}

// ---------------- attention scores via MFMA ----------------
__global__ __launch_bounds__(256) void attn_scores_mfma(
    const u16* __restrict__ featB, const u32* __restrict__ WF,
    const float* __restrict__ attn_b, const float* __restrict__ attnS_W,
    const float* __restrict__ attnS_b, float* __restrict__ scores)
{
  __shared__ __align__(16) u16 Af[4 * 16 * 64 * 8];   // 65536 B (reused as red after)
  const int tid = threadIdx.x;
  const int m0 = blockIdx.x * 64;

  #pragma unroll
  for (int i = 0; i < 16; ++i) {
    int c = (i << 8) + tid;
    int r = c >> 6, kb = c & 63;
    uint4 v = *(const uint4*)(featB + (((size_t)(m0 + r)) << 9) + (kb << 3));
    int kc = kb >> 2, lf = (r & 15) + ((kb & 3) << 4);
    *(uint4*)(Af + ((((r >> 4) * 16 + kc) << 6 | lf) << 3)) = v;
  }
  __syncthreads();

  const int w = tid >> 6, l = tid & 63;
  const u16* WF16 = (const u16*)WF;
  float p[4][4] = {};
  for (int nc = w * 4; nc < w * 4 + 4; ++nc) {
    f32x4 acc[4][2];
    #pragma unroll
    for (int rh = 0; rh < 4; ++rh) {
      acc[rh][0] = (f32x4){0.f, 0.f, 0.f, 0.f};
      acc[rh][1] = (f32x4){0.f, 0.f, 0.f, 0.f};
    }
    #pragma unroll 4
    for (int kc = 0; kc < 16; ++kc) {
      bf16x8 b0 = *(const bf16x8*)(WF16 + ((size_t)((((nc << 4) + kc) << 1 | 0) << 6 | l) << 3));
      bf16x8 b1 = *(const bf16x8*)(WF16 + ((size_t)((((nc << 4) + kc) << 1 | 1) << 6 | l) << 3));
      #pragma unroll
      for (int rh = 0; rh < 4; ++rh) {
        bf16x8 a = *(const bf16x8*)(Af + (((rh * 16 + kc) << 6 | l) << 3));
        acc[rh][0] = __builtin_amdgcn_mfma_f32_16x16x32_bf16(a, b0, acc[rh][0], 0, 0, 0);
        acc[rh][1] = __builtin_amdgcn_mfma_f32_16x16x32_bf16(a, b1, acc[rh][1], 0, 0, 0);
      }
    }
    int c0 = (nc << 5) + (l & 15), c1 = c0 + 16;
    float bb0 = attn_b[c0], sw0 = attnS_W[c0];
    float bb1 = attn_b[c1], sw1 = attnS_W[c1];
    #pragma unroll
    for (int rh = 0; rh < 4; ++rh)
      #pragma unroll
      for (int j = 0; j < 4; ++j)
        p[rh][j] += tanhf(acc[rh][0][j] + bb0) * sw0 + tanhf(acc[rh][1][j] + bb1) * sw1;
  }
  __syncthreads();
  float* red = (float*)Af;   // 64 x 68
  #pragma unroll
  for (int rh = 0; rh < 4; ++rh)
    #pragma unroll
    for (int j = 0; j < 4; ++j)
      red[(rh * 16 + ((l >> 4) << 2) + j) * 68 + (w << 4) + (l & 15)] = p[rh][j];
  __syncthreads();
  if (tid < 64) {
    float s = attnS_b[0];
    #pragma unroll 8
    for (int q = 0; q < 64; ++q) s += red[tid * 68 + q];
    scores[m0 + tid] = s;
  }
}

// masked softmax over T=200 + weighted pooling of bf16 feat -> pooled (B,H) fp32
__global__ __launch_bounds__(256) void softmax_pool_kernel(
    const float* __restrict__ scores, const int* __restrict__ tok_len,
    const u16* __restrict__ featB, float* __restrict__ pooled)
{
  const int b = blockIdx.x;
  const int tid = threadIdx.x;
  __shared__ float wgt[TCc];
  __shared__ float red[256];
  const int len = tok_len[b];

  float myv = -1e30f;
  if (tid < TCc) {
    float s = scores[b * TCc + tid];
    myv = (tid < len) ? s : -1e9f;
    wgt[tid] = myv;
  }
  red[tid] = myv;
  __syncthreads();
  for (int s = 128; s > 0; s >>= 1) {
    if (tid < s) red[tid] = fmaxf(red[tid], red[tid + s]);
    __syncthreads();
  }
  const float mx = red[0];
  __syncthreads();
  float e = 0.f;
  if (tid < TCc) e = expf(wgt[tid] - mx);
  red[tid] = e;
  __syncthreads();
  for (int s = 128; s > 0; s >>= 1) {
    if (tid < s) red[tid] += red[tid + s];
    __syncthreads();
  }
  const float sum = red[0];
  __syncthreads();
  if (tid < TCc) wgt[tid] = e / sum;
  __syncthreads();

  const u32* featU = (const u32*)featB;
  float a0 = 0.f, a1 = 0.f;
  for (int t = 0; t < TCc; ++t) {
    u32 v = featU[((size_t)b * TCc + t) * 256 + tid];
    float wv = wgt[t];
    a0 = fmaf(wv, bf2f((u16)(v & 0xFFFF)), a0);
    a1 = fmaf(wv, bf2f((u16)(v >> 16)), a1);
  }
  pooled[((size_t)b << 9) + tid * 2] = a0;
  pooled[((size_t)b << 9) + tid * 2 + 1] = a1;
}

// C[m,n] = tanh(A[m,:] . W[n,:] + bias[n]); fp32, grid (M/64, N/64)
__global__ __launch_bounds__(256) void gemm_bias_tanh_kernel(
    const float* __restrict__ A, const float* __restrict__ Bw,
    const float* __restrict__ bias, float* __restrict__ C, int M, int N, int K)
{
  const int r0 = blockIdx.x * 64;
  const int n0 = blockIdx.y * 64;
  const int tid = threadIdx.x;
  const int tu = tid & 15;
  const int tm = tid >> 4;
  __shared__ float As[32][68];
  __shared__ float Bs[32][68];

  float acc[4][4] = {};
  for (int k0 = 0; k0 < K; k0 += 32) {
    #pragma unroll
    for (int i = 0; i < 2; ++i) {
      int lin = tid + (i << 8);
      int kq = lin & 7, m = lin >> 3;
      int k = k0 + (kq << 2);
      int r = r0 + m; if (r >= M) r = M - 1;
      float4 va = *(const float4*)&A[(size_t)r * K + k];
      float4 vb = *(const float4*)&Bw[(size_t)(n0 + m) * K + k];
      As[(kq << 2) + 0][m] = va.x; As[(kq << 2) + 1][m] = va.y;
      As[(kq << 2) + 2][m] = va.z; As[(kq << 2) + 3][m] = va.w;
      Bs[(kq << 2) + 0][m] = vb.x; Bs[(kq << 2) + 1][m] = vb.y;
      Bs[(kq << 2) + 2][m] = vb.z; Bs[(kq << 2) + 3][m] = vb.w;
    }
    __syncthreads();
    #pragma unroll
    for (int kk = 0; kk < 32; ++kk) {
      float4 a = *(const float4*)&As[kk][tm << 2];
      float4 b = *(const float4*)&Bs[kk][tu << 2];
      acc[0][0] = fmaf(a.x, b.x, acc[0][0]); acc[0][1] = fmaf(a.x, b.y, acc[0][1]);
      acc[0][2] = fmaf(a.x, b.z, acc[0][2]); acc[0][3] = fmaf(a.x, b.w, acc[0][3]);
      acc[1][0] = fmaf(a.y, b.x, acc[1][0]); acc[1][1] = fmaf(a.y, b.y, acc[1][1]);
      acc[1][2] = fmaf(a.y, b.z, acc[1][2]); acc[1][3] = fmaf(a.y, b.w, acc[1][3]);
      acc[2][0] = fmaf(a.z, b.x, acc[2][0]); acc[2][1] = fmaf(a.z, b.y, acc[2][1]);
      acc[2][2] = fmaf(a.z, b.z, acc[2][2]); acc[2][3] = fmaf(a.z, b.w, acc[2][3]);
      acc[3][0] = fmaf(a.w, b.x, acc[3][0]); acc[3][1] = fmaf(a.w, b.y, acc[3][1]);
      acc[3][2] = fmaf(a.w, b.z, acc[3][2]); acc[3][3] = fmaf(a.w, b.w, acc[3][3]);
    }
    __syncthreads();
  }
  float bj[4];
  #pragma unroll
  for (int j = 0; j < 4; ++j) bj[j] = bias[n0 + (tu << 2) + j];
  #pragma unroll
  for (int i = 0; i < 4; ++i) {
    int r = r0 + (tm << 2) + i;
    if (r < M) {
      float4 v;
      v.x = tanhf(acc[i][0] + bj[0]); v.y = tanhf(acc[i][1] + bj[1]);
      v.z = tanhf(acc[i][2] + bj[2]); v.w = tanhf(acc[i][3] + bj[3]);
      *(float4*)&C[(size_t)r * N + n0 + (tu << 2)] = v;
    }
  }
}

__global__ __launch_bounds__(256) void loss_kernel(
    const float* __restrict__ code, const float* __restrict__ finals, float* __restrict__ out)
{
  const int b = threadIdx.x;
  const float* cv = code + (size_t)b * Hc;
  const float* av = finals + (size_t)b * Hc;
  const float* nv = finals + (size_t)(BATCH + b) * Hc;
  float dca = 0, dcn = 0, ncc = 0, naa = 0, nnn = 0;
  for (int k = 0; k < Hc; ++k) {
    float c = cv[k], a = av[k], n = nv[k];
    dca = fmaf(c, a, dca);
    dcn = fmaf(c, n, dcn);
    ncc = fmaf(c, c, ncc);
    naa = fmaf(a, a, naa);
    nnn = fmaf(n, n, nnn);
  }
  float cos_a = dca / fmaxf(sqrtf(ncc) * sqrtf(naa), 1e-8f);
  float cos_n = dcn / fmaxf(sqrtf(ncc) * sqrtf(nnn), 1e-8f);
  float hinge = fmaxf(0.6f - cos_a + cos_n, 1e-6f);
  __shared__ float red[256];
  red[b] = hinge;
  __syncthreads();
  for (int s = 128; s > 0; s >>= 1) {
    if (b < s) red[b] += red[b + s];
    __syncthreads();
  }
  if (b == 0) out[0] = red[0] / 256.0f;
}

extern "C" void kernel_launch(void* const* d_in, const int* in_sizes, int n_in,
                              void* d_out, int out_size, void* d_ws, size_t ws_size,
                              hipStream_t stream) {
  const int* tokens          = (const int*)d_in[0];
  const int* tok_len         = (const int*)d_in[1];
  const int* desc_anchor     = (const int*)d_in[2];
  const int* desc_anchor_len = (const int*)d_in[3];
  const int* desc_neg        = (const int*)d_in[4];
  const int* desc_neg_len    = (const int*)d_in[5];
  const float* tok_emb  = (const float*)d_in[6];
  const float* tok_Wih  = (const float*)d_in[7];
  const float* tok_Whh  = (const float*)d_in[8];
  const float* tok_bih  = (const float*)d_in[9];
  const float* tok_bhh  = (const float*)d_in[10];
  const float* desc_emb = (const float*)d_in[11];
  const float* desc_Wih = (const float*)d_in[12];
  const float* desc_Whh = (const float*)d_in[13];
  const float* desc_bih = (const float*)d_in[14];
  const float* desc_bhh = (const float*)d_in[15];
  const float* attn_W   = (const float*)d_in[16];
  const float* attn_b   = (const float*)d_in[17];
  const float* attnS_W  = (const float*)d_in[18];
  const float* attnS_b  = (const float*)d_in[19];
  const float* out_W1   = (const float*)d_in[20];
  const float* out_b1   = (const float*)d_in[21];
  const float* out_W2   = (const float*)d_in[22];
  const float* out_b2   = (const float*)d_in[23];

  float* p = (float*)d_ws;
  size_t off = 0;
  auto alloc = [&](size_t n) { float* q = p + off; off += n; return q; };

  u16*  featB  = (u16*)alloc(13107200);     // 256*200*512 bf16
  u16*  embT   = (u16*)alloc(1600000);      // VOC*320 bf16
  u16*  embD   = (u16*)alloc(1600000);
  u32*  WihT   = (u32*)alloc(327680);       // 64nc * 10kc * 2si * 64 * 4
  u32*  WihD   = (u32*)alloc(327680);
  u32*  WhhT   = (u32*)alloc(524288);       // 64nc * 16kc * 2si * 64 * 4
  u32*  WhhD   = (u32*)alloc(524288);
  u32*  attnWF = (u32*)alloc(131072);       // 16nc * 16kc * 2si * 64 * 4
  u16*  hA     = (u16*)alloc(65536);        // 256*512 bf16
  u16*  hB     = (u16*)alloc(65536);
  u16*  hC     = (u16*)alloc(131072);       // 512*512 bf16
  u16*  hD     = (u16*)alloc(131072);
  float* finals = alloc(262144);            // 512*512 fp32
  float* scores = alloc(51200);
  float* pooled = alloc(131072);
  float* a2     = alloc(131072);
  float* code   = alloc(131072);
  u32* flags = (u32*)alloc(4096);           // 4 rg x 64 blocks x 16-u32 spacing

  // weight / embedding conversions
  conv_emb_kernel<<<(VOC * (EPAD / 2) + 255) / 256, 256, 0, stream>>>(tok_emb, (u32*)embT);
  conv_emb_kernel<<<(VOC * (EPAD / 2) + 255) / 256, 256, 0, stream>>>(desc_emb, (u32*)embD);
  conv_wfrag_kernel<1><<<2048, 256, 0, stream>>>(tok_Whh, WhhT, KC_H, Hc, 524288);
  conv_wfrag_kernel<1><<<2048, 256, 0, stream>>>(desc_Whh, WhhD, KC_H, Hc, 524288);
  conv_wfrag_kernel<1><<<1280, 256, 0, stream>>>(tok_Wih, WihT, KC_E, Ec, 327680);
  conv_wfrag_kernel<1><<<1280, 256, 0, stream>>>(desc_Wih, WihD, KC_E, Ec, 327680);
  conv_wfrag_kernel<0><<<512, 256, 0, stream>>>(attn_W, attnWF, KC_H, Hc, 131072);
  zero_kernel<<<16, 256, 0, stream>>>((float*)flags, 4096);

  PArgs A;
  A.WhhT = WhhT; A.WihT = WihT; A.embT = embT;
  A.WhhD = WhhD; A.WihD = WihD; A.embD = embD;
  A.tokens = tokens; A.desc_anchor = desc_anchor; A.desc_neg = desc_neg;
  A.desc_anchor_len = desc_anchor_len; A.desc_neg_len = desc_neg_len;
  A.tok_bih = tok_bih; A.tok_bhh = tok_bhh;
  A.desc_bih = desc_bih; A.desc_bhh = desc_bhh;
  A.hA = hA; A.hB = hB; A.hC = hC; A.hD = hD;
  A.featB = featB; A.finals = finals; A.flags = flags;
  lstm_persist_kernel<<<256, 256, 0, stream>>>(A);

  attn_scores_mfma<<<(BATCH * TCc) / 64, 256, 0, stream>>>(
      featB, attnWF, attn_b, attnS_W, attnS_b, scores);
  softmax_pool_kernel<<<BATCH, 256, 0, stream>>>(scores, tok_len, featB, pooled);
  gemm_bias_tanh_kernel<<<dim3(BATCH / 64, Hc / 64), 256, 0, stream>>>(
      pooled, out_W1, out_b1, a2, BATCH, Hc, Hc);
  gemm_bias_tanh_kernel<<<dim3(BATCH / 64, Hc / 64), 256, 0, stream>>>(
      a2, out_W2, out_b2, code, BATCH, Hc, Hc);
  loss_kernel<<<1, 256, 0, stream>>>(code, finals, (float*)d_out);
}

// Round 9
// 2602.327 us; speedup vs baseline: 5.6924x; 1.3506x over previous
//
#include <hip/hip_runtime.h>
#include <hip/hip_bf16.h>
#include <math.h>

#define TCc 200
#define TDc 50
#define BATCH 256
#define Ec 300
#define Hc 512
#define VOC 10000
#define EPAD 320
#define KC_E 10
#define KC_H 16

typedef unsigned short u16;
typedef unsigned int u32;
typedef unsigned long long u64;
typedef __bf16 bf16x8 __attribute__((ext_vector_type(8)));
typedef float f32x4 __attribute__((ext_vector_type(4)));

__device__ __forceinline__ float sigf(float x) { return 1.f / (1.f + expf(-x)); }

__device__ __forceinline__ u16 f2bf(float f) {
  unsigned u = __float_as_uint(f);
  unsigned r = (u + 0x7FFFu + ((u >> 16) & 1u)) >> 16;  // RNE
  return (u16)r;
}
__device__ __forceinline__ float bf2f(u16 v) { return __uint_as_float(((unsigned)v) << 16); }

// LLC-coherent access: relaxed agent-scope atomics — bare sc1 ops, no cache maintenance.
__device__ __forceinline__ void st_llc(u32* p, u32 v) {
  __hip_atomic_store(p, v, __ATOMIC_RELAXED, __HIP_MEMORY_SCOPE_AGENT);
}
__device__ __forceinline__ u32 ld_llc(const u32* p) {
  return __hip_atomic_load(p, __ATOMIC_RELAXED, __HIP_MEMORY_SCOPE_AGENT);
}
__device__ __forceinline__ u64 ld_llc64(const u64* p) {
  return __hip_atomic_load(p, __ATOMIC_RELAXED, __HIP_MEMORY_SCOPE_AGENT);
}
__device__ __forceinline__ bf16x8 pair_bf16x8(u64 a, u64 b) {
  union { u64 q[2]; bf16x8 v; } t; t.q[0] = a; t.q[1] = b; return t.v;
}

__global__ __launch_bounds__(256) void zero_kernel(float* p, int n) {
  int i = blockIdx.x * 256 + threadIdx.x;
  if (i < n) p[i] = 0.f;
}

// emb (VOC, Ec) fp32 -> (VOC, EPAD) bf16, zero-padded
__global__ __launch_bounds__(256) void conv_emb_kernel(
    const float* __restrict__ emb, u32* __restrict__ out)
{
  int e = blockIdx.x * 256 + threadIdx.x;          // u32 index, VOC*EPAD/2 total
  if (e >= VOC * (EPAD / 2)) return;
  int v = e / (EPAD / 2);
  int k = (e - v * (EPAD / 2)) * 2;
  float a = (k < Ec) ? emb[(size_t)v * Ec + k] : 0.f;
  float b = (k + 1 < Ec) ? emb[(size_t)v * Ec + k + 1] : 0.f;
  out[e] = (u32)f2bf(a) | ((u32)f2bf(b) << 16);
}

// Weight (rows x K) fp32 -> MFMA B-fragment order bf16.
// Frag layout: [nc][kc][si][lane 64][8 bf16]; col-in-group c32 = si*16 + (lane&15);
// k = kc*32 + (lane>>4)*8 + jj.
// GATES: position ul'=c32>>2, g=c32&3; actual unit = ((ul'&3)<<1)|(ul'>>2); source row
// = g*512 + nc*8 + unit. Else: source row = nc*32 + c32.
template<int GATES>
__global__ __launch_bounds__(256) void conv_wfrag_kernel(
    const float* __restrict__ W, u32* __restrict__ out, int KC, int KREAL, int total)
{
  int e = blockIdx.x * 256 + threadIdx.x;          // u32 index
  if (e >= total) return;
  int jp = e & 3;
  int l = (e >> 2) & 63;
  int si = (e >> 8) & 1;
  int t2 = e >> 9;
  int kc = t2 % KC;
  int nc = t2 / KC;
  int c32 = (si << 4) + (l & 15);
  int srow;
  if (GATES) {
    int ulp = c32 >> 2, g = c32 & 3;
    int unit = ((ulp & 3) << 1) | (ulp >> 2);
    srow = (g << 9) + nc * 8 + unit;
  } else {
    srow = nc * 32 + c32;
  }
  int k = (kc << 5) + ((l >> 4) << 3) + (jp << 1);
  float a = (k < KREAL) ? W[(size_t)srow * KREAL + k] : 0.f;
  float b = (k + 1 < KREAL) ? W[(size_t)srow * KREAL + k + 1] : 0.f;
  out[e] = (u32)f2bf(a) | ((u32)f2bf(b) << 16);
}

// ---------------- persistent MFMA LSTM ----------------
// Barrier: single monotonic counter per rowgroup (own cacheline). vmcnt(0) drains the
// sc1 h-stores to LLC, then one relaxed fetch_add per block, lane0 polls the counter.
// Relaxed agent-scope => no L2 writeback/invalidate ops (round-5 lesson).
__device__ __forceinline__ void group_barrier(u32* cnt, u32 target) {
  asm volatile("s_waitcnt vmcnt(0)" ::: "memory");
  __syncthreads();
  if (threadIdx.x == 0) {
    __hip_atomic_fetch_add(cnt, 1u, __ATOMIC_RELAXED, __HIP_MEMORY_SCOPE_AGENT);
    while (__hip_atomic_load(cnt, __ATOMIC_RELAXED, __HIP_MEMORY_SCOPE_AGENT) < target)
      __builtin_amdgcn_s_sleep(1);
  }
  __syncthreads();
}

struct PArgs {
  const u32* WhhT; const u32* WihT; const u16* embT;
  const u32* WhhD; const u32* WihD; const u16* embD;
  const int* tokens; const int* desc_anchor; const int* desc_neg;
  const int* desc_anchor_len; const int* desc_neg_len;
  const float* tok_bih; const float* tok_bhh;
  const float* desc_bih; const float* desc_bhh;
  u16* hA; u16* hB; u16* hC; u16* hD;
  u16* featB; float* finals;
  u32* flags;
};

// 256 blocks = 4 rowgroups x 64 colgroups (8 units = 32 gate-cols each).
// ROWS=64 (tok) / 128 (desc). RPW = ROWS/64 row-halves per wave.
template<int ROWS, bool IS_TOK>
__device__ void lstm_phase(
    u16* WhF, u16* WiF, float* gsum, int* idsL,
    const u32* __restrict__ WhhF, const u32* __restrict__ WihF, const u16* __restrict__ embB,
    const int* __restrict__ idsA, const int* __restrict__ idsB,
    const int* __restrict__ lenA, const int* __restrict__ lenB,
    const float* __restrict__ bih, const float* __restrict__ bhh,
    u16* __restrict__ h0, u16* __restrict__ h1,
    u16* __restrict__ featB, float* __restrict__ finals,
    u32* cnt, int& gen, int T)
{
  constexpr int RPW = ROWS / 64;
  const int tid = threadIdx.x;
  const int cg = blockIdx.x & 63;
  const int row0 = (blockIdx.x >> 6) * ROWS;
  const int w = tid >> 6, l = tid & 63;
  const int rl = tid >> 2, u = tid & 3;

  // stage weight fragments into LDS
  {
    const uint4* s = (const uint4*)(WhhF + ((size_t)cg << 13));   // cg*8192 u32
    uint4* d = (uint4*)WhF;
    #pragma unroll
    for (int i = 0; i < 8; ++i) d[(i << 8) + tid] = s[(i << 8) + tid];
    const uint4* s2 = (const uint4*)(WihF + (size_t)cg * 5120);
    uint4* d2 = (uint4*)WiF;
    #pragma unroll
    for (int i = 0; i < 5; ++i) d2[(i << 8) + tid] = s2[(i << 8) + tid];
  }

  // units owned by this epilogue thread: ug0 = cg*8 + 2u, ug1 = ug0+1 (adjacent)
  float bsv[2][4];
  #pragma unroll
  for (int uu = 0; uu < 2; ++uu)
    #pragma unroll
    for (int g = 0; g < 4; ++g) {
      int ug = (cg << 3) + (u << 1) + uu;
      bsv[uu][g] = bih[(g << 9) + ug] + bhh[(g << 9) + ug];
    }

  float cc[RPW][2];
  int lens[RPW];
  #pragma unroll
  for (int p = 0; p < RPW; ++p) {
    cc[p][0] = 0.f; cc[p][1] = 0.f;
    int row = row0 + (p << 6) + rl;
    lens[p] = IS_TOK ? 0 : ((row < BATCH) ? lenA[row] : lenB[row - BATCH]);
    st_llc((u32*)(h0 + ((size_t)row << 9) + (cg << 3) + (u << 1)), 0u);
  }
  ++gen; group_barrier(cnt, (u32)gen * 64u);

  for (int t = 0; t < T; ++t) {
    const u16* hin = (t & 1) ? h1 : h0;
    u16* hout = (t & 1) ? h0 : h1;

    if (tid < ROWS) {
      int row = row0 + tid;
      idsL[tid] = IS_TOK ? idsA[row * T + t]
                         : ((row < BATCH) ? idsA[row * T + t] : idsB[(row - BATCH) * T + t]);
    }
    __syncthreads();

    f32x4 acc[RPW][2];
    #pragma unroll
    for (int p = 0; p < RPW; ++p) {
      acc[p][0] = (f32x4){0.f, 0.f, 0.f, 0.f};
      acc[p][1] = (f32x4){0.f, 0.f, 0.f, 0.f};
    }
    const u16* eb[RPW];
    const u64* hb[RPW];
    #pragma unroll
    for (int p = 0; p < RPW; ++p) {
      int rhp = w + (p << 2);
      int ida = idsL[(rhp << 4) + (l & 15)];
      eb[p] = embB + (size_t)ida * EPAD + ((l >> 4) << 3);
      hb[p] = (const u64*)(hin + (((size_t)(row0 + (rhp << 4) + (l & 15))) << 9)
                               + ((l >> 4) << 3));
    }

    // ---- prefetch ALL h for this step as relaxed 8B LLC loads (C-level; compiler
    // keeps them outstanding and sinks the waitcnt to first use in the h-MFMA loop) ----
    u64 hw[RPW][2 * KC_H];
    #pragma unroll
    for (int p = 0; p < RPW; ++p)
      #pragma unroll
      for (int kc = 0; kc < KC_H; ++kc) {
        hw[p][2 * kc]     = ld_llc64(hb[p] + (kc << 3));
        hw[p][2 * kc + 1] = ld_llc64(hb[p] + (kc << 3) + 1);
      }

    // ---- input-projection MFMAs (cached emb + LDS weights) hide h-load latency ----
    #pragma unroll
    for (int kc = 0; kc < KC_E; ++kc) {
      bf16x8 b0 = *(const bf16x8*)(WiF + ((((kc << 1) | 0) << 6 | l) << 3));
      bf16x8 b1 = *(const bf16x8*)(WiF + ((((kc << 1) | 1) << 6 | l) << 3));
      #pragma unroll
      for (int p = 0; p < RPW; ++p) {
        bf16x8 a = *(const bf16x8*)(eb[p] + (kc << 5));
        acc[p][0] = __builtin_amdgcn_mfma_f32_16x16x32_bf16(a, b0, acc[p][0], 0, 0, 0);
        acc[p][1] = __builtin_amdgcn_mfma_f32_16x16x32_bf16(a, b1, acc[p][1], 0, 0, 0);
      }
    }

    // ---- recurrent MFMAs from prefetched registers ----
    #pragma unroll
    for (int kc = 0; kc < KC_H; ++kc) {
      bf16x8 b0 = *(const bf16x8*)(WhF + ((((kc << 1) | 0) << 6 | l) << 3));
      bf16x8 b1 = *(const bf16x8*)(WhF + ((((kc << 1) | 1) << 6 | l) << 3));
      #pragma unroll
      for (int p = 0; p < RPW; ++p) {
        bf16x8 a = pair_bf16x8(hw[p][2 * kc], hw[p][2 * kc + 1]);
        acc[p][0] = __builtin_amdgcn_mfma_f32_16x16x32_bf16(a, b0, acc[p][0], 0, 0, 0);
        acc[p][1] = __builtin_amdgcn_mfma_f32_16x16x32_bf16(a, b1, acc[p][1], 0, 0, 0);
      }
    }

    #pragma unroll
    for (int p = 0; p < RPW; ++p) {
      int lr0 = (w << 4) + ((l >> 4) << 2);
      #pragma unroll
      for (int si = 0; si < 2; ++si)
        #pragma unroll
        for (int j = 0; j < 4; ++j)
          gsum[(lr0 + j) * 36 + (si << 4) + (l & 15)] = acc[p][si][j];
      __syncthreads();
      {
        float4 g0 = *(const float4*)&gsum[rl * 36 + (u << 2)];          // unit 2u
        float4 g1 = *(const float4*)&gsum[rl * 36 + ((u + 4) << 2)];    // unit 2u+1
        int row = row0 + (p << 6) + rl;
        float gi0 = sigf(g0.x + bsv[0][0]);
        float gf0 = sigf(g0.y + bsv[0][1]);
        float gg0 = tanhf(g0.z + bsv[0][2]);
        float go0 = sigf(g0.w + bsv[0][3]);
        float cn0 = gf0 * cc[p][0] + gi0 * gg0;
        cc[p][0] = cn0;
        float hn0 = go0 * tanhf(cn0);
        float gi1 = sigf(g1.x + bsv[1][0]);
        float gf1 = sigf(g1.y + bsv[1][1]);
        float gg1 = tanhf(g1.z + bsv[1][2]);
        float go1 = sigf(g1.w + bsv[1][3]);
        float cn1 = gf1 * cc[p][1] + gi1 * gg1;
        cc[p][1] = cn1;
        float hn1 = go1 * tanhf(cn1);
        int ug0 = (cg << 3) + (u << 1);
        st_llc((u32*)(hout + ((size_t)row << 9) + ug0),
               (u32)f2bf(hn0) | ((u32)f2bf(hn1) << 16));
        if (IS_TOK) {
          size_t fo = ((size_t)row * TCc + t) << 9;
          *(u32*)(featB + fo + ug0) =
              (u32)f2bf(tanhf(hn0)) | ((u32)f2bf(tanhf(hn1)) << 16);
        } else if (t == lens[p] - 1) {
          finals[((size_t)row << 9) + ug0]     = tanhf(hn0);
          finals[((size_t)row << 9) + ug0 + 1] = tanhf(hn1);
        }
      }
      __syncthreads();
    }
    ++gen; group_barrier(cnt, (u32)gen * 64u);
  }
}

__global__ void __launch_bounds__(256, 1) lstm_persist_kernel(PArgs A) {
  __shared__ __align__(16) u16 WhF[KC_H * 2 * 64 * 8];   // 32768 B
  __shared__ __align__(16) u16 WiF[KC_E * 2 * 64 * 8];   // 20480 B
  __shared__ __align__(16) float gsum[64 * 36];          // 9216 B
  __shared__ int idsL[128];                              // 512 B
  u32* cnt = A.flags + ((blockIdx.x >> 6) << 6);         // per-rowgroup counter, 256B apart
  int gen = 0;
  lstm_phase<64, true>(WhF, WiF, gsum, idsL, A.WhhT, A.WihT, A.embT,
                       A.tokens, nullptr, nullptr, nullptr,
                       A.tok_bih, A.tok_bhh, A.hA, A.hB, A.featB, nullptr,
                       cnt, gen, TCc);
  lstm_phase<128, false>(WhF, WiF, gsum, idsL, A.WhhD, A.WihD, A.embD,
                         A.desc_anchor, A.desc_neg, A.desc_anchor_len, A.desc_neg_len,
                         A.desc_bih, A.desc_bhh, A.hC, A.hD, nullptr, A.finals,
                         cnt, gen, TDc);
}

// ---------------- attention scores via MFMA ----------------
__global__ __launch_bounds__(256) void attn_scores_mfma(
    const u16* __restrict__ featB, const u32* __restrict__ WF,
    const float* __restrict__ attn_b, const float* __restrict__ attnS_W,
    const float* __restrict__ attnS_b, float* __restrict__ scores)
{
  __shared__ __align__(16) u16 Af[4 * 16 * 64 * 8];   // 65536 B (reused as red after)
  const int tid = threadIdx.x;
  const int m0 = blockIdx.x * 64;

  #pragma unroll
  for (int i = 0; i < 16; ++i) {
    int c = (i << 8) + tid;
    int r = c >> 6, kb = c & 63;
    uint4 v = *(const uint4*)(featB + (((size_t)(m0 + r)) << 9) + (kb << 3));
    int kc = kb >> 2, lf = (r & 15) + ((kb & 3) << 4);
    *(uint4*)(Af + ((((r >> 4) * 16 + kc) << 6 | lf) << 3)) = v;
  }
  __syncthreads();

  const int w = tid >> 6, l = tid & 63;
  const u16* WF16 = (const u16*)WF;
  float p[4][4] = {};
  for (int nc = w * 4; nc < w * 4 + 4; ++nc) {
    f32x4 acc[4][2];
    #pragma unroll
    for (int rh = 0; rh < 4; ++rh) {
      acc[rh][0] = (f32x4){0.f, 0.f, 0.f, 0.f};
      acc[rh][1] = (f32x4){0.f, 0.f, 0.f, 0.f};
    }
    #pragma unroll 4
    for (int kc = 0; kc < 16; ++kc) {
      bf16x8 b0 = *(const bf16x8*)(WF16 + ((size_t)((((nc << 4) + kc) << 1 | 0) << 6 | l) << 3));
      bf16x8 b1 = *(const bf16x8*)(WF16 + ((size_t)((((nc << 4) + kc) << 1 | 1) << 6 | l) << 3));
      #pragma unroll
      for (int rh = 0; rh < 4; ++rh) {
        bf16x8 a = *(const bf16x8*)(Af + (((rh * 16 + kc) << 6 | l) << 3));
        acc[rh][0] = __builtin_amdgcn_mfma_f32_16x16x32_bf16(a, b0, acc[rh][0], 0, 0, 0);
        acc[rh][1] = __builtin_amdgcn_mfma_f32_16x16x32_bf16(a, b1, acc[rh][1], 0, 0, 0);
      }
    }
    int c0 = (nc << 5) + (l & 15), c1 = c0 + 16;
    float bb0 = attn_b[c0], sw0 = attnS_W[c0];
    float bb1 = attn_b[c1], sw1 = attnS_W[c1];
    #pragma unroll
    for (int rh = 0; rh < 4; ++rh)
      #pragma unroll
      for (int j = 0; j < 4; ++j)
        p[rh][j] += tanhf(acc[rh][0][j] + bb0) * sw0 + tanhf(acc[rh][1][j] + bb1) * sw1;
  }
  __syncthreads();
  float* red = (float*)Af;   // 64 x 68
  #pragma unroll
  for (int rh = 0; rh < 4; ++rh)
    #pragma unroll
    for (int j = 0; j < 4; ++j)
      red[(rh * 16 + ((l >> 4) << 2) + j) * 68 + (w << 4) + (l & 15)] = p[rh][j];
  __syncthreads();
  if (tid < 64) {
    float s = attnS_b[0];
    #pragma unroll 8
    for (int q = 0; q < 64; ++q) s += red[tid * 68 + q];
    scores[m0 + tid] = s;
  }
}

// masked softmax over T=200 + weighted pooling of bf16 feat -> pooled (B,H) fp32
__global__ __launch_bounds__(256) void softmax_pool_kernel(
    const float* __restrict__ scores, const int* __restrict__ tok_len,
    const u16* __restrict__ featB, float* __restrict__ pooled)
{
  const int b = blockIdx.x;
  const int tid = threadIdx.x;
  __shared__ float wgt[TCc];
  __shared__ float red[256];
  const int len = tok_len[b];

  float myv = -1e30f;
  if (tid < TCc) {
    float s = scores[b * TCc + tid];
    myv = (tid < len) ? s : -1e9f;
    wgt[tid] = myv;
  }
  red[tid] = myv;
  __syncthreads();
  for (int s = 128; s > 0; s >>= 1) {
    if (tid < s) red[tid] = fmaxf(red[tid], red[tid + s]);
    __syncthreads();
  }
  const float mx = red[0];
  __syncthreads();
  float e = 0.f;
  if (tid < TCc) e = expf(wgt[tid] - mx);
  red[tid] = e;
  __syncthreads();
  for (int s = 128; s > 0; s >>= 1) {
    if (tid < s) red[tid] += red[tid + s];
    __syncthreads();
  }
  const float sum = red[0];
  __syncthreads();
  if (tid < TCc) wgt[tid] = e / sum;
  __syncthreads();

  const u32* featU = (const u32*)featB;
  float a0 = 0.f, a1 = 0.f;
  for (int t = 0; t < TCc; ++t) {
    u32 v = featU[((size_t)b * TCc + t) * 256 + tid];
    float wv = wgt[t];
    a0 = fmaf(wv, bf2f((u16)(v & 0xFFFF)), a0);
    a1 = fmaf(wv, bf2f((u16)(v >> 16)), a1);
  }
  pooled[((size_t)b << 9) + tid * 2] = a0;
  pooled[((size_t)b << 9) + tid * 2 + 1] = a1;
}

// C[m,n] = tanh(A[m,:] . W[n,:] + bias[n]); fp32, grid (M/64, N/64)
__global__ __launch_bounds__(256) void gemm_bias_tanh_kernel(
    const float* __restrict__ A, const float* __restrict__ Bw,
    const float* __restrict__ bias, float* __restrict__ C, int M, int N, int K)
{
  const int r0 = blockIdx.x * 64;
  const int n0 = blockIdx.y * 64;
  const int tid = threadIdx.x;
  const int tu = tid & 15;
  const int tm = tid >> 4;
  __shared__ float As[32][68];
  __shared__ float Bs[32][68];

  float acc[4][4] = {};
  for (int k0 = 0; k0 < K; k0 += 32) {
    #pragma unroll
    for (int i = 0; i < 2; ++i) {
      int lin = tid + (i << 8);
      int kq = lin & 7, m = lin >> 3;
      int k = k0 + (kq << 2);
      int r = r0 + m; if (r >= M) r = M - 1;
      float4 va = *(const float4*)&A[(size_t)r * K + k];
      float4 vb = *(const float4*)&Bw[(size_t)(n0 + m) * K + k];
      As[(kq << 2) + 0][m] = va.x; As[(kq << 2) + 1][m] = va.y;
      As[(kq << 2) + 2][m] = va.z; As[(kq << 2) + 3][m] = va.w;
      Bs[(kq << 2) + 0][m] = vb.x; Bs[(kq << 2) + 1][m] = vb.y;
      Bs[(kq << 2) + 2][m] = vb.z; Bs[(kq << 2) + 3][m] = vb.w;
    }
    __syncthreads();
    #pragma unroll
    for (int kk = 0; kk < 32; ++kk) {
      float4 a = *(const float4*)&As[kk][tm << 2];
      float4 b = *(const float4*)&Bs[kk][tu << 2];
      acc[0][0] = fmaf(a.x, b.x, acc[0][0]); acc[0][1] = fmaf(a.x, b.y, acc[0][1]);
      acc[0][2] = fmaf(a.x, b.z, acc[0][2]); acc[0][3] = fmaf(a.x, b.w, acc[0][3]);
      acc[1][0] = fmaf(a.y, b.x, acc[1][0]); acc[1][1] = fmaf(a.y, b.y, acc[1][1]);
      acc[1][2] = fmaf(a.y, b.z, acc[1][2]); acc[1][3] = fmaf(a.y, b.w, acc[1][3]);
      acc[2][0] = fmaf(a.z, b.x, acc[2][0]); acc[2][1] = fmaf(a.z, b.y, acc[2][1]);
      acc[2][2] = fmaf(a.z, b.z, acc[2][2]); acc[2][3] = fmaf(a.z, b.w, acc[2][3]);
      acc[3][0] = fmaf(a.w, b.x, acc[3][0]); acc[3][1] = fmaf(a.w, b.y, acc[3][1]);
      acc[3][2] = fmaf(a.w, b.z, acc[3][2]); acc[3][3] = fmaf(a.w, b.w, acc[3][3]);
    }
    __syncthreads();
  }
  float bj[4];
  #pragma unroll
  for (int j = 0; j < 4; ++j) bj[j] = bias[n0 + (tu << 2) + j];
  #pragma unroll
  for (int i = 0; i < 4; ++i) {
    int r = r0 + (tm << 2) + i;
    if (r < M) {
      float4 v;
      v.x = tanhf(acc[i][0] + bj[0]); v.y = tanhf(acc[i][1] + bj[1]);
      v.z = tanhf(acc[i][2] + bj[2]); v.w = tanhf(acc[i][3] + bj[3]);
      *(float4*)&C[(size_t)r * N + n0 + (tu << 2)] = v;
    }
  }
}

__global__ __launch_bounds__(256) void loss_kernel(
    const float* __restrict__ code, const float* __restrict__ finals, float* __restrict__ out)
{
  const int b = threadIdx.x;
  const float* cv = code + (size_t)b * Hc;
  const float* av = finals + (size_t)b * Hc;
  const float* nv = finals + (size_t)(BATCH + b) * Hc;
  float dca = 0, dcn = 0, ncc = 0, naa = 0, nnn = 0;
  for (int k = 0; k < Hc; ++k) {
    float c = cv[k], a = av[k], n = nv[k];
    dca = fmaf(c, a, dca);
    dcn = fmaf(c, n, dcn);
    ncc = fmaf(c, c, ncc);
    naa = fmaf(a, a, naa);
    nnn = fmaf(n, n, nnn);
  }
  float cos_a = dca / fmaxf(sqrtf(ncc) * sqrtf(naa), 1e-8f);
  float cos_n = dcn / fmaxf(sqrtf(ncc) * sqrtf(nnn), 1e-8f);
  float hinge = fmaxf(0.6f - cos_a + cos_n, 1e-6f);
  __shared__ float red[256];
  red[b] = hinge;
  __syncthreads();
  for (int s = 128; s > 0; s >>= 1) {
    if (b < s) red[b] += red[b + s];
    __syncthreads();
  }
  if (b == 0) out[0] = red[0] / 256.0f;
}

extern "C" void kernel_launch(void* const* d_in, const int* in_sizes, int n_in,
                              void* d_out, int out_size, void* d_ws, size_t ws_size,
                              hipStream_t stream) {
  const int* tokens          = (const int*)d_in[0];
  const int* tok_len         = (const int*)d_in[1];
  const int* desc_anchor     = (const int*)d_in[2];
  const int* desc_anchor_len = (const int*)d_in[3];
  const int* desc_neg        = (const int*)d_in[4];
  const int* desc_neg_len    = (const int*)d_in[5];
  const float* tok_emb  = (const float*)d_in[6];
  const float* tok_Wih  = (const float*)d_in[7];
  const float* tok_Whh  = (const float*)d_in[8];
  const float* tok_bih  = (const float*)d_in[9];
  const float* tok_bhh  = (const float*)d_in[10];
  const float* desc_emb = (const float*)d_in[11];
  const float* desc_Wih = (const float*)d_in[12];
  const float* desc_Whh = (const float*)d_in[13];
  const float* desc_bih = (const float*)d_in[14];
  const float* desc_bhh = (const float*)d_in[15];
  const float* attn_W   = (const float*)d_in[16];
  const float* attn_b   = (const float*)d_in[17];
  const float* attnS_W  = (const float*)d_in[18];
  const float* attnS_b  = (const float*)d_in[19];
  const float* out_W1   = (const float*)d_in[20];
  const float* out_b1   = (const float*)d_in[21];
  const float* out_W2   = (const float*)d_in[22];
  const float* out_b2   = (const float*)d_in[23];

  float* p = (float*)d_ws;
  size_t off = 0;
  auto alloc = [&](size_t n) { float* q = p + off; off += n; return q; };

  u16*  featB  = (u16*)alloc(13107200);     // 256*200*512 bf16
  u16*  embT   = (u16*)alloc(1600000);      // VOC*320 bf16
  u16*  embD   = (u16*)alloc(1600000);
  u32*  WihT   = (u32*)alloc(327680);       // 64nc * 10kc * 2si * 64 * 4
  u32*  WihD   = (u32*)alloc(327680);
  u32*  WhhT   = (u32*)alloc(524288);       // 64nc * 16kc * 2si * 64 * 4
  u32*  WhhD   = (u32*)alloc(524288);
  u32*  attnWF = (u32*)alloc(131072);       // 16nc * 16kc * 2si * 64 * 4
  u16*  hA     = (u16*)alloc(65536);        // 256*512 bf16
  u16*  hB     = (u16*)alloc(65536);
  u16*  hC     = (u16*)alloc(131072);       // 512*512 bf16
  u16*  hD     = (u16*)alloc(131072);
  float* finals = alloc(262144);            // 512*512 fp32
  float* scores = alloc(51200);
  float* pooled = alloc(131072);
  float* a2     = alloc(131072);
  float* code   = alloc(131072);
  u32* flags = (u32*)alloc(256);            // 4 rowgroup counters, 256B apart

  // weight / embedding conversions
  conv_emb_kernel<<<(VOC * (EPAD / 2) + 255) / 256, 256, 0, stream>>>(tok_emb, (u32*)embT);
  conv_emb_kernel<<<(VOC * (EPAD / 2) + 255) / 256, 256, 0, stream>>>(desc_emb, (u32*)embD);
  conv_wfrag_kernel<1><<<2048, 256, 0, stream>>>(tok_Whh, WhhT, KC_H, Hc, 524288);
  conv_wfrag_kernel<1><<<2048, 256, 0, stream>>>(desc_Whh, WhhD, KC_H, Hc, 524288);
  conv_wfrag_kernel<1><<<1280, 256, 0, stream>>>(tok_Wih, WihT, KC_E, Ec, 327680);
  conv_wfrag_kernel<1><<<1280, 256, 0, stream>>>(desc_Wih, WihD, KC_E, Ec, 327680);
  conv_wfrag_kernel<0><<<512, 256, 0, stream>>>(attn_W, attnWF, KC_H, Hc, 131072);
  zero_kernel<<<1, 256, 0, stream>>>((float*)flags, 256);

  PArgs A;
  A.WhhT = WhhT; A.WihT = WihT; A.embT = embT;
  A.WhhD = WhhD; A.WihD = WihD; A.embD = embD;
  A.tokens = tokens; A.desc_anchor = desc_anchor; A.desc_neg = desc_neg;
  A.desc_anchor_len = desc_anchor_len; A.desc_neg_len = desc_neg_len;
  A.tok_bih = tok_bih; A.tok_bhh = tok_bhh;
  A.desc_bih = desc_bih; A.desc_bhh = desc_bhh;
  A.hA = hA; A.hB = hB; A.hC = hC; A.hD = hD;
  A.featB = featB; A.finals = finals; A.flags = flags;
  lstm_persist_kernel<<<256, 256, 0, stream>>>(A);

  attn_scores_mfma<<<(BATCH * TCc) / 64, 256, 0, stream>>>(
      featB, attnWF, attn_b, attnS_W, attnS_b, scores);
  softmax_pool_kernel<<<BATCH, 256, 0, stream>>>(scores, tok_len, featB, pooled);
  gemm_bias_tanh_kernel<<<dim3(BATCH / 64, Hc / 64), 256, 0, stream>>>(
      pooled, out_W1, out_b1, a2, BATCH, Hc, Hc);
  gemm_bias_tanh_kernel<<<dim3(BATCH / 64, Hc / 64), 256, 0, stream>>>(
      a2, out_W2, out_b2, code, BATCH, Hc, Hc);
  loss_kernel<<<1, 256, 0, stream>>>(code, finals, (float*)d_out);
}

// Round 10
// 2361.609 us; speedup vs baseline: 6.2727x; 1.1019x over previous
//
#include <hip/hip_runtime.h>
#include <hip/hip_bf16.h>
#include <math.h>

#define TCc 200
#define TDc 50
#define BATCH 256
#define Ec 300
#define Hc 512
#define VOC 10000
#define EPAD 320
#define KC_E 10
#define KC_H 16

typedef unsigned short u16;
typedef unsigned int u32;
typedef unsigned long long u64;
typedef __bf16 bf16x8 __attribute__((ext_vector_type(8)));
typedef float f32x4 __attribute__((ext_vector_type(4)));

__device__ __forceinline__ float sigf(float x) { return 1.f / (1.f + expf(-x)); }

__device__ __forceinline__ u16 f2bf(float f) {
  unsigned u = __float_as_uint(f);
  unsigned r = (u + 0x7FFFu + ((u >> 16) & 1u)) >> 16;  // RNE
  return (u16)r;
}
__device__ __forceinline__ float bf2f(u16 v) { return __uint_as_float(((unsigned)v) << 16); }

// LLC-coherent access: relaxed agent-scope atomics — bare sc1 ops, no cache maintenance.
__device__ __forceinline__ void st_llc(u32* p, u32 v) {
  __hip_atomic_store(p, v, __ATOMIC_RELAXED, __HIP_MEMORY_SCOPE_AGENT);
}
__device__ __forceinline__ u32 ld_llc(const u32* p) {
  return __hip_atomic_load(p, __ATOMIC_RELAXED, __HIP_MEMORY_SCOPE_AGENT);
}
__device__ __forceinline__ u64 ld_llc64(const u64* p) {
  return __hip_atomic_load(p, __ATOMIC_RELAXED, __HIP_MEMORY_SCOPE_AGENT);
}
__device__ __forceinline__ bf16x8 pair_bf16x8(u64 a, u64 b) {
  union { u64 q[2]; bf16x8 v; } t; t.q[0] = a; t.q[1] = b; return t.v;
}

__global__ __launch_bounds__(256) void zero_kernel(float* p, int n) {
  int i = blockIdx.x * 256 + threadIdx.x;
  if (i < n) p[i] = 0.f;
}

// emb (VOC, Ec) fp32 -> (VOC, EPAD) bf16, zero-padded
__global__ __launch_bounds__(256) void conv_emb_kernel(
    const float* __restrict__ emb, u32* __restrict__ out)
{
  int e = blockIdx.x * 256 + threadIdx.x;          // u32 index, VOC*EPAD/2 total
  if (e >= VOC * (EPAD / 2)) return;
  int v = e / (EPAD / 2);
  int k = (e - v * (EPAD / 2)) * 2;
  float a = (k < Ec) ? emb[(size_t)v * Ec + k] : 0.f;
  float b = (k + 1 < Ec) ? emb[(size_t)v * Ec + k + 1] : 0.f;
  out[e] = (u32)f2bf(a) | ((u32)f2bf(b) << 16);
}

// Weight (rows x K) fp32 -> MFMA B-fragment order bf16.
// Frag layout: [nc][kc][si][lane 64][8 bf16]; col-in-group c32 = si*16 + (lane&15);
// k = kc*32 + (lane>>4)*8 + jj.
// GATES: position ul'=c32>>2, g=c32&3; actual unit = ((ul'&3)<<1)|(ul'>>2); source row
// = g*512 + nc*8 + unit. Else: source row = nc*32 + c32.
template<int GATES>
__global__ __launch_bounds__(256) void conv_wfrag_kernel(
    const float* __restrict__ W, u32* __restrict__ out, int KC, int KREAL, int total)
{
  int e = blockIdx.x * 256 + threadIdx.x;          // u32 index
  if (e >= total) return;
  int jp = e & 3;
  int l = (e >> 2) & 63;
  int si = (e >> 8) & 1;
  int t2 = e >> 9;
  int kc = t2 % KC;
  int nc = t2 / KC;
  int c32 = (si << 4) + (l & 15);
  int srow;
  if (GATES) {
    int ulp = c32 >> 2, g = c32 & 3;
    int unit = ((ulp & 3) << 1) | (ulp >> 2);
    srow = (g << 9) + nc * 8 + unit;
  } else {
    srow = nc * 32 + c32;
  }
  int k = (kc << 5) + ((l >> 4) << 3) + (jp << 1);
  float a = (k < KREAL) ? W[(size_t)srow * KREAL + k] : 0.f;
  float b = (k + 1 < KREAL) ? W[(size_t)srow * KREAL + k + 1] : 0.f;
  out[e] = (u32)f2bf(a) | ((u32)f2bf(b) << 16);
}

// ---------------- persistent MFMA LSTM ----------------
// Barrier split into signal/wait with 8-way counter striping per rowgroup.
// signal: drain own stores (vmcnt0), then ONE relaxed fetch_add to counter (cg&7).
// wait: lanes 0..7 poll the 8 counters for >= gen*8. Relaxed agent scope throughout
// => no L2 writeback/invalidate cache ops (round-5/6 lesson).
__device__ __forceinline__ void bar_signal(u32* cnt, int cg) {
  asm volatile("s_waitcnt vmcnt(0)" ::: "memory");
  __syncthreads();
  if (threadIdx.x == 0)
    __hip_atomic_fetch_add(cnt + ((cg & 7) << 4), 1u,
                           __ATOMIC_RELAXED, __HIP_MEMORY_SCOPE_AGENT);
}
__device__ __forceinline__ void bar_wait(u32* cnt, u32 target) {
  if (threadIdx.x < 8) {
    while (ld_llc(cnt + ((int)threadIdx.x << 4)) < target)
      __builtin_amdgcn_s_sleep(1);
  }
  __syncthreads();
}

struct PArgs {
  const u32* WhhT; const u32* WihT; const u16* embT;
  const u32* WhhD; const u32* WihD; const u16* embD;
  const int* tokens; const int* desc_anchor; const int* desc_neg;
  const int* desc_anchor_len; const int* desc_neg_len;
  const float* tok_bih; const float* tok_bhh;
  const float* desc_bih; const float* desc_bhh;
  u16* hA; u16* hB; u16* hC; u16* hD;
  u16* featB; float* finals;
  u32* flags;
};

// 256 blocks = 4 rowgroups x 64 colgroups (8 units = 32 gate-cols each).
// ROWS=64 (tok) / 128 (desc). RPW = ROWS/64 row-halves per wave.
template<int ROWS, bool IS_TOK>
__device__ void lstm_phase(
    u16* WhF, u16* WiF, float* gsum, int* idsL,
    const u32* __restrict__ WhhF, const u32* __restrict__ WihF, const u16* __restrict__ embB,
    const int* __restrict__ idsA, const int* __restrict__ idsB,
    const int* __restrict__ lenA, const int* __restrict__ lenB,
    const float* __restrict__ bih, const float* __restrict__ bhh,
    u16* __restrict__ h0, u16* __restrict__ h1,
    u16* __restrict__ featB, float* __restrict__ finals,
    u32* cnt, int& gen, int T)
{
  constexpr int RPW = ROWS / 64;
  const int tid = threadIdx.x;
  const int cg = blockIdx.x & 63;
  const int row0 = (blockIdx.x >> 6) * ROWS;
  const int w = tid >> 6, l = tid & 63;
  const int rl = tid >> 2, u = tid & 3;

  // stage weight fragments into LDS
  {
    const uint4* s = (const uint4*)(WhhF + ((size_t)cg << 13));   // cg*8192 u32
    uint4* d = (uint4*)WhF;
    #pragma unroll
    for (int i = 0; i < 8; ++i) d[(i << 8) + tid] = s[(i << 8) + tid];
    const uint4* s2 = (const uint4*)(WihF + (size_t)cg * 5120);
    uint4* d2 = (uint4*)WiF;
    #pragma unroll
    for (int i = 0; i < 5; ++i) d2[(i << 8) + tid] = s2[(i << 8) + tid];
  }

  // units owned by this epilogue thread: ug0 = cg*8 + 2u, ug1 = ug0+1 (adjacent)
  float bsv[2][4];
  #pragma unroll
  for (int uu = 0; uu < 2; ++uu)
    #pragma unroll
    for (int g = 0; g < 4; ++g) {
      int ug = (cg << 3) + (u << 1) + uu;
      bsv[uu][g] = bih[(g << 9) + ug] + bhh[(g << 9) + ug];
    }

  float cc[RPW][2];
  int lens[RPW];
  #pragma unroll
  for (int p = 0; p < RPW; ++p) {
    cc[p][0] = 0.f; cc[p][1] = 0.f;
    int row = row0 + (p << 6) + rl;
    lens[p] = IS_TOK ? 0 : ((row < BATCH) ? lenA[row] : lenB[row - BATCH]);
    st_llc((u32*)(h0 + ((size_t)row << 9) + (cg << 3) + (u << 1)), 0u);
  }
  bar_signal(cnt, cg); ++gen;   // zeros visible

  for (int t = 0; t < T; ++t) {
    const u16* hin = (t & 1) ? h1 : h0;
    u16* hout = (t & 1) ? h0 : h1;

    if (tid < ROWS) {
      int row = row0 + tid;
      idsL[tid] = IS_TOK ? idsA[row * T + t]
                         : ((row < BATCH) ? idsA[row * T + t] : idsB[(row - BATCH) * T + t]);
    }
    __syncthreads();

    f32x4 acc[RPW][2];
    #pragma unroll
    for (int p = 0; p < RPW; ++p) {
      acc[p][0] = (f32x4){0.f, 0.f, 0.f, 0.f};
      acc[p][1] = (f32x4){0.f, 0.f, 0.f, 0.f};
    }
    const u16* eb[RPW];
    const u64* hb[RPW];
    #pragma unroll
    for (int p = 0; p < RPW; ++p) {
      int rhp = w + (p << 2);
      int ida = idsL[(rhp << 4) + (l & 15)];
      eb[p] = embB + (size_t)ida * EPAD + ((l >> 4) << 3);
      hb[p] = (const u64*)(hin + (((size_t)(row0 + (rhp << 4) + (l & 15))) << 9)
                               + ((l >> 4) << 3));
    }

    // ---- h-independent input-projection MFMAs FIRST: they overlap the other
    // blocks' arrival RMWs that are still in flight for this generation ----
    #pragma unroll
    for (int kc = 0; kc < KC_E; ++kc) {
      bf16x8 b0 = *(const bf16x8*)(WiF + ((((kc << 1) | 0) << 6 | l) << 3));
      bf16x8 b1 = *(const bf16x8*)(WiF + ((((kc << 1) | 1) << 6 | l) << 3));
      #pragma unroll
      for (int p = 0; p < RPW; ++p) {
        bf16x8 a = *(const bf16x8*)(eb[p] + (kc << 5));
        acc[p][0] = __builtin_amdgcn_mfma_f32_16x16x32_bf16(a, b0, acc[p][0], 0, 0, 0);
        acc[p][1] = __builtin_amdgcn_mfma_f32_16x16x32_bf16(a, b1, acc[p][1], 0, 0, 0);
      }
    }

    // ---- now wait for h(t-1) visibility ----
    bar_wait(cnt, (u32)gen * 8u);

    // ---- prefetch h as relaxed 8B LLC loads, then recurrent MFMAs ----
    u64 hw[RPW][2 * KC_H];
    #pragma unroll
    for (int p = 0; p < RPW; ++p)
      #pragma unroll
      for (int kc = 0; kc < KC_H; ++kc) {
        hw[p][2 * kc]     = ld_llc64(hb[p] + (kc << 3));
        hw[p][2 * kc + 1] = ld_llc64(hb[p] + (kc << 3) + 1);
      }
    #pragma unroll
    for (int kc = 0; kc < KC_H; ++kc) {
      bf16x8 b0 = *(const bf16x8*)(WhF + ((((kc << 1) | 0) << 6 | l) << 3));
      bf16x8 b1 = *(const bf16x8*)(WhF + ((((kc << 1) | 1) << 6 | l) << 3));
      #pragma unroll
      for (int p = 0; p < RPW; ++p) {
        bf16x8 a = pair_bf16x8(hw[p][2 * kc], hw[p][2 * kc + 1]);
        acc[p][0] = __builtin_amdgcn_mfma_f32_16x16x32_bf16(a, b0, acc[p][0], 0, 0, 0);
        acc[p][1] = __builtin_amdgcn_mfma_f32_16x16x32_bf16(a, b1, acc[p][1], 0, 0, 0);
      }
    }

    #pragma unroll
    for (int p = 0; p < RPW; ++p) {
      int lr0 = (w << 4) + ((l >> 4) << 2);
      #pragma unroll
      for (int si = 0; si < 2; ++si)
        #pragma unroll
        for (int j = 0; j < 4; ++j)
          gsum[(lr0 + j) * 36 + (si << 4) + (l & 15)] = acc[p][si][j];
      __syncthreads();
      {
        float4 g0 = *(const float4*)&gsum[rl * 36 + (u << 2)];          // unit 2u
        float4 g1 = *(const float4*)&gsum[rl * 36 + ((u + 4) << 2)];    // unit 2u+1
        int row = row0 + (p << 6) + rl;
        float gi0 = sigf(g0.x + bsv[0][0]);
        float gf0 = sigf(g0.y + bsv[0][1]);
        float gg0 = tanhf(g0.z + bsv[0][2]);
        float go0 = sigf(g0.w + bsv[0][3]);
        float cn0 = gf0 * cc[p][0] + gi0 * gg0;
        cc[p][0] = cn0;
        float hn0 = go0 * tanhf(cn0);
        float gi1 = sigf(g1.x + bsv[1][0]);
        float gf1 = sigf(g1.y + bsv[1][1]);
        float gg1 = tanhf(g1.z + bsv[1][2]);
        float go1 = sigf(g1.w + bsv[1][3]);
        float cn1 = gf1 * cc[p][1] + gi1 * gg1;
        cc[p][1] = cn1;
        float hn1 = go1 * tanhf(cn1);
        int ug0 = (cg << 3) + (u << 1);
        st_llc((u32*)(hout + ((size_t)row << 9) + ug0),
               (u32)f2bf(hn0) | ((u32)f2bf(hn1) << 16));
        if (IS_TOK) {
          size_t fo = ((size_t)row * TCc + t) << 9;
          *(u32*)(featB + fo + ug0) =
              (u32)f2bf(tanhf(hn0)) | ((u32)f2bf(tanhf(hn1)) << 16);
        } else if (t == lens[p] - 1) {
          finals[((size_t)row << 9) + ug0]     = tanhf(hn0);
          finals[((size_t)row << 9) + ug0 + 1] = tanhf(hn1);
        }
      }
      __syncthreads();
    }
    bar_signal(cnt, cg); ++gen;   // h(t) stores visible
  }
}

__global__ void __launch_bounds__(256, 1) lstm_persist_kernel(PArgs A) {
  __shared__ __align__(16) u16 WhF[KC_H * 2 * 64 * 8];   // 32768 B
  __shared__ __align__(16) u16 WiF[KC_E * 2 * 64 * 8];   // 20480 B
  __shared__ __align__(16) float gsum[64 * 36];          // 9216 B
  __shared__ int idsL[128];                              // 512 B
  u32* cnt = A.flags + ((blockIdx.x >> 6) << 7);         // rowgroup: 8 counters, 64B apart
  int gen = 0;
  lstm_phase<64, true>(WhF, WiF, gsum, idsL, A.WhhT, A.WihT, A.embT,
                       A.tokens, nullptr, nullptr, nullptr,
                       A.tok_bih, A.tok_bhh, A.hA, A.hB, A.featB, nullptr,
                       cnt, gen, TCc);
  lstm_phase<128, false>(WhF, WiF, gsum, idsL, A.WhhD, A.WihD, A.embD,
                         A.desc_anchor, A.desc_neg, A.desc_anchor_len, A.desc_neg_len,
                         A.desc_bih, A.desc_bhh, A.hC, A.hD, nullptr, A.finals,
                         cnt, gen, TDc);
}

// ---------------- attention scores via MFMA ----------------
__global__ __launch_bounds__(256) void attn_scores_mfma(
    const u16* __restrict__ featB, const u32* __restrict__ WF,
    const float* __restrict__ attn_b, const float* __restrict__ attnS_W,
    const float* __restrict__ attnS_b, float* __restrict__ scores)
{
  __shared__ __align__(16) u16 Af[4 * 16 * 64 * 8];   // 65536 B (reused as red after)
  const int tid = threadIdx.x;
  const int m0 = blockIdx.x * 64;

  #pragma unroll
  for (int i = 0; i < 16; ++i) {
    int c = (i << 8) + tid;
    int r = c >> 6, kb = c & 63;
    uint4 v = *(const uint4*)(featB + (((size_t)(m0 + r)) << 9) + (kb << 3));
    int kc = kb >> 2, lf = (r & 15) + ((kb & 3) << 4);
    *(uint4*)(Af + ((((r >> 4) * 16 + kc) << 6 | lf) << 3)) = v;
  }
  __syncthreads();

  const int w = tid >> 6, l = tid & 63;
  const u16* WF16 = (const u16*)WF;
  float p[4][4] = {};
  for (int nc = w * 4; nc < w * 4 + 4; ++nc) {
    f32x4 acc[4][2];
    #pragma unroll
    for (int rh = 0; rh < 4; ++rh) {
      acc[rh][0] = (f32x4){0.f, 0.f, 0.f, 0.f};
      acc[rh][1] = (f32x4){0.f, 0.f, 0.f, 0.f};
    }
    #pragma unroll 4
    for (int kc = 0; kc < 16; ++kc) {
      bf16x8 b0 = *(const bf16x8*)(WF16 + ((size_t)((((nc << 4) + kc) << 1 | 0) << 6 | l) << 3));
      bf16x8 b1 = *(const bf16x8*)(WF16 + ((size_t)((((nc << 4) + kc) << 1 | 1) << 6 | l) << 3));
      #pragma unroll
      for (int rh = 0; rh < 4; ++rh) {
        bf16x8 a = *(const bf16x8*)(Af + (((rh * 16 + kc) << 6 | l) << 3));
        acc[rh][0] = __builtin_amdgcn_mfma_f32_16x16x32_bf16(a, b0, acc[rh][0], 0, 0, 0);
        acc[rh][1] = __builtin_amdgcn_mfma_f32_16x16x32_bf16(a, b1, acc[rh][1], 0, 0, 0);
      }
    }
    int c0 = (nc << 5) + (l & 15), c1 = c0 + 16;
    float bb0 = attn_b[c0], sw0 = attnS_W[c0];
    float bb1 = attn_b[c1], sw1 = attnS_W[c1];
    #pragma unroll
    for (int rh = 0; rh < 4; ++rh)
      #pragma unroll
      for (int j = 0; j < 4; ++j)
        p[rh][j] += tanhf(acc[rh][0][j] + bb0) * sw0 + tanhf(acc[rh][1][j] + bb1) * sw1;
  }
  __syncthreads();
  float* red = (float*)Af;   // 64 x 68
  #pragma unroll
  for (int rh = 0; rh < 4; ++rh)
    #pragma unroll
    for (int j = 0; j < 4; ++j)
      red[(rh * 16 + ((l >> 4) << 2) + j) * 68 + (w << 4) + (l & 15)] = p[rh][j];
  __syncthreads();
  if (tid < 64) {
    float s = attnS_b[0];
    #pragma unroll 8
    for (int q = 0; q < 64; ++q) s += red[tid * 68 + q];
    scores[m0 + tid] = s;
  }
}

// masked softmax over T=200 + weighted pooling of bf16 feat -> pooled (B,H) fp32
__global__ __launch_bounds__(256) void softmax_pool_kernel(
    const float* __restrict__ scores, const int* __restrict__ tok_len,
    const u16* __restrict__ featB, float* __restrict__ pooled)
{
  const int b = blockIdx.x;
  const int tid = threadIdx.x;
  __shared__ float wgt[TCc];
  __shared__ float red[256];
  const int len = tok_len[b];

  float myv = -1e30f;
  if (tid < TCc) {
    float s = scores[b * TCc + tid];
    myv = (tid < len) ? s : -1e9f;
    wgt[tid] = myv;
  }
  red[tid] = myv;
  __syncthreads();
  for (int s = 128; s > 0; s >>= 1) {
    if (tid < s) red[tid] = fmaxf(red[tid], red[tid + s]);
    __syncthreads();
  }
  const float mx = red[0];
  __syncthreads();
  float e = 0.f;
  if (tid < TCc) e = expf(wgt[tid] - mx);
  red[tid] = e;
  __syncthreads();
  for (int s = 128; s > 0; s >>= 1) {
    if (tid < s) red[tid] += red[tid + s];
    __syncthreads();
  }
  const float sum = red[0];
  __syncthreads();
  if (tid < TCc) wgt[tid] = e / sum;
  __syncthreads();

  const u32* featU = (const u32*)featB;
  float a0 = 0.f, a1 = 0.f;
  for (int t = 0; t < TCc; ++t) {
    u32 v = featU[((size_t)b * TCc + t) * 256 + tid];
    float wv = wgt[t];
    a0 = fmaf(wv, bf2f((u16)(v & 0xFFFF)), a0);
    a1 = fmaf(wv, bf2f((u16)(v >> 16)), a1);
  }
  pooled[((size_t)b << 9) + tid * 2] = a0;
  pooled[((size_t)b << 9) + tid * 2 + 1] = a1;
}

// C[m,n] = tanh(A[m,:] . W[n,:] + bias[n]); fp32, grid (M/64, N/64)
__global__ __launch_bounds__(256) void gemm_bias_tanh_kernel(
    const float* __restrict__ A, const float* __restrict__ Bw,
    const float* __restrict__ bias, float* __restrict__ C, int M, int N, int K)
{
  const int r0 = blockIdx.x * 64;
  const int n0 = blockIdx.y * 64;
  const int tid = threadIdx.x;
  const int tu = tid & 15;
  const int tm = tid >> 4;
  __shared__ float As[32][68];
  __shared__ float Bs[32][68];

  float acc[4][4] = {};
  for (int k0 = 0; k0 < K; k0 += 32) {
    #pragma unroll
    for (int i = 0; i < 2; ++i) {
      int lin = tid + (i << 8);
      int kq = lin & 7, m = lin >> 3;
      int k = k0 + (kq << 2);
      int r = r0 + m; if (r >= M) r = M - 1;
      float4 va = *(const float4*)&A[(size_t)r * K + k];
      float4 vb = *(const float4*)&Bw[(size_t)(n0 + m) * K + k];
      As[(kq << 2) + 0][m] = va.x; As[(kq << 2) + 1][m] = va.y;
      As[(kq << 2) + 2][m] = va.z; As[(kq << 2) + 3][m] = va.w;
      Bs[(kq << 2) + 0][m] = vb.x; Bs[(kq << 2) + 1][m] = vb.y;
      Bs[(kq << 2) + 2][m] = vb.z; Bs[(kq << 2) + 3][m] = vb.w;
    }
    __syncthreads();
    #pragma unroll
    for (int kk = 0; kk < 32; ++kk) {
      float4 a = *(const float4*)&As[kk][tm << 2];
      float4 b = *(const float4*)&Bs[kk][tu << 2];
      acc[0][0] = fmaf(a.x, b.x, acc[0][0]); acc[0][1] = fmaf(a.x, b.y, acc[0][1]);
      acc[0][2] = fmaf(a.x, b.z, acc[0][2]); acc[0][3] = fmaf(a.x, b.w, acc[0][3]);
      acc[1][0] = fmaf(a.y, b.x, acc[1][0]); acc[1][1] = fmaf(a.y, b.y, acc[1][1]);
      acc[1][2] = fmaf(a.y, b.z, acc[1][2]); acc[1][3] = fmaf(a.y, b.w, acc[1][3]);
      acc[2][0] = fmaf(a.z, b.x, acc[2][0]); acc[2][1] = fmaf(a.z, b.y, acc[2][1]);
      acc[2][2] = fmaf(a.z, b.z, acc[2][2]); acc[2][3] = fmaf(a.z, b.w, acc[2][3]);
      acc[3][0] = fmaf(a.w, b.x, acc[3][0]); acc[3][1] = fmaf(a.w, b.y, acc[3][1]);
      acc[3][2] = fmaf(a.w, b.z, acc[3][2]); acc[3][3] = fmaf(a.w, b.w, acc[3][3]);
    }
    __syncthreads();
  }
  float bj[4];
  #pragma unroll
  for (int j = 0; j < 4; ++j) bj[j] = bias[n0 + (tu << 2) + j];
  #pragma unroll
  for (int i = 0; i < 4; ++i) {
    int r = r0 + (tm << 2) + i;
    if (r < M) {
      float4 v;
      v.x = tanhf(acc[i][0] + bj[0]); v.y = tanhf(acc[i][1] + bj[1]);
      v.z = tanhf(acc[i][2] + bj[2]); v.w = tanhf(acc[i][3] + bj[3]);
      *(float4*)&C[(size_t)r * N + n0 + (tu << 2)] = v;
    }
  }
}

__global__ __launch_bounds__(256) void loss_kernel(
    const float* __restrict__ code, const float* __restrict__ finals, float* __restrict__ out)
{
  const int b = threadIdx.x;
  const float* cv = code + (size_t)b * Hc;
  const float* av = finals + (size_t)b * Hc;
  const float* nv = finals + (size_t)(BATCH + b) * Hc;
  float dca = 0, dcn = 0, ncc = 0, naa = 0, nnn = 0;
  for (int k = 0; k < Hc; ++k) {
    float c = cv[k], a = av[k], n = nv[k];
    dca = fmaf(c, a, dca);
    dcn = fmaf(c, n, dcn);
    ncc = fmaf(c, c, ncc);
    naa = fmaf(a, a, naa);
    nnn = fmaf(n, n, nnn);
  }
  float cos_a = dca / fmaxf(sqrtf(ncc) * sqrtf(naa), 1e-8f);
  float cos_n = dcn / fmaxf(sqrtf(ncc) * sqrtf(nnn), 1e-8f);
  float hinge = fmaxf(0.6f - cos_a + cos_n, 1e-6f);
  __shared__ float red[256];
  red[b] = hinge;
  __syncthreads();
  for (int s = 128; s > 0; s >>= 1) {
    if (b < s) red[b] += red[b + s];
    __syncthreads();
  }
  if (b == 0) out[0] = red[0] / 256.0f;
}

extern "C" void kernel_launch(void* const* d_in, const int* in_sizes, int n_in,
                              void* d_out, int out_size, void* d_ws, size_t ws_size,
                              hipStream_t stream) {
  const int* tokens          = (const int*)d_in[0];
  const int* tok_len         = (const int*)d_in[1];
  const int* desc_anchor     = (const int*)d_in[2];
  const int* desc_anchor_len = (const int*)d_in[3];
  const int* desc_neg        = (const int*)d_in[4];
  const int* desc_neg_len    = (const int*)d_in[5];
  const float* tok_emb  = (const float*)d_in[6];
  const float* tok_Wih  = (const float*)d_in[7];
  const float* tok_Whh  = (const float*)d_in[8];
  const float* tok_bih  = (const float*)d_in[9];
  const float* tok_bhh  = (const float*)d_in[10];
  const float* desc_emb = (const float*)d_in[11];
  const float* desc_Wih = (const float*)d_in[12];
  const float* desc_Whh = (const float*)d_in[13];
  const float* desc_bih = (const float*)d_in[14];
  const float* desc_bhh = (const float*)d_in[15];
  const float* attn_W   = (const float*)d_in[16];
  const float* attn_b   = (const float*)d_in[17];
  const float* attnS_W  = (const float*)d_in[18];
  const float* attnS_b  = (const float*)d_in[19];
  const float* out_W1   = (const float*)d_in[20];
  const float* out_b1   = (const float*)d_in[21];
  const float* out_W2   = (const float*)d_in[22];
  const float* out_b2   = (const float*)d_in[23];

  float* p = (float*)d_ws;
  size_t off = 0;
  auto alloc = [&](size_t n) { float* q = p + off; off += n; return q; };

  u16*  featB  = (u16*)alloc(13107200);     // 256*200*512 bf16
  u16*  embT   = (u16*)alloc(1600000);      // VOC*320 bf16
  u16*  embD   = (u16*)alloc(1600000);
  u32*  WihT   = (u32*)alloc(327680);       // 64nc * 10kc * 2si * 64 * 4
  u32*  WihD   = (u32*)alloc(327680);
  u32*  WhhT   = (u32*)alloc(524288);       // 64nc * 16kc * 2si * 64 * 4
  u32*  WhhD   = (u32*)alloc(524288);
  u32*  attnWF = (u32*)alloc(131072);       // 16nc * 16kc * 2si * 64 * 4
  u16*  hA     = (u16*)alloc(65536);        // 256*512 bf16
  u16*  hB     = (u16*)alloc(65536);
  u16*  hC     = (u16*)alloc(131072);       // 512*512 bf16
  u16*  hD     = (u16*)alloc(131072);
  float* finals = alloc(262144);            // 512*512 fp32
  float* scores = alloc(51200);
  float* pooled = alloc(131072);
  float* a2     = alloc(131072);
  float* code   = alloc(131072);
  u32* flags = (u32*)alloc(512);            // 4 rowgroups x 8 counters x 64B spacing

  // weight / embedding conversions
  conv_emb_kernel<<<(VOC * (EPAD / 2) + 255) / 256, 256, 0, stream>>>(tok_emb, (u32*)embT);
  conv_emb_kernel<<<(VOC * (EPAD / 2) + 255) / 256, 256, 0, stream>>>(desc_emb, (u32*)embD);
  conv_wfrag_kernel<1><<<2048, 256, 0, stream>>>(tok_Whh, WhhT, KC_H, Hc, 524288);
  conv_wfrag_kernel<1><<<2048, 256, 0, stream>>>(desc_Whh, WhhD, KC_H, Hc, 524288);
  conv_wfrag_kernel<1><<<1280, 256, 0, stream>>>(tok_Wih, WihT, KC_E, Ec, 327680);
  conv_wfrag_kernel<1><<<1280, 256, 0, stream>>>(desc_Wih, WihD, KC_E, Ec, 327680);
  conv_wfrag_kernel<0><<<512, 256, 0, stream>>>(attn_W, attnWF, KC_H, Hc, 131072);
  zero_kernel<<<2, 256, 0, stream>>>((float*)flags, 512);

  PArgs A;
  A.WhhT = WhhT; A.WihT = WihT; A.embT = embT;
  A.WhhD = WhhD; A.WihD = WihD; A.embD = embD;
  A.tokens = tokens; A.desc_anchor = desc_anchor; A.desc_neg = desc_neg;
  A.desc_anchor_len = desc_anchor_len; A.desc_neg_len = desc_neg_len;
  A.tok_bih = tok_bih; A.tok_bhh = tok_bhh;
  A.desc_bih = desc_bih; A.desc_bhh = desc_bhh;
  A.hA = hA; A.hB = hB; A.hC = hC; A.hD = hD;
  A.featB = featB; A.finals = finals; A.flags = flags;
  lstm_persist_kernel<<<256, 256, 0, stream>>>(A);

  attn_scores_mfma<<<(BATCH * TCc) / 64, 256, 0, stream>>>(
      featB, attnWF, attn_b, attnS_W, attnS_b, scores);
  softmax_pool_kernel<<<BATCH, 256, 0, stream>>>(scores, tok_len, featB, pooled);
  gemm_bias_tanh_kernel<<<dim3(BATCH / 64, Hc / 64), 256, 0, stream>>>(
      pooled, out_W1, out_b1, a2, BATCH, Hc, Hc);
  gemm_bias_tanh_kernel<<<dim3(BATCH / 64, Hc / 64), 256, 0, stream>>>(
      a2, out_W2, out_b2, code, BATCH, Hc, Hc);
  loss_kernel<<<1, 256, 0, stream>>>(code, finals, (float*)d_out);
}

// Round 11
// 2010.216 us; speedup vs baseline: 7.3691x; 1.1748x over previous
//
#include <hip/hip_runtime.h>
#include <hip/hip_bf16.h>
#include <math.h>

#define TCc 200
#define TDc 50
#define BATCH 256
#define Ec 300
#define Hc 512
#define VOC 10000
#define EPAD 320
#define KC_E 10
#define KC_H 16

typedef unsigned short u16;
typedef unsigned int u32;
typedef unsigned long long u64;
typedef __bf16 bf16x8 __attribute__((ext_vector_type(8)));
typedef float f32x4 __attribute__((ext_vector_type(4)));

__device__ __forceinline__ float sigf(float x) { return 1.f / (1.f + expf(-x)); }

__device__ __forceinline__ u16 f2bf(float f) {
  unsigned u = __float_as_uint(f);
  unsigned r = (u + 0x7FFFu + ((u >> 16) & 1u)) >> 16;  // RNE
  return (u16)r;
}
__device__ __forceinline__ float bf2f(u16 v) { return __uint_as_float(((unsigned)v) << 16); }

// LLC-coherent access: relaxed agent-scope atomics — bare sc1 ops, no cache maintenance.
__device__ __forceinline__ void st_llc(u32* p, u32 v) {
  __hip_atomic_store(p, v, __ATOMIC_RELAXED, __HIP_MEMORY_SCOPE_AGENT);
}
__device__ __forceinline__ u32 ld_llc(const u32* p) {
  return __hip_atomic_load(p, __ATOMIC_RELAXED, __HIP_MEMORY_SCOPE_AGENT);
}
__device__ __forceinline__ u64 ld_llc64(const u64* p) {
  return __hip_atomic_load(p, __ATOMIC_RELAXED, __HIP_MEMORY_SCOPE_AGENT);
}
__device__ __forceinline__ bf16x8 pair_bf16x8(u64 a, u64 b) {
  union { u64 q[2]; bf16x8 v; } t; t.q[0] = a; t.q[1] = b; return t.v;
}

__global__ __launch_bounds__(256) void zero_kernel(float* p, int n) {
  int i = blockIdx.x * 256 + threadIdx.x;
  if (i < n) p[i] = 0.f;
}

// emb (VOC, Ec) fp32 -> (VOC, EPAD) bf16, zero-padded
__global__ __launch_bounds__(256) void conv_emb_kernel(
    const float* __restrict__ emb, u32* __restrict__ out)
{
  int e = blockIdx.x * 256 + threadIdx.x;          // u32 index, VOC*EPAD/2 total
  if (e >= VOC * (EPAD / 2)) return;
  int v = e / (EPAD / 2);
  int k = (e - v * (EPAD / 2)) * 2;
  float a = (k < Ec) ? emb[(size_t)v * Ec + k] : 0.f;
  float b = (k + 1 < Ec) ? emb[(size_t)v * Ec + k + 1] : 0.f;
  out[e] = (u32)f2bf(a) | ((u32)f2bf(b) << 16);
}

// Weight (rows x K) fp32 -> MFMA B-fragment order bf16.
// Frag layout: [nc][kc][si][lane 64][8 bf16]; col-in-group c32 = si*16 + (lane&15);
// k = kc*32 + (lane>>4)*8 + jj.
// GATES: position ul'=c32>>2, g=c32&3; actual unit = ((ul'&3)<<1)|(ul'>>2); source row
// = g*512 + nc*8 + unit. Else: source row = nc*32 + c32.
template<int GATES>
__global__ __launch_bounds__(256) void conv_wfrag_kernel(
    const float* __restrict__ W, u32* __restrict__ out, int KC, int KREAL, int total)
{
  int e = blockIdx.x * 256 + threadIdx.x;          // u32 index
  if (e >= total) return;
  int jp = e & 3;
  int l = (e >> 2) & 63;
  int si = (e >> 8) & 1;
  int t2 = e >> 9;
  int kc = t2 % KC;
  int nc = t2 / KC;
  int c32 = (si << 4) + (l & 15);
  int srow;
  if (GATES) {
    int ulp = c32 >> 2, g = c32 & 3;
    int unit = ((ulp & 3) << 1) | (ulp >> 2);
    srow = (g << 9) + nc * 8 + unit;
  } else {
    srow = nc * 32 + c32;
  }
  int k = (kc << 5) + ((l >> 4) << 3) + (jp << 1);
  float a = (k < KREAL) ? W[(size_t)srow * KREAL + k] : 0.f;
  float b = (k + 1 < KREAL) ? W[(size_t)srow * KREAL + k + 1] : 0.f;
  out[e] = (u32)f2bf(a) | ((u32)f2bf(b) << 16);
}

// ---------------- persistent MFMA LSTM ----------------
// Barrier split into signal/wait with 8-way counter striping per rowgroup.
// signal: drain own h stores (vmcnt0), then ONE relaxed fetch_add to counter (cg&7).
// wait: lanes 0..7 poll the 8 counters for >= gen*8. Relaxed agent scope throughout
// => no L2 writeback/invalidate cache ops.
__device__ __forceinline__ void bar_signal(u32* cnt, int cg) {
  asm volatile("s_waitcnt vmcnt(0)" ::: "memory");
  __syncthreads();
  if (threadIdx.x == 0)
    __hip_atomic_fetch_add(cnt + ((cg & 7) << 4), 1u,
                           __ATOMIC_RELAXED, __HIP_MEMORY_SCOPE_AGENT);
}
__device__ __forceinline__ void bar_wait(u32* cnt, u32 target) {
  if (threadIdx.x < 8) {
    while (ld_llc(cnt + ((int)threadIdx.x << 4)) < target)
      __builtin_amdgcn_s_sleep(1);
  }
  __syncthreads();
}

struct PArgs {
  const u32* WhhT; const u32* WihT; const u16* embT;
  const u32* WhhD; const u32* WihD; const u16* embD;
  const int* tokens; const int* desc_anchor; const int* desc_neg;
  const int* desc_anchor_len; const int* desc_neg_len;
  const float* tok_bih; const float* tok_bhh;
  const float* desc_bih; const float* desc_bhh;
  u16* hA; u16* hB; u16* hC; u16* hD;
  u16* featB; float* finals;
  u32* flags;
};

// Phase: lbid in [0,256): 4 rowgroups x 64 colgroups (8 units = 32 gate-cols each).
// ROWS=64 (tok) / 128 (desc). RPW = ROWS/64 row-halves per wave.
// Tok: feat stores moved AFTER the signal (off the inter-block critical path).
template<int ROWS, bool IS_TOK>
__device__ void lstm_phase(
    int lbid, u16* WhF, u16* WiF, float* gsum, int* idsL,
    const u32* __restrict__ WhhF, const u32* __restrict__ WihF, const u16* __restrict__ embB,
    const int* __restrict__ idsA, const int* __restrict__ idsB,
    const int* __restrict__ lenA, const int* __restrict__ lenB,
    const float* __restrict__ bih, const float* __restrict__ bhh,
    u16* __restrict__ h0, u16* __restrict__ h1,
    u16* __restrict__ featB, float* __restrict__ finals,
    u32* cnt, int T)
{
  constexpr int RPW = ROWS / 64;
  const int tid = threadIdx.x;
  const int cg = lbid & 63;
  const int row0 = (lbid >> 6) * ROWS;
  const int w = tid >> 6, l = tid & 63;
  const int rl = tid >> 2, u = tid & 3;
  int gen = 0;

  // stage weight fragments into LDS
  {
    const uint4* s = (const uint4*)(WhhF + ((size_t)cg << 13));   // cg*8192 u32
    uint4* d = (uint4*)WhF;
    #pragma unroll
    for (int i = 0; i < 8; ++i) d[(i << 8) + tid] = s[(i << 8) + tid];
    const uint4* s2 = (const uint4*)(WihF + (size_t)cg * 5120);
    uint4* d2 = (uint4*)WiF;
    #pragma unroll
    for (int i = 0; i < 5; ++i) d2[(i << 8) + tid] = s2[(i << 8) + tid];
  }

  // units owned by this epilogue thread: ug0 = cg*8 + 2u, ug1 = ug0+1 (adjacent)
  float bsv[2][4];
  #pragma unroll
  for (int uu = 0; uu < 2; ++uu)
    #pragma unroll
    for (int g = 0; g < 4; ++g) {
      int ug = (cg << 3) + (u << 1) + uu;
      bsv[uu][g] = bih[(g << 9) + ug] + bhh[(g << 9) + ug];
    }

  float cc[RPW][2];
  int lens[RPW];
  #pragma unroll
  for (int p = 0; p < RPW; ++p) {
    cc[p][0] = 0.f; cc[p][1] = 0.f;
    int row = row0 + (p << 6) + rl;
    lens[p] = IS_TOK ? 0 : ((row < BATCH) ? lenA[row] : lenB[row - BATCH]);
    st_llc((u32*)(h0 + ((size_t)row << 9) + (cg << 3) + (u << 1)), 0u);
  }
  bar_signal(cnt, cg); ++gen;   // zeros visible

  for (int t = 0; t < T; ++t) {
    const u16* hin = (t & 1) ? h1 : h0;
    u16* hout = (t & 1) ? h0 : h1;

    if (tid < ROWS) {
      int row = row0 + tid;
      idsL[tid] = IS_TOK ? idsA[row * T + t]
                         : ((row < BATCH) ? idsA[row * T + t] : idsB[(row - BATCH) * T + t]);
    }
    __syncthreads();

    f32x4 acc[RPW][2];
    #pragma unroll
    for (int p = 0; p < RPW; ++p) {
      acc[p][0] = (f32x4){0.f, 0.f, 0.f, 0.f};
      acc[p][1] = (f32x4){0.f, 0.f, 0.f, 0.f};
    }
    const u16* eb[RPW];
    const u64* hb[RPW];
    #pragma unroll
    for (int p = 0; p < RPW; ++p) {
      int rhp = w + (p << 2);
      int ida = idsL[(rhp << 4) + (l & 15)];
      eb[p] = embB + (size_t)ida * EPAD + ((l >> 4) << 3);
      hb[p] = (const u64*)(hin + (((size_t)(row0 + (rhp << 4) + (l & 15))) << 9)
                               + ((l >> 4) << 3));
    }

    // ---- h-independent input-projection MFMAs FIRST (overlap others' arrivals) ----
    #pragma unroll
    for (int kc = 0; kc < KC_E; ++kc) {
      bf16x8 b0 = *(const bf16x8*)(WiF + ((((kc << 1) | 0) << 6 | l) << 3));
      bf16x8 b1 = *(const bf16x8*)(WiF + ((((kc << 1) | 1) << 6 | l) << 3));
      #pragma unroll
      for (int p = 0; p < RPW; ++p) {
        bf16x8 a = *(const bf16x8*)(eb[p] + (kc << 5));
        acc[p][0] = __builtin_amdgcn_mfma_f32_16x16x32_bf16(a, b0, acc[p][0], 0, 0, 0);
        acc[p][1] = __builtin_amdgcn_mfma_f32_16x16x32_bf16(a, b1, acc[p][1], 0, 0, 0);
      }
    }

    // ---- wait for h(t-1) visibility ----
    bar_wait(cnt, (u32)gen * 8u);

    // ---- prefetch h as relaxed 8B LLC loads, then recurrent MFMAs ----
    u64 hw[RPW][2 * KC_H];
    #pragma unroll
    for (int p = 0; p < RPW; ++p)
      #pragma unroll
      for (int kc = 0; kc < KC_H; ++kc) {
        hw[p][2 * kc]     = ld_llc64(hb[p] + (kc << 3));
        hw[p][2 * kc + 1] = ld_llc64(hb[p] + (kc << 3) + 1);
      }
    #pragma unroll
    for (int kc = 0; kc < KC_H; ++kc) {
      bf16x8 b0 = *(const bf16x8*)(WhF + ((((kc << 1) | 0) << 6 | l) << 3));
      bf16x8 b1 = *(const bf16x8*)(WhF + ((((kc << 1) | 1) << 6 | l) << 3));
      #pragma unroll
      for (int p = 0; p < RPW; ++p) {
        bf16x8 a = pair_bf16x8(hw[p][2 * kc], hw[p][2 * kc + 1]);
        acc[p][0] = __builtin_amdgcn_mfma_f32_16x16x32_bf16(a, b0, acc[p][0], 0, 0, 0);
        acc[p][1] = __builtin_amdgcn_mfma_f32_16x16x32_bf16(a, b1, acc[p][1], 0, 0, 0);
      }
    }

    // ---- epilogue: gates, c/h update; h stored NOW, feat deferred past signal ----
    float hnv[RPW][2];
    #pragma unroll
    for (int p = 0; p < RPW; ++p) {
      int lr0 = (w << 4) + ((l >> 4) << 2);
      #pragma unroll
      for (int si = 0; si < 2; ++si)
        #pragma unroll
        for (int j = 0; j < 4; ++j)
          gsum[(lr0 + j) * 36 + (si << 4) + (l & 15)] = acc[p][si][j];
      __syncthreads();
      {
        float4 g0 = *(const float4*)&gsum[rl * 36 + (u << 2)];          // unit 2u
        float4 g1 = *(const float4*)&gsum[rl * 36 + ((u + 4) << 2)];    // unit 2u+1
        int row = row0 + (p << 6) + rl;
        float gi0 = sigf(g0.x + bsv[0][0]);
        float gf0 = sigf(g0.y + bsv[0][1]);
        float gg0 = tanhf(g0.z + bsv[0][2]);
        float go0 = sigf(g0.w + bsv[0][3]);
        float cn0 = gf0 * cc[p][0] + gi0 * gg0;
        cc[p][0] = cn0;
        float hn0 = go0 * tanhf(cn0);
        float gi1 = sigf(g1.x + bsv[1][0]);
        float gf1 = sigf(g1.y + bsv[1][1]);
        float gg1 = tanhf(g1.z + bsv[1][2]);
        float go1 = sigf(g1.w + bsv[1][3]);
        float cn1 = gf1 * cc[p][1] + gi1 * gg1;
        cc[p][1] = cn1;
        float hn1 = go1 * tanhf(cn1);
        hnv[p][0] = hn0; hnv[p][1] = hn1;
        int ug0 = (cg << 3) + (u << 1);
        st_llc((u32*)(hout + ((size_t)row << 9) + ug0),
               (u32)f2bf(hn0) | ((u32)f2bf(hn1) << 16));
        if (!IS_TOK) {
          if (t == lens[p] - 1) {
            finals[((size_t)row << 9) + ug0]     = tanhf(hn0);
            finals[((size_t)row << 9) + ug0 + 1] = tanhf(hn1);
          }
        }
      }
      __syncthreads();
    }
    bar_signal(cnt, cg); ++gen;   // h(t) visible

    if (IS_TOK) {
      // feat = tanh(h) stores, off the inter-block critical path
      #pragma unroll
      for (int p = 0; p < RPW; ++p) {
        int row = row0 + (p << 6) + rl;
        int ug0 = (cg << 3) + (u << 1);
        size_t fo = ((size_t)row * TCc + t) << 9;
        *(u32*)(featB + fo + ug0) =
            (u32)f2bf(tanhf(hnv[p][0])) | ((u32)f2bf(tanhf(hnv[p][1])) << 16);
      }
    }
  }
}

// 512 blocks: 0-255 tok phase (4rg x 64cg), 256-511 desc phase (4rg x 64cg).
// Both co-resident (2 blocks/CU: LDS 2x61.5KB, 8 waves/CU) -> phases overlap;
// desc's 50 generations hide under tok's 200.
__global__ void __launch_bounds__(256, 1) lstm_persist_kernel(PArgs A) {
  __shared__ __align__(16) u16 WhF[KC_H * 2 * 64 * 8];   // 32768 B
  __shared__ __align__(16) u16 WiF[KC_E * 2 * 64 * 8];   // 20480 B
  __shared__ __align__(16) float gsum[64 * 36];          // 9216 B
  __shared__ int idsL[128];                              // 512 B
  int bid = blockIdx.x;
  if (bid < 256) {
    u32* cnt = A.flags + ((bid >> 6) << 7);              // rowgroups 0-3
    lstm_phase<64, true>(bid, WhF, WiF, gsum, idsL, A.WhhT, A.WihT, A.embT,
                         A.tokens, nullptr, nullptr, nullptr,
                         A.tok_bih, A.tok_bhh, A.hA, A.hB, A.featB, nullptr,
                         cnt, TCc);
  } else {
    int b2 = bid - 256;
    u32* cnt = A.flags + ((4 + (b2 >> 6)) << 7);         // rowgroups 4-7
    lstm_phase<128, false>(b2, WhF, WiF, gsum, idsL, A.WhhD, A.WihD, A.embD,
                           A.desc_anchor, A.desc_neg, A.desc_anchor_len, A.desc_neg_len,
                           A.desc_bih, A.desc_bhh, A.hC, A.hD, nullptr, A.finals,
                           cnt, TDc);
  }
}

// ---------------- attention scores via MFMA ----------------
__global__ __launch_bounds__(256) void attn_scores_mfma(
    const u16* __restrict__ featB, const u32* __restrict__ WF,
    const float* __restrict__ attn_b, const float* __restrict__ attnS_W,
    const float* __restrict__ attnS_b, float* __restrict__ scores)
{
  __shared__ __align__(16) u16 Af[4 * 16 * 64 * 8];   // 65536 B (reused as red after)
  const int tid = threadIdx.x;
  const int m0 = blockIdx.x * 64;

  #pragma unroll
  for (int i = 0; i < 16; ++i) {
    int c = (i << 8) + tid;
    int r = c >> 6, kb = c & 63;
    uint4 v = *(const uint4*)(featB + (((size_t)(m0 + r)) << 9) + (kb << 3));
    int kc = kb >> 2, lf = (r & 15) + ((kb & 3) << 4);
    *(uint4*)(Af + ((((r >> 4) * 16 + kc) << 6 | lf) << 3)) = v;
  }
  __syncthreads();

  const int w = tid >> 6, l = tid & 63;
  const u16* WF16 = (const u16*)WF;
  float p[4][4] = {};
  for (int nc = w * 4; nc < w * 4 + 4; ++nc) {
    f32x4 acc[4][2];
    #pragma unroll
    for (int rh = 0; rh < 4; ++rh) {
      acc[rh][0] = (f32x4){0.f, 0.f, 0.f, 0.f};
      acc[rh][1] = (f32x4){0.f, 0.f, 0.f, 0.f};
    }
    #pragma unroll 4
    for (int kc = 0; kc < 16; ++kc) {
      bf16x8 b0 = *(const bf16x8*)(WF16 + ((size_t)((((nc << 4) + kc) << 1 | 0) << 6 | l) << 3));
      bf16x8 b1 = *(const bf16x8*)(WF16 + ((size_t)((((nc << 4) + kc) << 1 | 1) << 6 | l) << 3));
      #pragma unroll
      for (int rh = 0; rh < 4; ++rh) {
        bf16x8 a = *(const bf16x8*)(Af + (((rh * 16 + kc) << 6 | l) << 3));
        acc[rh][0] = __builtin_amdgcn_mfma_f32_16x16x32_bf16(a, b0, acc[rh][0], 0, 0, 0);
        acc[rh][1] = __builtin_amdgcn_mfma_f32_16x16x32_bf16(a, b1, acc[rh][1], 0, 0, 0);
      }
    }
    int c0 = (nc << 5) + (l & 15), c1 = c0 + 16;
    float bb0 = attn_b[c0], sw0 = attnS_W[c0];
    float bb1 = attn_b[c1], sw1 = attnS_W[c1];
    #pragma unroll
    for (int rh = 0; rh < 4; ++rh)
      #pragma unroll
      for (int j = 0; j < 4; ++j)
        p[rh][j] += tanhf(acc[rh][0][j] + bb0) * sw0 + tanhf(acc[rh][1][j] + bb1) * sw1;
  }
  __syncthreads();
  float* red = (float*)Af;   // 64 x 68
  #pragma unroll
  for (int rh = 0; rh < 4; ++rh)
    #pragma unroll
    for (int j = 0; j < 4; ++j)
      red[(rh * 16 + ((l >> 4) << 2) + j) * 68 + (w << 4) + (l & 15)] = p[rh][j];
  __syncthreads();
  if (tid < 64) {
    float s = attnS_b[0];
    #pragma unroll 8
    for (int q = 0; q < 64; ++q) s += red[tid * 68 + q];
    scores[m0 + tid] = s;
  }
}

// masked softmax over T=200 + weighted pooling of bf16 feat -> pooled (B,H) fp32
__global__ __launch_bounds__(256) void softmax_pool_kernel(
    const float* __restrict__ scores, const int* __restrict__ tok_len,
    const u16* __restrict__ featB, float* __restrict__ pooled)
{
  const int b = blockIdx.x;
  const int tid = threadIdx.x;
  __shared__ float wgt[TCc];
  __shared__ float red[256];
  const int len = tok_len[b];

  float myv = -1e30f;
  if (tid < TCc) {
    float s = scores[b * TCc + tid];
    myv = (tid < len) ? s : -1e9f;
    wgt[tid] = myv;
  }
  red[tid] = myv;
  __syncthreads();
  for (int s = 128; s > 0; s >>= 1) {
    if (tid < s) red[tid] = fmaxf(red[tid], red[tid + s]);
    __syncthreads();
  }
  const float mx = red[0];
  __syncthreads();
  float e = 0.f;
  if (tid < TCc) e = expf(wgt[tid] - mx);
  red[tid] = e;
  __syncthreads();
  for (int s = 128; s > 0; s >>= 1) {
    if (tid < s) red[tid] += red[tid + s];
    __syncthreads();
  }
  const float sum = red[0];
  __syncthreads();
  if (tid < TCc) wgt[tid] = e / sum;
  __syncthreads();

  const u32* featU = (const u32*)featB;
  float a0 = 0.f, a1 = 0.f;
  for (int t = 0; t < TCc; ++t) {
    u32 v = featU[((size_t)b * TCc + t) * 256 + tid];
    float wv = wgt[t];
    a0 = fmaf(wv, bf2f((u16)(v & 0xFFFF)), a0);
    a1 = fmaf(wv, bf2f((u16)(v >> 16)), a1);
  }
  pooled[((size_t)b << 9) + tid * 2] = a0;
  pooled[((size_t)b << 9) + tid * 2 + 1] = a1;
}

// C[m,n] = tanh(A[m,:] . W[n,:] + bias[n]); fp32, grid (M/64, N/64)
__global__ __launch_bounds__(256) void gemm_bias_tanh_kernel(
    const float* __restrict__ A, const float* __restrict__ Bw,
    const float* __restrict__ bias, float* __restrict__ C, int M, int N, int K)
{
  const int r0 = blockIdx.x * 64;
  const int n0 = blockIdx.y * 64;
  const int tid = threadIdx.x;
  const int tu = tid & 15;
  const int tm = tid >> 4;
  __shared__ float As[32][68];
  __shared__ float Bs[32][68];

  float acc[4][4] = {};
  for (int k0 = 0; k0 < K; k0 += 32) {
    #pragma unroll
    for (int i = 0; i < 2; ++i) {
      int lin = tid + (i << 8);
      int kq = lin & 7, m = lin >> 3;
      int k = k0 + (kq << 2);
      int r = r0 + m; if (r >= M) r = M - 1;
      float4 va = *(const float4*)&A[(size_t)r * K + k];
      float4 vb = *(const float4*)&Bw[(size_t)(n0 + m) * K + k];
      As[(kq << 2) + 0][m] = va.x; As[(kq << 2) + 1][m] = va.y;
      As[(kq << 2) + 2][m] = va.z; As[(kq << 2) + 3][m] = va.w;
      Bs[(kq << 2) + 0][m] = vb.x; Bs[(kq << 2) + 1][m] = vb.y;
      Bs[(kq << 2) + 2][m] = vb.z; Bs[(kq << 2) + 3][m] = vb.w;
    }
    __syncthreads();
    #pragma unroll
    for (int kk = 0; kk < 32; ++kk) {
      float4 a = *(const float4*)&As[kk][tm << 2];
      float4 b = *(const float4*)&Bs[kk][tu << 2];
      acc[0][0] = fmaf(a.x, b.x, acc[0][0]); acc[0][1] = fmaf(a.x, b.y, acc[0][1]);
      acc[0][2] = fmaf(a.x, b.z, acc[0][2]); acc[0][3] = fmaf(a.x, b.w, acc[0][3]);
      acc[1][0] = fmaf(a.y, b.x, acc[1][0]); acc[1][1] = fmaf(a.y, b.y, acc[1][1]);
      acc[1][2] = fmaf(a.y, b.z, acc[1][2]); acc[1][3] = fmaf(a.y, b.w, acc[1][3]);
      acc[2][0] = fmaf(a.z, b.x, acc[2][0]); acc[2][1] = fmaf(a.z, b.y, acc[2][1]);
      acc[2][2] = fmaf(a.z, b.z, acc[2][2]); acc[2][3] = fmaf(a.z, b.w, acc[2][3]);
      acc[3][0] = fmaf(a.w, b.x, acc[3][0]); acc[3][1] = fmaf(a.w, b.y, acc[3][1]);
      acc[3][2] = fmaf(a.w, b.z, acc[3][2]); acc[3][3] = fmaf(a.w, b.w, acc[3][3]);
    }
    __syncthreads();
  }
  float bj[4];
  #pragma unroll
  for (int j = 0; j < 4; ++j) bj[j] = bias[n0 + (tu << 2) + j];
  #pragma unroll
  for (int i = 0; i < 4; ++i) {
    int r = r0 + (tm << 2) + i;
    if (r < M) {
      float4 v;
      v.x = tanhf(acc[i][0] + bj[0]); v.y = tanhf(acc[i][1] + bj[1]);
      v.z = tanhf(acc[i][2] + bj[2]); v.w = tanhf(acc[i][3] + bj[3]);
      *(float4*)&C[(size_t)r * N + n0 + (tu << 2)] = v;
    }
  }
}

__global__ __launch_bounds__(256) void loss_kernel(
    const float* __restrict__ code, const float* __restrict__ finals, float* __restrict__ out)
{
  const int b = threadIdx.x;
  const float* cv = code + (size_t)b * Hc;
  const float* av = finals + (size_t)b * Hc;
  const float* nv = finals + (size_t)(BATCH + b) * Hc;
  float dca = 0, dcn = 0, ncc = 0, naa = 0, nnn = 0;
  for (int k = 0; k < Hc; ++k) {
    float c = cv[k], a = av[k], n = nv[k];
    dca = fmaf(c, a, dca);
    dcn = fmaf(c, n, dcn);
    ncc = fmaf(c, c, ncc);
    naa = fmaf(a, a, naa);
    nnn = fmaf(n, n, nnn);
  }
  float cos_a = dca / fmaxf(sqrtf(ncc) * sqrtf(naa), 1e-8f);
  float cos_n = dcn / fmaxf(sqrtf(ncc) * sqrtf(nnn), 1e-8f);
  float hinge = fmaxf(0.6f - cos_a + cos_n, 1e-6f);
  __shared__ float red[256];
  red[b] = hinge;
  __syncthreads();
  for (int s = 128; s > 0; s >>= 1) {
    if (b < s) red[b] += red[b + s];
    __syncthreads();
  }
  if (b == 0) out[0] = red[0] / 256.0f;
}

extern "C" void kernel_launch(void* const* d_in, const int* in_sizes, int n_in,
                              void* d_out, int out_size, void* d_ws, size_t ws_size,
                              hipStream_t stream) {
  const int* tokens          = (const int*)d_in[0];
  const int* tok_len         = (const int*)d_in[1];
  const int* desc_anchor     = (const int*)d_in[2];
  const int* desc_anchor_len = (const int*)d_in[3];
  const int* desc_neg        = (const int*)d_in[4];
  const int* desc_neg_len    = (const int*)d_in[5];
  const float* tok_emb  = (const float*)d_in[6];
  const float* tok_Wih  = (const float*)d_in[7];
  const float* tok_Whh  = (const float*)d_in[8];
  const float* tok_bih  = (const float*)d_in[9];
  const float* tok_bhh  = (const float*)d_in[10];
  const float* desc_emb = (const float*)d_in[11];
  const float* desc_Wih = (const float*)d_in[12];
  const float* desc_Whh = (const float*)d_in[13];
  const float* desc_bih = (const float*)d_in[14];
  const float* desc_bhh = (const float*)d_in[15];
  const float* attn_W   = (const float*)d_in[16];
  const float* attn_b   = (const float*)d_in[17];
  const float* attnS_W  = (const float*)d_in[18];
  const float* attnS_b  = (const float*)d_in[19];
  const float* out_W1   = (const float*)d_in[20];
  const float* out_b1   = (const float*)d_in[21];
  const float* out_W2   = (const float*)d_in[22];
  const float* out_b2   = (const float*)d_in[23];

  float* p = (float*)d_ws;
  size_t off = 0;
  auto alloc = [&](size_t n) { float* q = p + off; off += n; return q; };

  u16*  featB  = (u16*)alloc(13107200);     // 256*200*512 bf16
  u16*  embT   = (u16*)alloc(1600000);      // VOC*320 bf16
  u16*  embD   = (u16*)alloc(1600000);
  u32*  WihT   = (u32*)alloc(327680);       // 64nc * 10kc * 2si * 64 * 4
  u32*  WihD   = (u32*)alloc(327680);
  u32*  WhhT   = (u32*)alloc(524288);       // 64nc * 16kc * 2si * 64 * 4
  u32*  WhhD   = (u32*)alloc(524288);
  u32*  attnWF = (u32*)alloc(131072);       // 16nc * 16kc * 2si * 64 * 4
  u16*  hA     = (u16*)alloc(65536);        // 256*512 bf16
  u16*  hB     = (u16*)alloc(65536);
  u16*  hC     = (u16*)alloc(131072);       // 512*512 bf16
  u16*  hD     = (u16*)alloc(131072);
  float* finals = alloc(262144);            // 512*512 fp32
  float* scores = alloc(51200);
  float* pooled = alloc(131072);
  float* a2     = alloc(131072);
  float* code   = alloc(131072);
  u32* flags = (u32*)alloc(1024);           // 8 rowgroups x 8 counters x 64B spacing

  // weight / embedding conversions
  conv_emb_kernel<<<(VOC * (EPAD / 2) + 255) / 256, 256, 0, stream>>>(tok_emb, (u32*)embT);
  conv_emb_kernel<<<(VOC * (EPAD / 2) + 255) / 256, 256, 0, stream>>>(desc_emb, (u32*)embD);
  conv_wfrag_kernel<1><<<2048, 256, 0, stream>>>(tok_Whh, WhhT, KC_H, Hc, 524288);
  conv_wfrag_kernel<1><<<2048, 256, 0, stream>>>(desc_Whh, WhhD, KC_H, Hc, 524288);
  conv_wfrag_kernel<1><<<1280, 256, 0, stream>>>(tok_Wih, WihT, KC_E, Ec, 327680);
  conv_wfrag_kernel<1><<<1280, 256, 0, stream>>>(desc_Wih, WihD, KC_E, Ec, 327680);
  conv_wfrag_kernel<0><<<512, 256, 0, stream>>>(attn_W, attnWF, KC_H, Hc, 131072);
  zero_kernel<<<4, 256, 0, stream>>>((float*)flags, 1024);

  PArgs A;
  A.WhhT = WhhT; A.WihT = WihT; A.embT = embT;
  A.WhhD = WhhD; A.WihD = WihD; A.embD = embD;
  A.tokens = tokens; A.desc_anchor = desc_anchor; A.desc_neg = desc_neg;
  A.desc_anchor_len = desc_anchor_len; A.desc_neg_len = desc_neg_len;
  A.tok_bih = tok_bih; A.tok_bhh = tok_bhh;
  A.desc_bih = desc_bih; A.desc_bhh = desc_bhh;
  A.hA = hA; A.hB = hB; A.hC = hC; A.hD = hD;
  A.featB = featB; A.finals = finals; A.flags = flags;
  lstm_persist_kernel<<<512, 256, 0, stream>>>(A);

  attn_scores_mfma<<<(BATCH * TCc) / 64, 256, 0, stream>>>(
      featB, attnWF, attn_b, attnS_W, attnS_b, scores);
  softmax_pool_kernel<<<BATCH, 256, 0, stream>>>(scores, tok_len, featB, pooled);
  gemm_bias_tanh_kernel<<<dim3(BATCH / 64, Hc / 64), 256, 0, stream>>>(
      pooled, out_W1, out_b1, a2, BATCH, Hc, Hc);
  gemm_bias_tanh_kernel<<<dim3(BATCH / 64, Hc / 64), 256, 0, stream>>>(
      a2, out_W2, out_b2, code, BATCH, Hc, Hc);
  loss_kernel<<<1, 256, 0, stream>>>(code, finals, (float*)d_out);
}

// Round 12
// 1319.104 us; speedup vs baseline: 11.2300x; 1.5239x over previous
//
#include <hip/hip_runtime.h>
#include <hip/hip_bf16.h>
#include <math.h>

#define TCc 200
#define TDc 50
#define BATCH 256
#define Ec 300
#define Hc 512
#define VOC 10000
#define EPAD 320
#define KC_E 10
#define KC_H 16

typedef unsigned short u16;
typedef unsigned int u32;
typedef unsigned long long u64;
typedef __bf16 bf16x8 __attribute__((ext_vector_type(8)));
typedef float f32x4 __attribute__((ext_vector_type(4)));

__device__ __forceinline__ float sigf(float x) { return 1.f / (1.f + expf(-x)); }

__device__ __forceinline__ u16 f2bf(float f) {
  unsigned u = __float_as_uint(f);
  unsigned r = (u + 0x7FFFu + ((u >> 16) & 1u)) >> 16;  // RNE
  return (u16)r;
}
__device__ __forceinline__ float bf2f(u16 v) { return __uint_as_float(((unsigned)v) << 16); }

// LLC-coherent access: relaxed agent-scope atomics — bare sc1 ops, no cache maintenance.
__device__ __forceinline__ void st_llc(u32* p, u32 v) {
  __hip_atomic_store(p, v, __ATOMIC_RELAXED, __HIP_MEMORY_SCOPE_AGENT);
}
__device__ __forceinline__ u32 ld_llc(const u32* p) {
  return __hip_atomic_load(p, __ATOMIC_RELAXED, __HIP_MEMORY_SCOPE_AGENT);
}
__device__ __forceinline__ u64 ld_llc64(const u64* p) {
  return __hip_atomic_load(p, __ATOMIC_RELAXED, __HIP_MEMORY_SCOPE_AGENT);
}
__device__ __forceinline__ bf16x8 pair_bf16x8(u64 a, u64 b) {
  union { u64 q[2]; bf16x8 v; } t; t.q[0] = a; t.q[1] = b; return t.v;
}

__global__ __launch_bounds__(256) void zero_kernel(float* p, int n) {
  int i = blockIdx.x * 256 + threadIdx.x;
  if (i < n) p[i] = 0.f;
}

// emb (VOC, Ec) fp32 -> (VOC, EPAD) bf16, zero-padded
__global__ __launch_bounds__(256) void conv_emb_kernel(
    const float* __restrict__ emb, u32* __restrict__ out)
{
  int e = blockIdx.x * 256 + threadIdx.x;          // u32 index, VOC*EPAD/2 total
  if (e >= VOC * (EPAD / 2)) return;
  int v = e / (EPAD / 2);
  int k = (e - v * (EPAD / 2)) * 2;
  float a = (k < Ec) ? emb[(size_t)v * Ec + k] : 0.f;
  float b = (k + 1 < Ec) ? emb[(size_t)v * Ec + k + 1] : 0.f;
  out[e] = (u32)f2bf(a) | ((u32)f2bf(b) << 16);
}

// Weight (rows x K) fp32 -> MFMA B-fragment order bf16.
// Frag layout: [nc][kc][si][lane 64][8 bf16]; col-in-group c32 = si*16 + (lane&15);
// k = kc*32 + (lane>>4)*8 + jj.
// GATES: position ul'=c32>>2, g=c32&3; actual unit = ((ul'&3)<<1)|(ul'>>2); source row
// = g*512 + nc*8 + unit. Else: source row = nc*32 + c32.
template<int GATES>
__global__ __launch_bounds__(256) void conv_wfrag_kernel(
    const float* __restrict__ W, u32* __restrict__ out, int KC, int KREAL, int total)
{
  int e = blockIdx.x * 256 + threadIdx.x;          // u32 index
  if (e >= total) return;
  int jp = e & 3;
  int l = (e >> 2) & 63;
  int si = (e >> 8) & 1;
  int t2 = e >> 9;
  int kc = t2 % KC;
  int nc = t2 / KC;
  int c32 = (si << 4) + (l & 15);
  int srow;
  if (GATES) {
    int ulp = c32 >> 2, g = c32 & 3;
    int unit = ((ulp & 3) << 1) | (ulp >> 2);
    srow = (g << 9) + nc * 8 + unit;
  } else {
    srow = nc * 32 + c32;
  }
  int k = (kc << 5) + ((l >> 4) << 3) + (jp << 1);
  float a = (k < KREAL) ? W[(size_t)srow * KREAL + k] : 0.f;
  float b = (k + 1 < KREAL) ? W[(size_t)srow * KREAL + k + 1] : 0.f;
  out[e] = (u32)f2bf(a) | ((u32)f2bf(b) << 16);
}

// ---------------- persistent MFMA LSTM ----------------
// Barrier split into signal/wait with 8-way counter striping per rowgroup.
__device__ __forceinline__ void bar_signal(u32* cnt, int cg) {
  asm volatile("s_waitcnt vmcnt(0)" ::: "memory");
  __syncthreads();
  if (threadIdx.x == 0)
    __hip_atomic_fetch_add(cnt + ((cg & 7) << 4), 1u,
                           __ATOMIC_RELAXED, __HIP_MEMORY_SCOPE_AGENT);
}
__device__ __forceinline__ void bar_wait(u32* cnt, u32 target) {
  if (threadIdx.x < 8) {
    while (ld_llc(cnt + ((int)threadIdx.x << 4)) < target)
      __builtin_amdgcn_s_sleep(1);
  }
  __syncthreads();
}

struct PArgs {
  const u32* WhhT; const u32* WihT; const u16* embT;
  const u32* WhhD; const u32* WihD; const u16* embD;
  const int* tokens; const int* desc_anchor; const int* desc_neg;
  const int* desc_anchor_len; const int* desc_neg_len;
  const float* tok_bih; const float* tok_bhh;
  const float* desc_bih; const float* desc_bhh;
  u16* hA; u16* hB; u16* hC; u16* hD;
  u16* featB; float* finals;
  u32* flags;
};

// Phase: lbid in [0,256): 4 rowgroups x 64 colgroups (8 units = 32 gate-cols each).
// ROWS=64 (tok) / 128 (desc). RPW = ROWS/64 row-halves per wave.
// h exchange buffers are in MFMA A-FRAGMENT ORDER per rowgroup:
//   [rhp = localrow>>4][kc 16][lane 64][8 bf16], so consumer lane l reads its 16B
//   contiguously ((64 lanes x 16B = 1KB/instr) -> coalesced LLC traffic).
//   (row,col) -> kc=col>>5, lane=(row&15)|(((col>>3)&3)<<4), j=col&7.
// h0/h1 passed ALREADY OFFSET to this rowgroup's buffer base.
template<int ROWS, bool IS_TOK>
__device__ void lstm_phase(
    int lbid, u16* WhF, u16* WiF, float* gsum, int* idsL,
    const u32* __restrict__ WhhF, const u32* __restrict__ WihF, const u16* __restrict__ embB,
    const int* __restrict__ idsA, const int* __restrict__ idsB,
    const int* __restrict__ lenA, const int* __restrict__ lenB,
    const float* __restrict__ bih, const float* __restrict__ bhh,
    u16* __restrict__ h0, u16* __restrict__ h1,
    u16* __restrict__ featB, float* __restrict__ finals,
    u32* cnt, int T)
{
  constexpr int RPW = ROWS / 64;
  const int tid = threadIdx.x;
  const int cg = lbid & 63;
  const int row0 = (lbid >> 6) * ROWS;
  const int w = tid >> 6, l = tid & 63;
  const int rl = tid >> 2, u = tid & 3;
  int gen = 0;

  // stage weight fragments into LDS
  {
    const uint4* s = (const uint4*)(WhhF + ((size_t)cg << 13));   // cg*8192 u32
    uint4* d = (uint4*)WhF;
    #pragma unroll
    for (int i = 0; i < 8; ++i) d[(i << 8) + tid] = s[(i << 8) + tid];
    const uint4* s2 = (const uint4*)(WihF + (size_t)cg * 5120);
    uint4* d2 = (uint4*)WiF;
    #pragma unroll
    for (int i = 0; i < 5; ++i) d2[(i << 8) + tid] = s2[(i << 8) + tid];
  }

  // units owned by this epilogue thread: ug0 = cg*8 + 2u, ug1 = ug0+1 (adjacent)
  const int ug0 = (cg << 3) + (u << 1);
  float bsv[2][4];
  #pragma unroll
  for (int uu = 0; uu < 2; ++uu)
    #pragma unroll
    for (int g = 0; g < 4; ++g)
      bsv[uu][g] = bih[(g << 9) + ug0 + uu] + bhh[(g << 9) + ug0 + uu];

  // producer fragment-store offset pieces (row part added per p)
  const int kcs   = ug0 >> 5;
  const int lanehi = (ug0 >> 3) & 3;
  const int jpos  = ug0 & 7;   // even

  float cc[RPW][2];
  int lens[RPW];
  #pragma unroll
  for (int p = 0; p < RPW; ++p) {
    cc[p][0] = 0.f; cc[p][1] = 0.f;
    int lrow = (p << 6) + rl;             // local row in rowgroup
    int row = row0 + lrow;
    lens[p] = IS_TOK ? 0 : ((row < BATCH) ? lenA[row] : lenB[row - BATCH]);
    int rhp = lrow >> 4;
    int lane_s = (rl & 15) | (lanehi << 4);
    size_t off16 = ((((size_t)rhp << 4) + kcs) << 6 | lane_s) << 3 | jpos;
    st_llc((u32*)(h0 + off16), 0u);
  }
  bar_signal(cnt, cg); ++gen;   // zeros visible

  for (int t = 0; t < T; ++t) {
    const u16* hin = (t & 1) ? h1 : h0;
    u16* hout = (t & 1) ? h0 : h1;

    if (tid < ROWS) {
      int row = row0 + tid;
      idsL[tid] = IS_TOK ? idsA[row * T + t]
                         : ((row < BATCH) ? idsA[row * T + t] : idsB[(row - BATCH) * T + t]);
    }
    __syncthreads();

    f32x4 acc[RPW][2];
    #pragma unroll
    for (int p = 0; p < RPW; ++p) {
      acc[p][0] = (f32x4){0.f, 0.f, 0.f, 0.f};
      acc[p][1] = (f32x4){0.f, 0.f, 0.f, 0.f};
    }
    const u16* eb[RPW];
    const u64* hfb[RPW];
    #pragma unroll
    for (int p = 0; p < RPW; ++p) {
      int rhp = w + (p << 2);
      int ida = idsL[(rhp << 4) + (l & 15)];
      eb[p] = embB + (size_t)ida * EPAD + ((l >> 4) << 3);
      // fragment base at kc=0: u64 index = (((rhp<<4)+kc)<<6 | l) * 2
      hfb[p] = (const u64*)hin + ((((size_t)rhp << 4) << 6 | l) << 1);
    }

    // ---- h-independent input-projection MFMAs FIRST (overlap others' arrivals) ----
    #pragma unroll
    for (int kc = 0; kc < KC_E; ++kc) {
      bf16x8 b0 = *(const bf16x8*)(WiF + ((((kc << 1) | 0) << 6 | l) << 3));
      bf16x8 b1 = *(const bf16x8*)(WiF + ((((kc << 1) | 1) << 6 | l) << 3));
      #pragma unroll
      for (int p = 0; p < RPW; ++p) {
        bf16x8 a = *(const bf16x8*)(eb[p] + (kc << 5));
        acc[p][0] = __builtin_amdgcn_mfma_f32_16x16x32_bf16(a, b0, acc[p][0], 0, 0, 0);
        acc[p][1] = __builtin_amdgcn_mfma_f32_16x16x32_bf16(a, b1, acc[p][1], 0, 0, 0);
      }
    }

    // ---- wait for h(t-1) visibility ----
    bar_wait(cnt, (u32)gen * 8u);

    // ---- prefetch h (fragment layout, coalesced), then recurrent MFMAs ----
    u64 hw[RPW][2 * KC_H];
    #pragma unroll
    for (int p = 0; p < RPW; ++p)
      #pragma unroll
      for (int kc = 0; kc < KC_H; ++kc) {
        hw[p][2 * kc]     = ld_llc64(hfb[p] + (kc << 7));
        hw[p][2 * kc + 1] = ld_llc64(hfb[p] + (kc << 7) + 1);
      }
    #pragma unroll
    for (int kc = 0; kc < KC_H; ++kc) {
      bf16x8 b0 = *(const bf16x8*)(WhF + ((((kc << 1) | 0) << 6 | l) << 3));
      bf16x8 b1 = *(const bf16x8*)(WhF + ((((kc << 1) | 1) << 6 | l) << 3));
      #pragma unroll
      for (int p = 0; p < RPW; ++p) {
        bf16x8 a = pair_bf16x8(hw[p][2 * kc], hw[p][2 * kc + 1]);
        acc[p][0] = __builtin_amdgcn_mfma_f32_16x16x32_bf16(a, b0, acc[p][0], 0, 0, 0);
        acc[p][1] = __builtin_amdgcn_mfma_f32_16x16x32_bf16(a, b1, acc[p][1], 0, 0, 0);
      }
    }

    // ---- epilogue: gates, c/h update; h stored in fragment order, feat deferred ----
    float hnv[RPW][2];
    #pragma unroll
    for (int p = 0; p < RPW; ++p) {
      int lr0 = (w << 4) + ((l >> 4) << 2);
      #pragma unroll
      for (int si = 0; si < 2; ++si)
        #pragma unroll
        for (int j = 0; j < 4; ++j)
          gsum[(lr0 + j) * 36 + (si << 4) + (l & 15)] = acc[p][si][j];
      __syncthreads();
      {
        float4 g0 = *(const float4*)&gsum[rl * 36 + (u << 2)];          // unit 2u
        float4 g1 = *(const float4*)&gsum[rl * 36 + ((u + 4) << 2)];    // unit 2u+1
        int lrow = (p << 6) + rl;
        int row = row0 + lrow;
        float gi0 = sigf(g0.x + bsv[0][0]);
        float gf0 = sigf(g0.y + bsv[0][1]);
        float gg0 = tanhf(g0.z + bsv[0][2]);
        float go0 = sigf(g0.w + bsv[0][3]);
        float cn0 = gf0 * cc[p][0] + gi0 * gg0;
        cc[p][0] = cn0;
        float hn0 = go0 * tanhf(cn0);
        float gi1 = sigf(g1.x + bsv[1][0]);
        float gf1 = sigf(g1.y + bsv[1][1]);
        float gg1 = tanhf(g1.z + bsv[1][2]);
        float go1 = sigf(g1.w + bsv[1][3]);
        float cn1 = gf1 * cc[p][1] + gi1 * gg1;
        cc[p][1] = cn1;
        float hn1 = go1 * tanhf(cn1);
        hnv[p][0] = hn0; hnv[p][1] = hn1;
        int rhp = lrow >> 4;
        int lane_s = (rl & 15) | (lanehi << 4);
        size_t off16 = ((((size_t)rhp << 4) + kcs) << 6 | lane_s) << 3 | jpos;
        st_llc((u32*)(hout + off16), (u32)f2bf(hn0) | ((u32)f2bf(hn1) << 16));
        if (!IS_TOK) {
          if (t == lens[p] - 1) {
            finals[((size_t)row << 9) + ug0]     = tanhf(hn0);
            finals[((size_t)row << 9) + ug0 + 1] = tanhf(hn1);
          }
        }
      }
      __syncthreads();
    }
    bar_signal(cnt, cg); ++gen;   // h(t) visible

    if (IS_TOK) {
      // feat = tanh(h) stores (normal cached path), off the inter-block critical path
      #pragma unroll
      for (int p = 0; p < RPW; ++p) {
        int row = row0 + (p << 6) + rl;
        size_t fo = ((size_t)row * TCc + t) << 9;
        *(u32*)(featB + fo + ug0) =
            (u32)f2bf(tanhf(hnv[p][0])) | ((u32)f2bf(tanhf(hnv[p][1])) << 16);
      }
    }
  }
}

// 512 blocks: 0-255 tok phase (4rg x 64cg), 256-511 desc phase (4rg x 64cg).
// 2 blocks/CU co-resident -> phases overlap; desc's 50 gens hide under tok's 200.
__global__ void __launch_bounds__(256, 1) lstm_persist_kernel(PArgs A) {
  __shared__ __align__(16) u16 WhF[KC_H * 2 * 64 * 8];   // 32768 B
  __shared__ __align__(16) u16 WiF[KC_E * 2 * 64 * 8];   // 20480 B
  __shared__ __align__(16) float gsum[64 * 36];          // 9216 B
  __shared__ int idsL[128];                              // 512 B
  int bid = blockIdx.x;
  if (bid < 256) {
    u32* cnt = A.flags + ((bid >> 6) << 7);              // rowgroups 0-3
    size_t hoff = (size_t)(bid >> 6) << 15;              // 32768 u16 per tok rowgroup
    lstm_phase<64, true>(bid, WhF, WiF, gsum, idsL, A.WhhT, A.WihT, A.embT,
                         A.tokens, nullptr, nullptr, nullptr,
                         A.tok_bih, A.tok_bhh, A.hA + hoff, A.hB + hoff, A.featB, nullptr,
                         cnt, TCc);
  } else {
    int b2 = bid - 256;
    u32* cnt = A.flags + ((4 + (b2 >> 6)) << 7);         // rowgroups 4-7
    size_t hoff = (size_t)(b2 >> 6) << 16;               // 65536 u16 per desc rowgroup
    lstm_phase<128, false>(b2, WhF, WiF, gsum, idsL, A.WhhD, A.WihD, A.embD,
                           A.desc_anchor, A.desc_neg, A.desc_anchor_len, A.desc_neg_len,
                           A.desc_bih, A.desc_bhh, A.hC + hoff, A.hD + hoff, nullptr, A.finals,
                           cnt, TDc);
  }
}

// ---------------- attention scores via MFMA ----------------
__global__ __launch_bounds__(256) void attn_scores_mfma(
    const u16* __restrict__ featB, const u32* __restrict__ WF,
    const float* __restrict__ attn_b, const float* __restrict__ attnS_W,
    const float* __restrict__ attnS_b, float* __restrict__ scores)
{
  __shared__ __align__(16) u16 Af[4 * 16 * 64 * 8];   // 65536 B (reused as red after)
  const int tid = threadIdx.x;
  const int m0 = blockIdx.x * 64;

  #pragma unroll
  for (int i = 0; i < 16; ++i) {
    int c = (i << 8) + tid;
    int r = c >> 6, kb = c & 63;
    uint4 v = *(const uint4*)(featB + (((size_t)(m0 + r)) << 9) + (kb << 3));
    int kc = kb >> 2, lf = (r & 15) + ((kb & 3) << 4);
    *(uint4*)(Af + ((((r >> 4) * 16 + kc) << 6 | lf) << 3)) = v;
  }
  __syncthreads();

  const int w = tid >> 6, l = tid & 63;
  const u16* WF16 = (const u16*)WF;
  float p[4][4] = {};
  for (int nc = w * 4; nc < w * 4 + 4; ++nc) {
    f32x4 acc[4][2];
    #pragma unroll
    for (int rh = 0; rh < 4; ++rh) {
      acc[rh][0] = (f32x4){0.f, 0.f, 0.f, 0.f};
      acc[rh][1] = (f32x4){0.f, 0.f, 0.f, 0.f};
    }
    #pragma unroll 4
    for (int kc = 0; kc < 16; ++kc) {
      bf16x8 b0 = *(const bf16x8*)(WF16 + ((size_t)((((nc << 4) + kc) << 1 | 0) << 6 | l) << 3));
      bf16x8 b1 = *(const bf16x8*)(WF16 + ((size_t)((((nc << 4) + kc) << 1 | 1) << 6 | l) << 3));
      #pragma unroll
      for (int rh = 0; rh < 4; ++rh) {
        bf16x8 a = *(const bf16x8*)(Af + (((rh * 16 + kc) << 6 | l) << 3));
        acc[rh][0] = __builtin_amdgcn_mfma_f32_16x16x32_bf16(a, b0, acc[rh][0], 0, 0, 0);
        acc[rh][1] = __builtin_amdgcn_mfma_f32_16x16x32_bf16(a, b1, acc[rh][1], 0, 0, 0);
      }
    }
    int c0 = (nc << 5) + (l & 15), c1 = c0 + 16;
    float bb0 = attn_b[c0], sw0 = attnS_W[c0];
    float bb1 = attn_b[c1], sw1 = attnS_W[c1];
    #pragma unroll
    for (int rh = 0; rh < 4; ++rh)
      #pragma unroll
      for (int j = 0; j < 4; ++j)
        p[rh][j] += tanhf(acc[rh][0][j] + bb0) * sw0 + tanhf(acc[rh][1][j] + bb1) * sw1;
  }
  __syncthreads();
  float* red = (float*)Af;   // 64 x 68
  #pragma unroll
  for (int rh = 0; rh < 4; ++rh)
    #pragma unroll
    for (int j = 0; j < 4; ++j)
      red[(rh * 16 + ((l >> 4) << 2) + j) * 68 + (w << 4) + (l & 15)] = p[rh][j];
  __syncthreads();
  if (tid < 64) {
    float s = attnS_b[0];
    #pragma unroll 8
    for (int q = 0; q < 64; ++q) s += red[tid * 68 + q];
    scores[m0 + tid] = s;
  }
}

// masked softmax over T=200 + weighted pooling of bf16 feat -> pooled (B,H) fp32
__global__ __launch_bounds__(256) void softmax_pool_kernel(
    const float* __restrict__ scores, const int* __restrict__ tok_len,
    const u16* __restrict__ featB, float* __restrict__ pooled)
{
  const int b = blockIdx.x;
  const int tid = threadIdx.x;
  __shared__ float wgt[TCc];
  __shared__ float red[256];
  const int len = tok_len[b];

  float myv = -1e30f;
  if (tid < TCc) {
    float s = scores[b * TCc + tid];
    myv = (tid < len) ? s : -1e9f;
    wgt[tid] = myv;
  }
  red[tid] = myv;
  __syncthreads();
  for (int s = 128; s > 0; s >>= 1) {
    if (tid < s) red[tid] = fmaxf(red[tid], red[tid + s]);
    __syncthreads();
  }
  const float mx = red[0];
  __syncthreads();
  float e = 0.f;
  if (tid < TCc) e = expf(wgt[tid] - mx);
  red[tid] = e;
  __syncthreads();
  for (int s = 128; s > 0; s >>= 1) {
    if (tid < s) red[tid] += red[tid + s];
    __syncthreads();
  }
  const float sum = red[0];
  __syncthreads();
  if (tid < TCc) wgt[tid] = e / sum;
  __syncthreads();

  const u32* featU = (const u32*)featB;
  float a0 = 0.f, a1 = 0.f;
  for (int t = 0; t < TCc; ++t) {
    u32 v = featU[((size_t)b * TCc + t) * 256 + tid];
    float wv = wgt[t];
    a0 = fmaf(wv, bf2f((u16)(v & 0xFFFF)), a0);
    a1 = fmaf(wv, bf2f((u16)(v >> 16)), a1);
  }
  pooled[((size_t)b << 9) + tid * 2] = a0;
  pooled[((size_t)b << 9) + tid * 2 + 1] = a1;
}

// C[m,n] = tanh(A[m,:] . W[n,:] + bias[n]); fp32, grid (M/64, N/64)
__global__ __launch_bounds__(256) void gemm_bias_tanh_kernel(
    const float* __restrict__ A, const float* __restrict__ Bw,
    const float* __restrict__ bias, float* __restrict__ C, int M, int N, int K)
{
  const int r0 = blockIdx.x * 64;
  const int n0 = blockIdx.y * 64;
  const int tid = threadIdx.x;
  const int tu = tid & 15;
  const int tm = tid >> 4;
  __shared__ float As[32][68];
  __shared__ float Bs[32][68];

  float acc[4][4] = {};
  for (int k0 = 0; k0 < K; k0 += 32) {
    #pragma unroll
    for (int i = 0; i < 2; ++i) {
      int lin = tid + (i << 8);
      int kq = lin & 7, m = lin >> 3;
      int k = k0 + (kq << 2);
      int r = r0 + m; if (r >= M) r = M - 1;
      float4 va = *(const float4*)&A[(size_t)r * K + k];
      float4 vb = *(const float4*)&Bw[(size_t)(n0 + m) * K + k];
      As[(kq << 2) + 0][m] = va.x; As[(kq << 2) + 1][m] = va.y;
      As[(kq << 2) + 2][m] = va.z; As[(kq << 2) + 3][m] = va.w;
      Bs[(kq << 2) + 0][m] = vb.x; Bs[(kq << 2) + 1][m] = vb.y;
      Bs[(kq << 2) + 2][m] = vb.z; Bs[(kq << 2) + 3][m] = vb.w;
    }
    __syncthreads();
    #pragma unroll
    for (int kk = 0; kk < 32; ++kk) {
      float4 a = *(const float4*)&As[kk][tm << 2];
      float4 b = *(const float4*)&Bs[kk][tu << 2];
      acc[0][0] = fmaf(a.x, b.x, acc[0][0]); acc[0][1] = fmaf(a.x, b.y, acc[0][1]);
      acc[0][2] = fmaf(a.x, b.z, acc[0][2]); acc[0][3] = fmaf(a.x, b.w, acc[0][3]);
      acc[1][0] = fmaf(a.y, b.x, acc[1][0]); acc[1][1] = fmaf(a.y, b.y, acc[1][1]);
      acc[1][2] = fmaf(a.y, b.z, acc[1][2]); acc[1][3] = fmaf(a.y, b.w, acc[1][3]);
      acc[2][0] = fmaf(a.z, b.x, acc[2][0]); acc[2][1] = fmaf(a.z, b.y, acc[2][1]);
      acc[2][2] = fmaf(a.z, b.z, acc[2][2]); acc[2][3] = fmaf(a.z, b.w, acc[2][3]);
      acc[3][0] = fmaf(a.w, b.x, acc[3][0]); acc[3][1] = fmaf(a.w, b.y, acc[3][1]);
      acc[3][2] = fmaf(a.w, b.z, acc[3][2]); acc[3][3] = fmaf(a.w, b.w, acc[3][3]);
    }
    __syncthreads();
  }
  float bj[4];
  #pragma unroll
  for (int j = 0; j < 4; ++j) bj[j] = bias[n0 + (tu << 2) + j];
  #pragma unroll
  for (int i = 0; i < 4; ++i) {
    int r = r0 + (tm << 2) + i;
    if (r < M) {
      float4 v;
      v.x = tanhf(acc[i][0] + bj[0]); v.y = tanhf(acc[i][1] + bj[1]);
      v.z = tanhf(acc[i][2] + bj[2]); v.w = tanhf(acc[i][3] + bj[3]);
      *(float4*)&C[(size_t)r * N + n0 + (tu << 2)] = v;
    }
  }
}

__global__ __launch_bounds__(256) void loss_kernel(
    const float* __restrict__ code, const float* __restrict__ finals, float* __restrict__ out)
{
  const int b = threadIdx.x;
  const float* cv = code + (size_t)b * Hc;
  const float* av = finals + (size_t)b * Hc;
  const float* nv = finals + (size_t)(BATCH + b) * Hc;
  float dca = 0, dcn = 0, ncc = 0, naa = 0, nnn = 0;
  for (int k = 0; k < Hc; ++k) {
    float c = cv[k], a = av[k], n = nv[k];
    dca = fmaf(c, a, dca);
    dcn = fmaf(c, n, dcn);
    ncc = fmaf(c, c, ncc);
    naa = fmaf(a, a, naa);
    nnn = fmaf(n, n, nnn);
  }
  float cos_a = dca / fmaxf(sqrtf(ncc) * sqrtf(naa), 1e-8f);
  float cos_n = dcn / fmaxf(sqrtf(ncc) * sqrtf(nnn), 1e-8f);
  float hinge = fmaxf(0.6f - cos_a + cos_n, 1e-6f);
  __shared__ float red[256];
  red[b] = hinge;
  __syncthreads();
  for (int s = 128; s > 0; s >>= 1) {
    if (b < s) red[b] += red[b + s];
    __syncthreads();
  }
  if (b == 0) out[0] = red[0] / 256.0f;
}

extern "C" void kernel_launch(void* const* d_in, const int* in_sizes, int n_in,
                              void* d_out, int out_size, void* d_ws, size_t ws_size,
                              hipStream_t stream) {
  const int* tokens          = (const int*)d_in[0];
  const int* tok_len         = (const int*)d_in[1];
  const int* desc_anchor     = (const int*)d_in[2];
  const int* desc_anchor_len = (const int*)d_in[3];
  const int* desc_neg        = (const int*)d_in[4];
  const int* desc_neg_len    = (const int*)d_in[5];
  const float* tok_emb  = (const float*)d_in[6];
  const float* tok_Wih  = (const float*)d_in[7];
  const float* tok_Whh  = (const float*)d_in[8];
  const float* tok_bih  = (const float*)d_in[9];
  const float* tok_bhh  = (const float*)d_in[10];
  const float* desc_emb = (const float*)d_in[11];
  const float* desc_Wih = (const float*)d_in[12];
  const float* desc_Whh = (const float*)d_in[13];
  const float* desc_bih = (const float*)d_in[14];
  const float* desc_bhh = (const float*)d_in[15];
  const float* attn_W   = (const float*)d_in[16];
  const float* attn_b   = (const float*)d_in[17];
  const float* attnS_W  = (const float*)d_in[18];
  const float* attnS_b  = (const float*)d_in[19];
  const float* out_W1   = (const float*)d_in[20];
  const float* out_b1   = (const float*)d_in[21];
  const float* out_W2   = (const float*)d_in[22];
  const float* out_b2   = (const float*)d_in[23];

  float* p = (float*)d_ws;
  size_t off = 0;
  auto alloc = [&](size_t n) { float* q = p + off; off += n; return q; };

  u16*  featB  = (u16*)alloc(13107200);     // 256*200*512 bf16
  u16*  embT   = (u16*)alloc(1600000);      // VOC*320 bf16
  u16*  embD   = (u16*)alloc(1600000);
  u32*  WihT   = (u32*)alloc(327680);       // 64nc * 10kc * 2si * 64 * 4
  u32*  WihD   = (u32*)alloc(327680);
  u32*  WhhT   = (u32*)alloc(524288);       // 64nc * 16kc * 2si * 64 * 4
  u32*  WhhD   = (u32*)alloc(524288);
  u32*  attnWF = (u32*)alloc(131072);       // 16nc * 16kc * 2si * 64 * 4
  u16*  hA     = (u16*)alloc(65536);        // tok h frag: 4rg x 32768 u16
  u16*  hB     = (u16*)alloc(65536);
  u16*  hC     = (u16*)alloc(131072);       // desc h frag: 4rg x 65536 u16
  u16*  hD     = (u16*)alloc(131072);
  float* finals = alloc(262144);            // 512*512 fp32
  float* scores = alloc(51200);
  float* pooled = alloc(131072);
  float* a2     = alloc(131072);
  float* code   = alloc(131072);
  u32* flags = (u32*)alloc(1024);           // 8 rowgroups x 8 counters x 64B spacing

  // weight / embedding conversions
  conv_emb_kernel<<<(VOC * (EPAD / 2) + 255) / 256, 256, 0, stream>>>(tok_emb, (u32*)embT);
  conv_emb_kernel<<<(VOC * (EPAD / 2) + 255) / 256, 256, 0, stream>>>(desc_emb, (u32*)embD);
  conv_wfrag_kernel<1><<<2048, 256, 0, stream>>>(tok_Whh, WhhT, KC_H, Hc, 524288);
  conv_wfrag_kernel<1><<<2048, 256, 0, stream>>>(desc_Whh, WhhD, KC_H, Hc, 524288);
  conv_wfrag_kernel<1><<<1280, 256, 0, stream>>>(tok_Wih, WihT, KC_E, Ec, 327680);
  conv_wfrag_kernel<1><<<1280, 256, 0, stream>>>(desc_Wih, WihD, KC_E, Ec, 327680);
  conv_wfrag_kernel<0><<<512, 256, 0, stream>>>(attn_W, attnWF, KC_H, Hc, 131072);
  zero_kernel<<<4, 256, 0, stream>>>((float*)flags, 1024);

  PArgs A;
  A.WhhT = WhhT; A.WihT = WihT; A.embT = embT;
  A.WhhD = WhhD; A.WihD = WihD; A.embD = embD;
  A.tokens = tokens; A.desc_anchor = desc_anchor; A.desc_neg = desc_neg;
  A.desc_anchor_len = desc_anchor_len; A.desc_neg_len = desc_neg_len;
  A.tok_bih = tok_bih; A.tok_bhh = tok_bhh;
  A.desc_bih = desc_bih; A.desc_bhh = desc_bhh;
  A.hA = hA; A.hB = hB; A.hC = hC; A.hD = hD;
  A.featB = featB; A.finals = finals; A.flags = flags;
  lstm_persist_kernel<<<512, 256, 0, stream>>>(A);

  attn_scores_mfma<<<(BATCH * TCc) / 64, 256, 0, stream>>>(
      featB, attnWF, attn_b, attnS_W, attnS_b, scores);
  softmax_pool_kernel<<<BATCH, 256, 0, stream>>>(scores, tok_len, featB, pooled);
  gemm_bias_tanh_kernel<<<dim3(BATCH / 64, Hc / 64), 256, 0, stream>>>(
      pooled, out_W1, out_b1, a2, BATCH, Hc, Hc);
  gemm_bias_tanh_kernel<<<dim3(BATCH / 64, Hc / 64), 256, 0, stream>>>(
      a2, out_W2, out_b2, code, BATCH, Hc, Hc);
  loss_kernel<<<1, 256, 0, stream>>>(code, finals, (float*)d_out);
}

// Round 13
// 1183.204 us; speedup vs baseline: 12.5199x; 1.1149x over previous
//
#include <hip/hip_runtime.h>
#include <hip/hip_bf16.h>
#include <math.h>

#define TCc 200
#define TDc 50
#define BATCH 256
#define Ec 300
#define Hc 512
#define VOC 10000
#define EPAD 320
#define KC_E 10
#define KC_H 16
#define ROT 16   // h rotation depth (L1 self-eviction window)

typedef unsigned short u16;
typedef unsigned int u32;
typedef unsigned long long u64;
typedef __bf16 bf16x8 __attribute__((ext_vector_type(8)));
typedef float f32x4 __attribute__((ext_vector_type(4)));

__device__ __forceinline__ float sigf(float x) { return 1.f / (1.f + expf(-x)); }

__device__ __forceinline__ u16 f2bf(float f) {
  unsigned u = __float_as_uint(f);
  unsigned r = (u + 0x7FFFu + ((u >> 16) & 1u)) >> 16;  // RNE
  return (u16)r;
}
__device__ __forceinline__ float bf2f(u16 v) { return __uint_as_float(((unsigned)v) << 16); }

// L2-local atomic (no sc1 -> RMW executes in this XCD's L2; atomics bypass L1)
__device__ __forceinline__ u32 l2_add(u32* p, u32 v) {
  return __hip_atomic_fetch_add(p, v, __ATOMIC_RELAXED, __HIP_MEMORY_SCOPE_WORKGROUP);
}

__global__ __launch_bounds__(256) void zero_kernel(float* p, int n) {
  int i = blockIdx.x * 256 + threadIdx.x;
  if (i < n) p[i] = 0.f;
}

// emb (VOC, Ec) fp32 -> (VOC, EPAD) bf16, zero-padded
__global__ __launch_bounds__(256) void conv_emb_kernel(
    const float* __restrict__ emb, u32* __restrict__ out)
{
  int e = blockIdx.x * 256 + threadIdx.x;          // u32 index, VOC*EPAD/2 total
  if (e >= VOC * (EPAD / 2)) return;
  int v = e / (EPAD / 2);
  int k = (e - v * (EPAD / 2)) * 2;
  float a = (k < Ec) ? emb[(size_t)v * Ec + k] : 0.f;
  float b = (k + 1 < Ec) ? emb[(size_t)v * Ec + k + 1] : 0.f;
  out[e] = (u32)f2bf(a) | ((u32)f2bf(b) << 16);
}

// Weight (rows x K) fp32 -> MFMA B-fragment order bf16 (same as round 12).
template<int GATES>
__global__ __launch_bounds__(256) void conv_wfrag_kernel(
    const float* __restrict__ W, u32* __restrict__ out, int KC, int KREAL, int total)
{
  int e = blockIdx.x * 256 + threadIdx.x;          // u32 index
  if (e >= total) return;
  int jp = e & 3;
  int l = (e >> 2) & 63;
  int si = (e >> 8) & 1;
  int t2 = e >> 9;
  int kc = t2 % KC;
  int nc = t2 / KC;
  int c32 = (si << 4) + (l & 15);
  int srow;
  if (GATES) {
    int ulp = c32 >> 2, g = c32 & 3;
    int unit = ((ulp & 3) << 1) | (ulp >> 2);
    srow = (g << 9) + nc * 8 + unit;
  } else {
    srow = nc * 32 + c32;
  }
  int k = (kc << 5) + ((l >> 4) << 3) + (jp << 1);
  float a = (k < KREAL) ? W[(size_t)srow * KREAL + k] : 0.f;
  float b = (k + 1 < KREAL) ? W[(size_t)srow * KREAL + k + 1] : 0.f;
  out[e] = (u32)f2bf(a) | ((u32)f2bf(b) << 16);
}

// ---------------- persistent MFMA LSTM, XCD-local rowgroups ----------------
// Rowgroup = physical XCD (all 64 blocks share one L2). h exchange via PLAIN cached
// ld/st (dirty in shared L2); L1 staleness avoided by 16-deep buffer rotation
// (a CU re-touches an address only after ~2MB has streamed through its 32KB L1).
// Barrier: workgroup-scope relaxed atomics (L2-local RMW, no MALL, no cache ops).
__device__ __forceinline__ void bar_signal(u32* cnt, int cg) {
  asm volatile("s_waitcnt vmcnt(0)" ::: "memory");   // h stores acked by L2
  __syncthreads();
  if (threadIdx.x == 0) l2_add(cnt + ((cg & 7) << 4), 1u);
}
__device__ __forceinline__ void bar_wait(u32* cnt, u32 target) {
  if (threadIdx.x < 8) {
    while (l2_add(cnt + ((int)threadIdx.x << 4), 0u) < target)   // RMW read: bypasses L1
      __builtin_amdgcn_s_sleep(1);
  }
  __syncthreads();
}

struct PArgs {
  const u32* WhhT; const u32* WihT; const u16* embT;
  const u32* WhhD; const u32* WihD; const u16* embD;
  const int* tokens; const int* desc_anchor; const int* desc_neg;
  const int* desc_anchor_len; const int* desc_neg_len;
  const float* tok_bih; const float* tok_bhh;
  const float* desc_bih; const float* desc_bhh;
  u16* hTok; u16* hDesc;      // rotating fragment buffers: [rg][ROT][ROWS*512] u16
  u16* featB; float* finals;
  u32* flags;                  // [8 rg x 8 cnt x 16] + [8 claim x 16]
};

// cg in [0,64); rg fixed by XCD. ROWS=64 (tok) / 128 (desc). RPW = ROWS/64.
// h fragment layout per buffer: [rhp=lrow>>4][kc 16][lane 64][8 bf16].
template<int ROWS, bool IS_TOK>
__device__ void lstm_phase(
    int cg, int rg, u16* WhF, u16* WiF, float* gsum, int* idsL,
    const u32* __restrict__ WhhF, const u32* __restrict__ WihF, const u16* __restrict__ embB,
    const int* __restrict__ idsA, const int* __restrict__ idsB,
    const int* __restrict__ lenA, const int* __restrict__ lenB,
    const float* __restrict__ bih, const float* __restrict__ bhh,
    u16* __restrict__ hrot,
    u16* __restrict__ featB, float* __restrict__ finals,
    u32* cnt, int T)
{
  constexpr int RPW = ROWS / 64;
  constexpr size_t BUFN = (size_t)ROWS << 9;   // u16 per rotation slot
  const int tid = threadIdx.x;
  const int row0 = rg * ROWS;
  const int w = tid >> 6, l = tid & 63;
  const int rl = tid >> 2, u = tid & 3;
  int gen = 0;

  // stage weight fragments into LDS
  {
    const uint4* s = (const uint4*)(WhhF + ((size_t)cg << 13));
    uint4* d = (uint4*)WhF;
    #pragma unroll
    for (int i = 0; i < 8; ++i) d[(i << 8) + tid] = s[(i << 8) + tid];
    const uint4* s2 = (const uint4*)(WihF + (size_t)cg * 5120);
    uint4* d2 = (uint4*)WiF;
    #pragma unroll
    for (int i = 0; i < 5; ++i) d2[(i << 8) + tid] = s2[(i << 8) + tid];
  }

  const int ug0 = (cg << 3) + (u << 1);   // this thread's two adjacent units
  float bsv[2][4];
  #pragma unroll
  for (int uu = 0; uu < 2; ++uu)
    #pragma unroll
    for (int g = 0; g < 4; ++g)
      bsv[uu][g] = bih[(g << 9) + ug0 + uu] + bhh[(g << 9) + ug0 + uu];

  const int kcs    = ug0 >> 5;
  const int lanehi = (ug0 >> 3) & 3;
  const int jpos   = ug0 & 7;   // even

  float cc[RPW][2];
  int lens[RPW];
  #pragma unroll
  for (int p = 0; p < RPW; ++p) {
    cc[p][0] = 0.f; cc[p][1] = 0.f;
    int lrow = (p << 6) + rl;
    int row = row0 + lrow;
    lens[p] = IS_TOK ? 0 : ((row < BATCH) ? lenA[row] : lenB[row - BATCH]);
    int rhp = lrow >> 4;
    int lane_s = (rl & 15) | (lanehi << 4);
    size_t off16 = ((((size_t)rhp << 4) + kcs) << 6 | lane_s) << 3 | jpos;
    *(u32*)(hrot + off16) = 0u;   // slot 0 = initial zeros (plain store -> L2)
  }
  bar_signal(cnt, cg); ++gen;

  for (int t = 0; t < T; ++t) {
    const u16* hin = hrot + (size_t)(t & (ROT - 1)) * BUFN;
    u16* hout = hrot + (size_t)((t + 1) & (ROT - 1)) * BUFN;

    if (tid < ROWS) {
      int row = row0 + tid;
      idsL[tid] = IS_TOK ? idsA[row * T + t]
                         : ((row < BATCH) ? idsA[row * T + t] : idsB[(row - BATCH) * T + t]);
    }
    __syncthreads();

    f32x4 acc[RPW][2];
    #pragma unroll
    for (int p = 0; p < RPW; ++p) {
      acc[p][0] = (f32x4){0.f, 0.f, 0.f, 0.f};
      acc[p][1] = (f32x4){0.f, 0.f, 0.f, 0.f};
    }
    const u16* eb[RPW];
    const u16* hfb[RPW];
    #pragma unroll
    for (int p = 0; p < RPW; ++p) {
      int rhp = w + (p << 2);
      int ida = idsL[(rhp << 4) + (l & 15)];
      eb[p] = embB + (size_t)ida * EPAD + ((l >> 4) << 3);
      hfb[p] = hin + ((((size_t)rhp << 4) << 9) | (l << 3));   // kc stride = 512 u16
    }

    // ---- h-independent input-projection MFMAs first ----
    #pragma unroll
    for (int kc = 0; kc < KC_E; ++kc) {
      bf16x8 b0 = *(const bf16x8*)(WiF + ((((kc << 1) | 0) << 6 | l) << 3));
      bf16x8 b1 = *(const bf16x8*)(WiF + ((((kc << 1) | 1) << 6 | l) << 3));
      #pragma unroll
      for (int p = 0; p < RPW; ++p) {
        bf16x8 a = *(const bf16x8*)(eb[p] + (kc << 5));
        acc[p][0] = __builtin_amdgcn_mfma_f32_16x16x32_bf16(a, b0, acc[p][0], 0, 0, 0);
        acc[p][1] = __builtin_amdgcn_mfma_f32_16x16x32_bf16(a, b1, acc[p][1], 0, 0, 0);
      }
    }

    // ---- wait for h(t-1) visibility (L2-local) ----
    bar_wait(cnt, (u32)gen * 8u);

    // ---- recurrent MFMAs from plain cached 16B loads (L2 hits) ----
    #pragma unroll
    for (int kc = 0; kc < KC_H; ++kc) {
      bf16x8 b0 = *(const bf16x8*)(WhF + ((((kc << 1) | 0) << 6 | l) << 3));
      bf16x8 b1 = *(const bf16x8*)(WhF + ((((kc << 1) | 1) << 6 | l) << 3));
      #pragma unroll
      for (int p = 0; p < RPW; ++p) {
        bf16x8 a = *(const bf16x8*)(hfb[p] + (kc << 9));
        acc[p][0] = __builtin_amdgcn_mfma_f32_16x16x32_bf16(a, b0, acc[p][0], 0, 0, 0);
        acc[p][1] = __builtin_amdgcn_mfma_f32_16x16x32_bf16(a, b1, acc[p][1], 0, 0, 0);
      }
    }

    // ---- epilogue: gates, c/h update; h (fragment order, plain store); feat deferred ----
    float hnv[RPW][2];
    #pragma unroll
    for (int p = 0; p < RPW; ++p) {
      int lr0 = (w << 4) + ((l >> 4) << 2);
      #pragma unroll
      for (int si = 0; si < 2; ++si)
        #pragma unroll
        for (int j = 0; j < 4; ++j)
          gsum[(lr0 + j) * 36 + (si << 4) + (l & 15)] = acc[p][si][j];
      __syncthreads();
      {
        float4 g0 = *(const float4*)&gsum[rl * 36 + (u << 2)];          // unit 2u
        float4 g1 = *(const float4*)&gsum[rl * 36 + ((u + 4) << 2)];    // unit 2u+1
        int lrow = (p << 6) + rl;
        int row = row0 + lrow;
        float gi0 = sigf(g0.x + bsv[0][0]);
        float gf0 = sigf(g0.y + bsv[0][1]);
        float gg0 = tanhf(g0.z + bsv[0][2]);
        float go0 = sigf(g0.w + bsv[0][3]);
        float cn0 = gf0 * cc[p][0] + gi0 * gg0;
        cc[p][0] = cn0;
        float hn0 = go0 * tanhf(cn0);
        float gi1 = sigf(g1.x + bsv[1][0]);
        float gf1 = sigf(g1.y + bsv[1][1]);
        float gg1 = tanhf(g1.z + bsv[1][2]);
        float go1 = sigf(g1.w + bsv[1][3]);
        float cn1 = gf1 * cc[p][1] + gi1 * gg1;
        cc[p][1] = cn1;
        float hn1 = go1 * tanhf(cn1);
        hnv[p][0] = hn0; hnv[p][1] = hn1;
        int rhp = lrow >> 4;
        int lane_s = (rl & 15) | (lanehi << 4);
        size_t off16 = ((((size_t)rhp << 4) + kcs) << 6 | lane_s) << 3 | jpos;
        *(u32*)(hout + off16) = (u32)f2bf(hn0) | ((u32)f2bf(hn1) << 16);
        if (!IS_TOK) {
          if (t == lens[p] - 1) {
            finals[((size_t)row << 9) + ug0]     = tanhf(hn0);
            finals[((size_t)row << 9) + ug0 + 1] = tanhf(hn1);
          }
        }
      }
      __syncthreads();
    }
    bar_signal(cnt, cg); ++gen;   // h(t) visible in L2

    if (IS_TOK) {
      #pragma unroll
      for (int p = 0; p < RPW; ++p) {
        int row = row0 + (p << 6) + rl;
        size_t fo = ((size_t)row * TCc + t) << 9;
        *(u32*)(featB + fo + ug0) =
            (u32)f2bf(tanhf(hnv[p][0])) | ((u32)f2bf(tanhf(hnv[p][1])) << 16);
      }
    }
  }
}

// 512 blocks; each claims (xcd, rank) at start. Capacity (2 blocks/CU by LDS, 32 CU/XCD)
// forces exactly 64 blocks per XCD. XCDs 0-3 -> tok rowgroups, 4-7 -> desc rowgroups.
__global__ void __launch_bounds__(256, 1) lstm_persist_kernel(PArgs A) {
  __shared__ __align__(16) u16 WhF[KC_H * 2 * 64 * 8];   // 32768 B
  __shared__ __align__(16) u16 WiF[KC_E * 2 * 64 * 8];   // 20480 B
  __shared__ __align__(16) float gsum[64 * 36];          // 9216 B
  __shared__ int idsL[128];                              // 512 B
  __shared__ int s_claim[2];
  if (threadIdx.x == 0) {
    int xcd;
    asm("s_getreg_b32 %0, hwreg(HW_REG_XCC_ID)" : "=s"(xcd));
    xcd &= 7;
    u32 rank = l2_add(A.flags + 1024 + (xcd << 4), 1u);   // claim slot (L2-local)
    s_claim[0] = xcd;
    s_claim[1] = (int)rank;
  }
  __syncthreads();
  const int xcd = s_claim[0];
  const int cg = s_claim[1] & 63;

  if (xcd < 4) {
    int rg = xcd;
    u32* cnt = A.flags + (rg << 7);
    u16* hrot = A.hTok + (size_t)rg * ROT * ((size_t)64 << 9);
    lstm_phase<64, true>(cg, rg, WhF, WiF, gsum, idsL, A.WhhT, A.WihT, A.embT,
                         A.tokens, nullptr, nullptr, nullptr,
                         A.tok_bih, A.tok_bhh, hrot, A.featB, nullptr,
                         cnt, TCc);
  } else {
    int rg = xcd - 4;
    u32* cnt = A.flags + ((4 + rg) << 7);
    u16* hrot = A.hDesc + (size_t)rg * ROT * ((size_t)128 << 9);
    lstm_phase<128, false>(cg, rg, WhF, WiF, gsum, idsL, A.WhhD, A.WihD, A.embD,
                           A.desc_anchor, A.desc_neg, A.desc_anchor_len, A.desc_neg_len,
                           A.desc_bih, A.desc_bhh, hrot, nullptr, A.finals,
                           cnt, TDc);
  }
}

// ---------------- attention scores via MFMA ----------------
__global__ __launch_bounds__(256) void attn_scores_mfma(
    const u16* __restrict__ featB, const u32* __restrict__ WF,
    const float* __restrict__ attn_b, const float* __restrict__ attnS_W,
    const float* __restrict__ attnS_b, float* __restrict__ scores)
{
  __shared__ __align__(16) u16 Af[4 * 16 * 64 * 8];   // 65536 B (reused as red after)
  const int tid = threadIdx.x;
  const int m0 = blockIdx.x * 64;

  #pragma unroll
  for (int i = 0; i < 16; ++i) {
    int c = (i << 8) + tid;
    int r = c >> 6, kb = c & 63;
    uint4 v = *(const uint4*)(featB + (((size_t)(m0 + r)) << 9) + (kb << 3));
    int kc = kb >> 2, lf = (r & 15) + ((kb & 3) << 4);
    *(uint4*)(Af + ((((r >> 4) * 16 + kc) << 6 | lf) << 3)) = v;
  }
  __syncthreads();

  const int w = tid >> 6, l = tid & 63;
  const u16* WF16 = (const u16*)WF;
  float p[4][4] = {};
  for (int nc = w * 4; nc < w * 4 + 4; ++nc) {
    f32x4 acc[4][2];
    #pragma unroll
    for (int rh = 0; rh < 4; ++rh) {
      acc[rh][0] = (f32x4){0.f, 0.f, 0.f, 0.f};
      acc[rh][1] = (f32x4){0.f, 0.f, 0.f, 0.f};
    }
    #pragma unroll 4
    for (int kc = 0; kc < 16; ++kc) {
      bf16x8 b0 = *(const bf16x8*)(WF16 + ((size_t)((((nc << 4) + kc) << 1 | 0) << 6 | l) << 3));
      bf16x8 b1 = *(const bf16x8*)(WF16 + ((size_t)((((nc << 4) + kc) << 1 | 1) << 6 | l) << 3));
      #pragma unroll
      for (int rh = 0; rh < 4; ++rh) {
        bf16x8 a = *(const bf16x8*)(Af + (((rh * 16 + kc) << 6 | l) << 3));
        acc[rh][0] = __builtin_amdgcn_mfma_f32_16x16x32_bf16(a, b0, acc[rh][0], 0, 0, 0);
        acc[rh][1] = __builtin_amdgcn_mfma_f32_16x16x32_bf16(a, b1, acc[rh][1], 0, 0, 0);
      }
    }
    int c0 = (nc << 5) + (l & 15), c1 = c0 + 16;
    float bb0 = attn_b[c0], sw0 = attnS_W[c0];
    float bb1 = attn_b[c1], sw1 = attnS_W[c1];
    #pragma unroll
    for (int rh = 0; rh < 4; ++rh)
      #pragma unroll
      for (int j = 0; j < 4; ++j)
        p[rh][j] += tanhf(acc[rh][0][j] + bb0) * sw0 + tanhf(acc[rh][1][j] + bb1) * sw1;
  }
  __syncthreads();
  float* red = (float*)Af;   // 64 x 68
  #pragma unroll
  for (int rh = 0; rh < 4; ++rh)
    #pragma unroll
    for (int j = 0; j < 4; ++j)
      red[(rh * 16 + ((l >> 4) << 2) + j) * 68 + (w << 4) + (l & 15)] = p[rh][j];
  __syncthreads();
  if (tid < 64) {
    float s = attnS_b[0];
    #pragma unroll 8
    for (int q = 0; q < 64; ++q) s += red[tid * 68 + q];
    scores[m0 + tid] = s;
  }
}

// masked softmax over T=200 + weighted pooling of bf16 feat -> pooled (B,H) fp32
__global__ __launch_bounds__(256) void softmax_pool_kernel(
    const float* __restrict__ scores, const int* __restrict__ tok_len,
    const u16* __restrict__ featB, float* __restrict__ pooled)
{
  const int b = blockIdx.x;
  const int tid = threadIdx.x;
  __shared__ float wgt[TCc];
  __shared__ float red[256];
  const int len = tok_len[b];

  float myv = -1e30f;
  if (tid < TCc) {
    float s = scores[b * TCc + tid];
    myv = (tid < len) ? s : -1e9f;
    wgt[tid] = myv;
  }
  red[tid] = myv;
  __syncthreads();
  for (int s = 128; s > 0; s >>= 1) {
    if (tid < s) red[tid] = fmaxf(red[tid], red[tid + s]);
    __syncthreads();
  }
  const float mx = red[0];
  __syncthreads();
  float e = 0.f;
  if (tid < TCc) e = expf(wgt[tid] - mx);
  red[tid] = e;
  __syncthreads();
  for (int s = 128; s > 0; s >>= 1) {
    if (tid < s) red[tid] += red[tid + s];
    __syncthreads();
  }
  const float sum = red[0];
  __syncthreads();
  if (tid < TCc) wgt[tid] = e / sum;
  __syncthreads();

  const u32* featU = (const u32*)featB;
  float a0 = 0.f, a1 = 0.f;
  for (int t = 0; t < TCc; ++t) {
    u32 v = featU[((size_t)b * TCc + t) * 256 + tid];
    float wv = wgt[t];
    a0 = fmaf(wv, bf2f((u16)(v & 0xFFFF)), a0);
    a1 = fmaf(wv, bf2f((u16)(v >> 16)), a1);
  }
  pooled[((size_t)b << 9) + tid * 2] = a0;
  pooled[((size_t)b << 9) + tid * 2 + 1] = a1;
}

// C[m,n] = tanh(A[m,:] . W[n,:] + bias[n]); fp32, grid (M/64, N/64)
__global__ __launch_bounds__(256) void gemm_bias_tanh_kernel(
    const float* __restrict__ A, const float* __restrict__ Bw,
    const float* __restrict__ bias, float* __restrict__ C, int M, int N, int K)
{
  const int r0 = blockIdx.x * 64;
  const int n0 = blockIdx.y * 64;
  const int tid = threadIdx.x;
  const int tu = tid & 15;
  const int tm = tid >> 4;
  __shared__ float As[32][68];
  __shared__ float Bs[32][68];

  float acc[4][4] = {};
  for (int k0 = 0; k0 < K; k0 += 32) {
    #pragma unroll
    for (int i = 0; i < 2; ++i) {
      int lin = tid + (i << 8);
      int kq = lin & 7, m = lin >> 3;
      int k = k0 + (kq << 2);
      int r = r0 + m; if (r >= M) r = M - 1;
      float4 va = *(const float4*)&A[(size_t)r * K + k];
      float4 vb = *(const float4*)&Bw[(size_t)(n0 + m) * K + k];
      As[(kq << 2) + 0][m] = va.x; As[(kq << 2) + 1][m] = va.y;
      As[(kq << 2) + 2][m] = va.z; As[(kq << 2) + 3][m] = va.w;
      Bs[(kq << 2) + 0][m] = vb.x; Bs[(kq << 2) + 1][m] = vb.y;
      Bs[(kq << 2) + 2][m] = vb.z; Bs[(kq << 2) + 3][m] = vb.w;
    }
    __syncthreads();
    #pragma unroll
    for (int kk = 0; kk < 32; ++kk) {
      float4 a = *(const float4*)&As[kk][tm << 2];
      float4 b = *(const float4*)&Bs[kk][tu << 2];
      acc[0][0] = fmaf(a.x, b.x, acc[0][0]); acc[0][1] = fmaf(a.x, b.y, acc[0][1]);
      acc[0][2] = fmaf(a.x, b.z, acc[0][2]); acc[0][3] = fmaf(a.x, b.w, acc[0][3]);
      acc[1][0] = fmaf(a.y, b.x, acc[1][0]); acc[1][1] = fmaf(a.y, b.y, acc[1][1]);
      acc[1][2] = fmaf(a.y, b.z, acc[1][2]); acc[1][3] = fmaf(a.y, b.w, acc[1][3]);
      acc[2][0] = fmaf(a.z, b.x, acc[2][0]); acc[2][1] = fmaf(a.z, b.y, acc[2][1]);
      acc[2][2] = fmaf(a.z, b.z, acc[2][2]); acc[2][3] = fmaf(a.z, b.w, acc[2][3]);
      acc[3][0] = fmaf(a.w, b.x, acc[3][0]); acc[3][1] = fmaf(a.w, b.y, acc[3][1]);
      acc[3][2] = fmaf(a.w, b.z, acc[3][2]); acc[3][3] = fmaf(a.w, b.w, acc[3][3]);
    }
    __syncthreads();
  }
  float bj[4];
  #pragma unroll
  for (int j = 0; j < 4; ++j) bj[j] = bias[n0 + (tu << 2) + j];
  #pragma unroll
  for (int i = 0; i < 4; ++i) {
    int r = r0 + (tm << 2) + i;
    if (r < M) {
      float4 v;
      v.x = tanhf(acc[i][0] + bj[0]); v.y = tanhf(acc[i][1] + bj[1]);
      v.z = tanhf(acc[i][2] + bj[2]); v.w = tanhf(acc[i][3] + bj[3]);
      *(float4*)&C[(size_t)r * N + n0 + (tu << 2)] = v;
    }
  }
}

__global__ __launch_bounds__(256) void loss_kernel(
    const float* __restrict__ code, const float* __restrict__ finals, float* __restrict__ out)
{
  const int b = threadIdx.x;
  const float* cv = code + (size_t)b * Hc;
  const float* av = finals + (size_t)b * Hc;
  const float* nv = finals + (size_t)(BATCH + b) * Hc;
  float dca = 0, dcn = 0, ncc = 0, naa = 0, nnn = 0;
  for (int k = 0; k < Hc; ++k) {
    float c = cv[k], a = av[k], n = nv[k];
    dca = fmaf(c, a, dca);
    dcn = fmaf(c, n, dcn);
    ncc = fmaf(c, c, ncc);
    naa = fmaf(a, a, naa);
    nnn = fmaf(n, n, nnn);
  }
  float cos_a = dca / fmaxf(sqrtf(ncc) * sqrtf(naa), 1e-8f);
  float cos_n = dcn / fmaxf(sqrtf(ncc) * sqrtf(nnn), 1e-8f);
  float hinge = fmaxf(0.6f - cos_a + cos_n, 1e-6f);
  __shared__ float red[256];
  red[b] = hinge;
  __syncthreads();
  for (int s = 128; s > 0; s >>= 1) {
    if (b < s) red[b] += red[b + s];
    __syncthreads();
  }
  if (b == 0) out[0] = red[0] / 256.0f;
}

extern "C" void kernel_launch(void* const* d_in, const int* in_sizes, int n_in,
                              void* d_out, int out_size, void* d_ws, size_t ws_size,
                              hipStream_t stream) {
  const int* tokens          = (const int*)d_in[0];
  const int* tok_len         = (const int*)d_in[1];
  const int* desc_anchor     = (const int*)d_in[2];
  const int* desc_anchor_len = (const int*)d_in[3];
  const int* desc_neg        = (const int*)d_in[4];
  const int* desc_neg_len    = (const int*)d_in[5];
  const float* tok_emb  = (const float*)d_in[6];
  const float* tok_Wih  = (const float*)d_in[7];
  const float* tok_Whh  = (const float*)d_in[8];
  const float* tok_bih  = (const float*)d_in[9];
  const float* tok_bhh  = (const float*)d_in[10];
  const float* desc_emb = (const float*)d_in[11];
  const float* desc_Wih = (const float*)d_in[12];
  const float* desc_Whh = (const float*)d_in[13];
  const float* desc_bih = (const float*)d_in[14];
  const float* desc_bhh = (const float*)d_in[15];
  const float* attn_W   = (const float*)d_in[16];
  const float* attn_b   = (const float*)d_in[17];
  const float* attnS_W  = (const float*)d_in[18];
  const float* attnS_b  = (const float*)d_in[19];
  const float* out_W1   = (const float*)d_in[20];
  const float* out_b1   = (const float*)d_in[21];
  const float* out_W2   = (const float*)d_in[22];
  const float* out_b2   = (const float*)d_in[23];

  float* p = (float*)d_ws;
  size_t off = 0;
  auto alloc = [&](size_t n) { float* q = p + off; off += n; return q; };

  u16*  featB  = (u16*)alloc(13107200);     // 256*200*512 bf16 (2x slop)
  u16*  embT   = (u16*)alloc(1600000);
  u16*  embD   = (u16*)alloc(1600000);
  u32*  WihT   = (u32*)alloc(327680);
  u32*  WihD   = (u32*)alloc(327680);
  u32*  WhhT   = (u32*)alloc(524288);
  u32*  WhhD   = (u32*)alloc(524288);
  u32*  attnWF = (u32*)alloc(131072);
  u16*  hTok   = (u16*)alloc(1048576);      // 4rg x ROT16 x 32768 u16 = 2,097,152 u16
  u16*  hDesc  = (u16*)alloc(2097152);      // 4rg x ROT16 x 65536 u16 = 4,194,304 u16
  float* finals = alloc(262144);
  float* scores = alloc(51200);
  float* pooled = alloc(131072);
  float* a2     = alloc(131072);
  float* code   = alloc(131072);
  u32* flags = (u32*)alloc(1280);           // 1024 barrier cnts + 128 claim + pad

  // weight / embedding conversions
  conv_emb_kernel<<<(VOC * (EPAD / 2) + 255) / 256, 256, 0, stream>>>(tok_emb, (u32*)embT);
  conv_emb_kernel<<<(VOC * (EPAD / 2) + 255) / 256, 256, 0, stream>>>(desc_emb, (u32*)embD);
  conv_wfrag_kernel<1><<<2048, 256, 0, stream>>>(tok_Whh, WhhT, KC_H, Hc, 524288);
  conv_wfrag_kernel<1><<<2048, 256, 0, stream>>>(desc_Whh, WhhD, KC_H, Hc, 524288);
  conv_wfrag_kernel<1><<<1280, 256, 0, stream>>>(tok_Wih, WihT, KC_E, Ec, 327680);
  conv_wfrag_kernel<1><<<1280, 256, 0, stream>>>(desc_Wih, WihD, KC_E, Ec, 327680);
  conv_wfrag_kernel<0><<<512, 256, 0, stream>>>(attn_W, attnWF, KC_H, Hc, 131072);
  zero_kernel<<<5, 256, 0, stream>>>((float*)flags, 1280);

  PArgs A;
  A.WhhT = WhhT; A.WihT = WihT; A.embT = embT;
  A.WhhD = WhhD; A.WihD = WihD; A.embD = embD;
  A.tokens = tokens; A.desc_anchor = desc_anchor; A.desc_neg = desc_neg;
  A.desc_anchor_len = desc_anchor_len; A.desc_neg_len = desc_neg_len;
  A.tok_bih = tok_bih; A.tok_bhh = tok_bhh;
  A.desc_bih = desc_bih; A.desc_bhh = desc_bhh;
  A.hTok = hTok; A.hDesc = hDesc;
  A.featB = featB; A.finals = finals; A.flags = flags;
  lstm_persist_kernel<<<512, 256, 0, stream>>>(A);

  attn_scores_mfma<<<(BATCH * TCc) / 64, 256, 0, stream>>>(
      featB, attnWF, attn_b, attnS_W, attnS_b, scores);
  softmax_pool_kernel<<<BATCH, 256, 0, stream>>>(scores, tok_len, featB, pooled);
  gemm_bias_tanh_kernel<<<dim3(BATCH / 64, Hc / 64), 256, 0, stream>>>(
      pooled, out_W1, out_b1, a2, BATCH, Hc, Hc);
  gemm_bias_tanh_kernel<<<dim3(BATCH / 64, Hc / 64), 256, 0, stream>>>(
      a2, out_W2, out_b2, code, BATCH, Hc, Hc);
  loss_kernel<<<1, 256, 0, stream>>>(code, finals, (float*)d_out);
}